// Round 6
// baseline (2665.861 us; speedup 1.0000x reference)
//
#include <hip/hip_runtime.h>
#include <hip/hip_bf16.h>

// LightGCN encoder on MI355X.
// Device dtypes: user_emb/item_emb/adj_val = float32 (bf16-rounded values),
// adj_row/adj_col = int32, drop_mask = bool/int32 (runtime-detected),
// users/items = int64/int32 (runtime-detected), output = float32.
//
// Round-5 evidence: CSR scatter had 8x write amplification (WRITE_SIZE 127 MB
// for a 16 MB payload -> 2M random 8B stores each dirtying a 64B line), and
// the whole CSR prep (hist + scans + scatter) cost ~160 us. This version
// replaces it with ONE bucket-partition pass (bucket = row>>6, per-bucket
// cursor -> stores cluster into dense 16 KB regions -> L2 write-combining,
// ~1x amplification) and an LDS-accumulating SpMM (one WG per 64-row bucket,
// 16 KB f32 accumulator, ds_add_f32, unroll-8 gathers for MLP).
// Edge record: u64 = row(18b) | col(18b)<<18 | val_bf16(16b)<<36; val is
// exactly bf16-representable (inputs bf16-rounded, x2 = exponent bump).

#define NUSER 100000
#define NITEM 50000
#define NNODE 150000
#define DIM   64
#define NNZ   4000000
#define BATCH 16384
#define BSH   6
#define BROWS 64
#define NB    2344      // ceil(150000/64)
#define BCAP  2048      // bucket capacity; mean kept/bucket: items ~1280, +20 sigma safe
#define ITEM_B 1562     // first bucket with item rows (100000>>6); schedule heavy first

typedef __hip_bfloat16 bf16;
typedef unsigned long long u64;
typedef float f4 __attribute__((ext_vector_type(4)));

__device__ __forceinline__ float loadF(const void* p, long i, int isbf16) {
    return isbf16 ? __bfloat162float(((const bf16*)p)[i]) : ((const float*)p)[i];
}

__device__ __forceinline__ bool keepE(const void* mask, int e, int isbyte) {
    return isbyte ? (((const unsigned char*)mask)[e] != 0)
                  : (((const int*)mask)[e] != 0);
}

// ---------------------------------------------------------------------------
// flags[0]: drop_mask is 1-byte. flags[1]: users/items are int64.
// flags[2]: float arrays are bf16 (insurance; expected 0 = f32).
__global__ __launch_bounds__(256) void detect_fmt(const unsigned int* __restrict__ mask,
                                                  const unsigned int* __restrict__ users,
                                                  const unsigned int* __restrict__ adjv,
                                                  int* __restrict__ flags) {
    __shared__ int s[3];
    if (threadIdx.x < 3) s[threadIdx.x] = 0;
    __syncthreads();
    int c0 = 0, c1 = 0, c2 = 0;
    for (int i = threadIdx.x; i < 4096; i += 256) {
        c0 += (mask[i] > 1u) ? 1 : 0;
        if (i & 1) c1 += (users[i] == 0u) ? 1 : 0;
        unsigned lo = adjv[i] & 0xFFFFu;
        unsigned ex = (lo >> 7) & 0xFFu;
        c2 += ((lo >> 15) == 0u && ex >= 0x60u && ex <= 0x7Fu) ? 1 : 0;
    }
    atomicAdd(&s[0], c0); atomicAdd(&s[1], c1); atomicAdd(&s[2], c2);
    __syncthreads();
    if (threadIdx.x == 0) {
        flags[0] = (s[0] > 16) ? 1 : 0;
        flags[1] = (s[1] > 1024) ? 1 : 0;
        flags[2] = (s[2] > 3000) ? 1 : 0;
    }
}

// single-pass bucket partition of kept edges (replaces hist+scan+scatter)
__global__ __launch_bounds__(256) void partition_edges(const void* __restrict__ mask,
                                                       const int* __restrict__ rows,
                                                       const int* __restrict__ cols,
                                                       const void* __restrict__ adjv,
                                                       const int* __restrict__ flags,
                                                       int* __restrict__ bcur,
                                                       u64* __restrict__ part) {
    int e = blockIdx.x * 256 + threadIdx.x;
    if (e >= NNZ) return;
    if (!keepE(mask, e, flags[0])) return;
    int r = rows[e];
    int c = cols[e];
    float v = 2.0f * loadF(adjv, e, flags[2]);     // 1/(1-0.5) rescale
    u64 rec = (u64)(unsigned)r
            | ((u64)(unsigned)c << 18)
            | ((u64)(__float_as_uint(v) >> 16) << 36);
    int b = r >> BSH;
    int pos = atomicAdd(&bcur[b], 1);
    if (pos < BCAP) part[(size_t)b * BCAP + pos] = rec;
}

// A = f32(concat(user_emb, item_emb))
__global__ __launch_bounds__(256) void concat_cast(const void* __restrict__ ue,
                                                   const void* __restrict__ ie,
                                                   const int* __restrict__ flags,
                                                   float* __restrict__ A) {
    long q = (long)blockIdx.x * 256 + threadIdx.x;   // float4 index
    const long NU4 = (long)NUSER * DIM / 4;
    const long NT4 = (long)NNODE * DIM / 4;
    if (q >= NT4) return;
    if (!flags[2]) {
        const f4* s = (q < NU4) ? (const f4*)ue : (const f4*)ie;
        long qi = (q < NU4) ? q : q - NU4;
        ((f4*)A)[q] = s[qi];
    } else {
        long i = q * 4;
        const long NU = NU4 * 4;
        for (int k = 0; k < 4; ++k)
            A[i + k] = (i + k < NU) ? loadF(ue, i + k, 1) : loadF(ie, i + k - NU, 1);
    }
}

// One WG per bucket: LDS f32[64][64] accumulator; wave-per-edge, lane = dim.
// Unroll-8 -> 8 independent 256B row-gathers in flight per wave.
__global__ __launch_bounds__(256) void spmm_lds(const float* __restrict__ src,
                                                const u64* __restrict__ part,
                                                const int* __restrict__ bcur,
                                                float* __restrict__ dst) {
    __shared__ float lacc[BROWS * DIM];
    int b = blockIdx.x + ITEM_B;          // heavy (item) buckets first
    if (b >= NB) b -= NB;
    int n = bcur[b];
    if (n > BCAP) n = BCAP;
    const u64* ep = part + (size_t)b * BCAP;

    for (int i = threadIdx.x; i < BROWS * DIM; i += 256) lacc[i] = 0.0f;
    __syncthreads();

    int w = threadIdx.x >> 6, lane = threadIdx.x & 63;
    int j = w * 8;
    for (; j + 8 <= n; j += 32) {
        u64 e[8];
        #pragma unroll
        for (int k = 0; k < 8; ++k) e[k] = ep[j + k];
        float s[8], v[8]; int rl[8];
        #pragma unroll
        for (int k = 0; k < 8; ++k) {
            int c = (int)((e[k] >> 18) & 0x3FFFF);
            rl[k] = (int)(e[k] & (BROWS - 1));
            v[k]  = __uint_as_float((unsigned)((e[k] >> 36) & 0xFFFF) << 16);
            s[k]  = src[(size_t)c * DIM + lane];
        }
        #pragma unroll
        for (int k = 0; k < 8; ++k)
            atomicAdd(&lacc[rl[k] * DIM + lane], v[k] * s[k]);
    }
    for (int k = j; k < n && k < j + 8; ++k) {
        u64 ek = ep[k];
        int c = (int)((ek >> 18) & 0x3FFFF);
        int rl = (int)(ek & (BROWS - 1));
        float vv = __uint_as_float((unsigned)((ek >> 36) & 0xFFFF) << 16);
        atomicAdd(&lacc[rl * DIM + lane], vv * src[(size_t)c * DIM + lane]);
    }
    __syncthreads();

    int rbase = b << BSH;
    for (int i = threadIdx.x; i < BROWS * DIM / 4; i += 256) {   // f4 units
        int rr = rbase + (i >> 4);
        if (rr < NNODE) {
            f4 val = ((const f4*)lacc)[i];
            __builtin_nontemporal_store(val, (f4*)(dst + (size_t)rr * DIM) + (i & 15));
        }
    }
}

__device__ __forceinline__ long nodeOf(int b, const int* users, const int* items, int sh) {
    if (b < BATCH) return (long)users[(size_t)b << sh];
    return (long)NUSER + (long)items[(size_t)(b - BATCH) << sh];
}

// acc[b,:] = table[node(b),:]        (first layer: store, saves memset+read)
__global__ __launch_bounds__(256) void gather_first(const float* __restrict__ table,
                                                    const int* __restrict__ users,
                                                    const int* __restrict__ items,
                                                    const int* __restrict__ flags,
                                                    float* __restrict__ acc) {
    int t = blockIdx.x * 256 + threadIdx.x;          // float4 index
    if (t >= 2 * BATCH * DIM / 4) return;
    long node = nodeOf(t >> 4, users, items, flags[1]);
    ((f4*)acc)[t] = ((const f4*)(table + node * DIM))[t & 15];
}

// acc[b,:] += table[node(b),:]
__global__ __launch_bounds__(256) void gather_add(const float* __restrict__ table,
                                                  const int* __restrict__ users,
                                                  const int* __restrict__ items,
                                                  const int* __restrict__ flags,
                                                  float* __restrict__ acc) {
    int t = blockIdx.x * 256 + threadIdx.x;
    if (t >= 2 * BATCH * DIM / 4) return;
    long node = nodeOf(t >> 4, users, items, flags[1]);
    f4 a = ((f4*)acc)[t];
    a += ((const f4*)(table + node * DIM))[t & 15];
    ((f4*)acc)[t] = a;
}

// out = 0.25 * (acc + table[node])   (fused last gather + scale)
__global__ __launch_bounds__(256) void gather_final(const float* __restrict__ table,
                                                    const int* __restrict__ users,
                                                    const int* __restrict__ items,
                                                    const int* __restrict__ flags,
                                                    const float* __restrict__ acc,
                                                    float* __restrict__ out) {
    int t = blockIdx.x * 256 + threadIdx.x;
    if (t >= 2 * BATCH * DIM / 4) return;
    long node = nodeOf(t >> 4, users, items, flags[1]);
    f4 a = ((const f4*)acc)[t];
    a += ((const f4*)(table + node * DIM))[t & 15];
    a *= 0.25f;
    __builtin_nontemporal_store(a, (f4*)out + t);
}

extern "C" void kernel_launch(void* const* d_in, const int* in_sizes, int n_in,
                              void* d_out, int out_size, void* d_ws, size_t ws_size,
                              hipStream_t stream) {
    const void* user_emb = d_in[0];
    const void* item_emb = d_in[1];
    const void* adj_val  = d_in[2];
    const int*  adj_row  = (const int*)d_in[3];
    const int*  adj_col  = (const int*)d_in[4];
    const void* drop_msk = d_in[5];
    const int*  users    = (const int*)d_in[6];
    const int*  items    = (const int*)d_in[7];
    float* out = (float*)d_out;

    char* ws = (char*)d_ws;
    size_t off = 0;
    int* flags = (int*)(ws + off);            off += 256;
    float* out_acc = (float*)(ws + off);      off += (size_t)2 * BATCH * DIM * 4;   // 8 MB
    float* A = (float*)(ws + off);            off += (size_t)NNODE * DIM * 4;       // 38.4 MB
    float* B = (float*)(ws + off);            off += (size_t)NNODE * DIM * 4;       // 38.4 MB
    int* bcur = (int*)(ws + off);             off += (size_t)((NB * 4 + 255) / 256) * 256;
    u64* part = (u64*)(ws + off);             off += (size_t)NB * BCAP * 8 + 256;   // 38.4 MB

    const int OUTN4 = 2 * BATCH * DIM / 4;            // 524288
    const int GOUT = (OUTN4 + 255) / 256;             // 2048
    const int GEDGE = (NNZ + 255) / 256;              // 15625

    (void)hipMemsetAsync(bcur, 0, (size_t)NB * 4, stream);

    detect_fmt<<<1, 256, 0, stream>>>((const unsigned int*)drop_msk,
                                      (const unsigned int*)users,
                                      (const unsigned int*)adj_val, flags);
    partition_edges<<<GEDGE, 256, 0, stream>>>(drop_msk, adj_row, adj_col, adj_val,
                                               flags, bcur, part);
    concat_cast<<<((NNODE * DIM / 4) + 255) / 256, 256, 0, stream>>>(user_emb, item_emb,
                                                                     flags, A);
    gather_first<<<GOUT, 256, 0, stream>>>(A, users, items, flags, out_acc);

    float* src = A;
    float* dst = B;
    for (int l = 0; l < 3; ++l) {
        spmm_lds<<<NB, 256, 0, stream>>>(src, part, bcur, dst);
        if (l < 2) {
            gather_add<<<GOUT, 256, 0, stream>>>(dst, users, items, flags, out_acc);
        } else {
            gather_final<<<GOUT, 256, 0, stream>>>(dst, users, items, flags, out_acc, out);
        }
        float* t = src; src = dst; dst = t;
    }
}

// Round 7
// 437.398 us; speedup vs baseline: 6.0948x; 6.0948x over previous
//
#include <hip/hip_runtime.h>
#include <hip/hip_bf16.h>

// LightGCN encoder on MI355X.
// Device dtypes: user_emb/item_emb/adj_val = float32 (bf16-rounded values),
// adj_row/adj_col = int32, drop_mask = bool/int32 (runtime-detected),
// users/items = int64/int32 (runtime-detected), output = float32.
//
// Round-6 post-mortem: LDS-accumulator SpMM collapsed MLP (VGPR=20, serialized
// gathers) and bucket partition false-shared across XCDs. Reverted to the
// round-5 structure (wave-per-row CSR SpMM, quarter-wave gathers) with two
// byte-shrinking changes:
//  * edges packed to u32: col(18b) | val-code(13b). val in (0,2] is exactly
//    bf16 (inputs bf16-rounded; x2 bumps exponent) -> 6b exp-offset + 7b mant.
//    Scatter stores 4B/edge (was 8B) -> ~half the write amplification.
//  * propagation tables in bf16: gathers 128B/row (was 256B), table writes
//    19.2MB (was 38.4). Accumulation stays f32; layer-0 table is exact.

#define NUSER 100000
#define NITEM 50000
#define NNODE 150000
#define DIM   64
#define NNZ   4000000
#define BATCH 16384
#define SCAN_BLOCKS 586   // ceil(NNODE/256)

typedef __hip_bfloat16 bf16;
typedef unsigned short ushort;
typedef float f4 __attribute__((ext_vector_type(4)));
typedef ushort us4 __attribute__((ext_vector_type(4)));

__device__ __forceinline__ float loadF(const void* p, long i, int isbf16) {
    return isbf16 ? __bfloat162float(((const bf16*)p)[i]) : ((const float*)p)[i];
}

__device__ __forceinline__ bool keepE(const void* mask, int e, int isbyte) {
    return isbyte ? (((const unsigned char*)mask)[e] != 0)
                  : (((const int*)mask)[e] != 0);
}

__device__ __forceinline__ ushort f2bf(float x) {   // round-to-nearest-even
    unsigned u = __float_as_uint(x);
    return (ushort)((u + 0x7FFFu + ((u >> 16) & 1u)) >> 16);
}
__device__ __forceinline__ float bf2f(ushort u) {
    return __uint_as_float((unsigned)u << 16);
}

// ---------------------------------------------------------------------------
// flags[0]: drop_mask is 1-byte. flags[1]: users/items are int64.
// flags[2]: float arrays are bf16 (insurance; expected 0 = f32).
__global__ __launch_bounds__(256) void detect_fmt(const unsigned int* __restrict__ mask,
                                                  const unsigned int* __restrict__ users,
                                                  const unsigned int* __restrict__ adjv,
                                                  int* __restrict__ flags) {
    __shared__ int s[3];
    if (threadIdx.x < 3) s[threadIdx.x] = 0;
    __syncthreads();
    int c0 = 0, c1 = 0, c2 = 0;
    for (int i = threadIdx.x; i < 4096; i += 256) {
        c0 += (mask[i] > 1u) ? 1 : 0;
        if (i & 1) c1 += (users[i] == 0u) ? 1 : 0;
        unsigned lo = adjv[i] & 0xFFFFu;
        unsigned ex = (lo >> 7) & 0xFFu;
        c2 += ((lo >> 15) == 0u && ex >= 0x60u && ex <= 0x7Fu) ? 1 : 0;
    }
    atomicAdd(&s[0], c0); atomicAdd(&s[1], c1); atomicAdd(&s[2], c2);
    __syncthreads();
    if (threadIdx.x == 0) {
        flags[0] = (s[0] > 16) ? 1 : 0;
        flags[1] = (s[1] > 1024) ? 1 : 0;
        flags[2] = (s[2] > 3000) ? 1 : 0;
    }
}

__global__ __launch_bounds__(256) void hist_kept(const void* __restrict__ mask,
                                                 const int* __restrict__ rows,
                                                 const int* __restrict__ flags,
                                                 int* __restrict__ count) {
    int e = blockIdx.x * 256 + threadIdx.x;
    if (e >= NNZ) return;
    if (keepE(mask, e, flags[0])) atomicAdd(&count[rows[e]], 1);
}

__global__ __launch_bounds__(256) void scan_blocks(const int* __restrict__ count,
                                                   int* __restrict__ rowptr,
                                                   int* __restrict__ partials) {
    __shared__ int s[256];
    int i = blockIdx.x * 256 + threadIdx.x;
    int v = (i < NNODE) ? count[i] : 0;
    s[threadIdx.x] = v;
    __syncthreads();
    for (int off = 1; off < 256; off <<= 1) {
        int t = (threadIdx.x >= off) ? s[threadIdx.x - off] : 0;
        __syncthreads();
        s[threadIdx.x] += t;
        __syncthreads();
    }
    if (i < NNODE) rowptr[i + 1] = s[threadIdx.x];
    if (threadIdx.x == 255) partials[blockIdx.x] = s[255];
}

__global__ __launch_bounds__(1024) void scan_partials(int* __restrict__ partials) {
    __shared__ int s[1024];
    int v = (threadIdx.x < SCAN_BLOCKS) ? partials[threadIdx.x] : 0;
    s[threadIdx.x] = v;
    __syncthreads();
    for (int off = 1; off < 1024; off <<= 1) {
        int t = (threadIdx.x >= off) ? s[threadIdx.x - off] : 0;
        __syncthreads();
        s[threadIdx.x] += t;
        __syncthreads();
    }
    if (threadIdx.x < SCAN_BLOCKS) partials[threadIdx.x] = s[threadIdx.x] - v;
}

// rowptr[i+1] finalized; cursor[i] = rowptr[i] (scatter start positions)
__global__ __launch_bounds__(256) void add_back(int* __restrict__ rowptr,
                                                int* __restrict__ cursor,
                                                const int* __restrict__ partials) {
    int i = blockIdx.x * 256 + threadIdx.x;
    if (i >= NNODE) return;
    int v = rowptr[i + 1] + partials[blockIdx.x];
    rowptr[i + 1] = v;
    cursor[i + 1] = v;
    if (i == 0) { rowptr[0] = 0; cursor[0] = 0; }
}

// one packed 4B store per kept edge: col(18b) | ((e8-95)<<7 | m7) << 18
// val = 2*adj_val in (0,2] => f32 exponent e8 in [96,128], mantissa 7 bits exact.
__global__ __launch_bounds__(256) void scatter_csr(const void* __restrict__ mask,
                                                   const int* __restrict__ rows,
                                                   const int* __restrict__ cols,
                                                   const void* __restrict__ adjv,
                                                   const int* __restrict__ flags,
                                                   int* __restrict__ cursor,
                                                   unsigned* __restrict__ edges) {
    int e = blockIdx.x * 256 + threadIdx.x;
    if (e >= NNZ) return;
    if (!keepE(mask, e, flags[0])) return;
    int pos = atomicAdd(&cursor[rows[e]], 1);
    float v = 2.0f * loadF(adjv, e, flags[2]);     // 1/(1-0.5) rescale
    unsigned fb = __float_as_uint(v);
    unsigned e8 = (fb >> 23) & 0xFFu;              // [96,128]
    unsigned m7 = (fb >> 16) & 0x7Fu;
    edges[pos] = (unsigned)cols[e] | ((((e8 - 95u) << 7) | m7) << 18);
}

__device__ __forceinline__ float decodeV(unsigned code) {
    unsigned vb = code >> 18;                      // 13 bits
    return __uint_as_float((((vb >> 7) + 95u) << 23) | ((vb & 0x7Fu) << 16));
}

// A(bf16) = concat(user_emb, item_emb); thread = one us4 (4 dims)
__global__ __launch_bounds__(256) void concat_cast(const void* __restrict__ ue,
                                                   const void* __restrict__ ie,
                                                   const int* __restrict__ flags,
                                                   ushort* __restrict__ A) {
    long q = (long)blockIdx.x * 256 + threadIdx.x;   // us4 index
    const long NU4 = (long)NUSER * DIM / 4;
    const long NT4 = (long)NNODE * DIM / 4;
    if (q >= NT4) return;
    us4 o;
    if (!flags[2]) {
        const f4* s = (q < NU4) ? (const f4*)ue : (const f4*)ie;
        f4 v = s[(q < NU4) ? q : q - NU4];
        o[0] = f2bf(v.x); o[1] = f2bf(v.y); o[2] = f2bf(v.z); o[3] = f2bf(v.w);
    } else {
        const us4* s = (q < NU4) ? (const us4*)ue : (const us4*)ie;
        o = s[(q < NU4) ? q : q - NU4];
    }
    ((us4*)A)[q] = o;
}

// dst[r,:] = sum_j val[j] * src[col[j],:]   (src/dst bf16, acc f32)
// One 64-lane wave per row. lane = q*16 + t: quarter q handles edges
// j0+q, j0+q+4, ...; lane t covers dims [4t,4t+4) via one 8B ushort4 gather.
// Unroll-2 => 8 independent gathers in flight per wave.
__global__ __launch_bounds__(256) void spmm_csr(const ushort* __restrict__ src,
                                                const int* __restrict__ rowptr,
                                                const unsigned* __restrict__ edges,
                                                ushort* __restrict__ dst) {
    int r = blockIdx.x * 4 + (threadIdx.x >> 6);
    if (r >= NNODE) return;
    int lane = threadIdx.x & 63;
    int q = lane >> 4;
    int t = lane & 15;
    int j0 = rowptr[r], j1 = rowptr[r + 1];
    f4 acc = {0.0f, 0.0f, 0.0f, 0.0f};
    int j = j0 + q;
    for (; j + 4 < j1; j += 8) {
        unsigned e0 = edges[j];
        unsigned e1 = edges[j + 4];
        int c0 = (int)(e0 & 0x3FFFFu);
        int c1 = (int)(e1 & 0x3FFFFu);
        float v0 = decodeV(e0);
        float v1 = decodeV(e1);
        us4 s0 = ((const us4*)(src + (size_t)c0 * DIM))[t];
        us4 s1 = ((const us4*)(src + (size_t)c1 * DIM))[t];
        acc.x += v0 * bf2f(s0[0]); acc.y += v0 * bf2f(s0[1]);
        acc.z += v0 * bf2f(s0[2]); acc.w += v0 * bf2f(s0[3]);
        acc.x += v1 * bf2f(s1[0]); acc.y += v1 * bf2f(s1[1]);
        acc.z += v1 * bf2f(s1[2]); acc.w += v1 * bf2f(s1[3]);
    }
    if (j < j1) {
        unsigned e0 = edges[j];
        int c0 = (int)(e0 & 0x3FFFFu);
        float v0 = decodeV(e0);
        us4 s0 = ((const us4*)(src + (size_t)c0 * DIM))[t];
        acc.x += v0 * bf2f(s0[0]); acc.y += v0 * bf2f(s0[1]);
        acc.z += v0 * bf2f(s0[2]); acc.w += v0 * bf2f(s0[3]);
    }
    // reduce across quarters (lanes t, t+16, t+32, t+48)
    acc.x += __shfl_xor(acc.x, 16); acc.y += __shfl_xor(acc.y, 16);
    acc.z += __shfl_xor(acc.z, 16); acc.w += __shfl_xor(acc.w, 16);
    acc.x += __shfl_xor(acc.x, 32); acc.y += __shfl_xor(acc.y, 32);
    acc.z += __shfl_xor(acc.z, 32); acc.w += __shfl_xor(acc.w, 32);
    if (q == 0) {
        us4 o;
        o[0] = f2bf(acc.x); o[1] = f2bf(acc.y); o[2] = f2bf(acc.z); o[3] = f2bf(acc.w);
        __builtin_nontemporal_store(o, (us4*)(dst + (size_t)r * DIM) + t);
    }
}

__device__ __forceinline__ long nodeOf(int b, const int* users, const int* items, int sh) {
    if (b < BATCH) return (long)users[(size_t)b << sh];
    return (long)NUSER + (long)items[(size_t)(b - BATCH) << sh];
}

// acc[b,:] = table[node(b),:]        (first layer: store, saves memset+read)
__global__ __launch_bounds__(256) void gather_first(const ushort* __restrict__ table,
                                                    const int* __restrict__ users,
                                                    const int* __restrict__ items,
                                                    const int* __restrict__ flags,
                                                    float* __restrict__ acc) {
    int t = blockIdx.x * 256 + threadIdx.x;          // f4/us4 index
    if (t >= 2 * BATCH * DIM / 4) return;
    long node = nodeOf(t >> 4, users, items, flags[1]);
    us4 u = ((const us4*)(table + node * DIM))[t & 15];
    f4 a = {bf2f(u[0]), bf2f(u[1]), bf2f(u[2]), bf2f(u[3])};
    ((f4*)acc)[t] = a;
}

// acc[b,:] += table[node(b),:]
__global__ __launch_bounds__(256) void gather_add(const ushort* __restrict__ table,
                                                  const int* __restrict__ users,
                                                  const int* __restrict__ items,
                                                  const int* __restrict__ flags,
                                                  float* __restrict__ acc) {
    int t = blockIdx.x * 256 + threadIdx.x;
    if (t >= 2 * BATCH * DIM / 4) return;
    long node = nodeOf(t >> 4, users, items, flags[1]);
    us4 u = ((const us4*)(table + node * DIM))[t & 15];
    f4 a = ((f4*)acc)[t];
    a.x += bf2f(u[0]); a.y += bf2f(u[1]); a.z += bf2f(u[2]); a.w += bf2f(u[3]);
    ((f4*)acc)[t] = a;
}

// out = 0.25 * (acc + table[node])   (fused last gather + scale)
__global__ __launch_bounds__(256) void gather_final(const ushort* __restrict__ table,
                                                    const int* __restrict__ users,
                                                    const int* __restrict__ items,
                                                    const int* __restrict__ flags,
                                                    const float* __restrict__ acc,
                                                    float* __restrict__ out) {
    int t = blockIdx.x * 256 + threadIdx.x;
    if (t >= 2 * BATCH * DIM / 4) return;
    long node = nodeOf(t >> 4, users, items, flags[1]);
    us4 u = ((const us4*)(table + node * DIM))[t & 15];
    f4 a = ((const f4*)acc)[t];
    a.x = 0.25f * (a.x + bf2f(u[0]));
    a.y = 0.25f * (a.y + bf2f(u[1]));
    a.z = 0.25f * (a.z + bf2f(u[2]));
    a.w = 0.25f * (a.w + bf2f(u[3]));
    __builtin_nontemporal_store(a, (f4*)out + t);
}

extern "C" void kernel_launch(void* const* d_in, const int* in_sizes, int n_in,
                              void* d_out, int out_size, void* d_ws, size_t ws_size,
                              hipStream_t stream) {
    const void* user_emb = d_in[0];
    const void* item_emb = d_in[1];
    const void* adj_val  = d_in[2];
    const int*  adj_row  = (const int*)d_in[3];
    const int*  adj_col  = (const int*)d_in[4];
    const void* drop_msk = d_in[5];
    const int*  users    = (const int*)d_in[6];
    const int*  items    = (const int*)d_in[7];
    float* out = (float*)d_out;

    char* ws = (char*)d_ws;
    size_t off = 0;
    int* flags = (int*)(ws + off);            off += 256;
    float* out_acc = (float*)(ws + off);      off += (size_t)2 * BATCH * DIM * 4;   // 8 MB
    ushort* A = (ushort*)(ws + off);          off += (size_t)NNODE * DIM * 2;       // 19.2 MB
    ushort* B = (ushort*)(ws + off);          off += (size_t)NNODE * DIM * 2;       // 19.2 MB
    int* rowptr = (int*)(ws + off);           off += 600064;
    int* count = (int*)(ws + off);            off += 600064;
    int* cursor = (int*)(ws + off);           off += 600064;
    int* partials = (int*)(ws + off);         off += 4096;
    unsigned* edges = (unsigned*)(ws + off);  off += (size_t)NNZ * 4;               // 16 MB

    const int OUTN4 = 2 * BATCH * DIM / 4;            // 524288
    const int GOUT = (OUTN4 + 255) / 256;             // 2048
    const int GEDGE = (NNZ + 255) / 256;              // 15625

    (void)hipMemsetAsync(count, 0, (size_t)NNODE * 4, stream);

    detect_fmt<<<1, 256, 0, stream>>>((const unsigned int*)drop_msk,
                                      (const unsigned int*)users,
                                      (const unsigned int*)adj_val, flags);
    hist_kept<<<GEDGE, 256, 0, stream>>>(drop_msk, adj_row, flags, count);
    scan_blocks<<<SCAN_BLOCKS, 256, 0, stream>>>(count, rowptr, partials);
    scan_partials<<<1, 1024, 0, stream>>>(partials);
    add_back<<<SCAN_BLOCKS, 256, 0, stream>>>(rowptr, cursor, partials);
    scatter_csr<<<GEDGE, 256, 0, stream>>>(drop_msk, adj_row, adj_col, adj_val,
                                           flags, cursor, edges);
    concat_cast<<<((NNODE * DIM / 4) + 255) / 256, 256, 0, stream>>>(user_emb, item_emb,
                                                                     flags, A);
    gather_first<<<GOUT, 256, 0, stream>>>(A, users, items, flags, out_acc);

    ushort* src = A;
    ushort* dst = B;
    for (int l = 0; l < 3; ++l) {
        spmm_csr<<<(NNODE + 3) / 4, 256, 0, stream>>>(src, rowptr, edges, dst);
        if (l < 2) {
            gather_add<<<GOUT, 256, 0, stream>>>(dst, users, items, flags, out_acc);
        } else {
            gather_final<<<GOUT, 256, 0, stream>>>(dst, users, items, flags, out_acc, out);
        }
        ushort* t = src; src = dst; dst = t;
    }
}

// Round 8
// 380.107 us; speedup vs baseline: 7.0134x; 1.1507x over previous
//
#include <hip/hip_runtime.h>
#include <hip/hip_bf16.h>

// LightGCN encoder on MI355X.
// Device dtypes: user_emb/item_emb/adj_val = float32 (bf16-rounded values),
// adj_row/adj_col = int32, drop_mask = bool/int32 (runtime-detected),
// users/items = int64/int32 (runtime-detected), output = float32.
//
// Round-7 post-mortem: CSR build was op-count bound -- 2M random singleton
// stores (each dirtying a 64B line cross-XCD => WRITE_SIZE ~134MB no matter
// the record size) + 2x 2M random device atomics (cursor + hist).
// This version builds the CSR with a locality-controlled two-pass partition:
//   pass1: per-block LDS histogram over 147 coarse buckets (row>>10), ONE
//          global atomicAdd per (block,bucket) run reservation (~36K atomics),
//          then contiguous run fills (same-XCD L2 write-combining, ~1.2x amp).
//   pass2: one WG per bucket builds the bucket-local CSR in LDS (1024-row
//          hist+scan+scatter); random writes confined to an ~80KB L2-resident
//          region. Emits the same rowptr/edges format as round 7.
// SpMM (wave-per-row, quarter-wave ushort4 gathers, bf16 tables, f32 acc)
// and gather kernels are unchanged (proven at 437us).

#define NUSER 100000
#define NITEM 50000
#define NNODE 150000
#define DIM   64
#define NNZ   4000000
#define BATCH 16384

#define BSH2  10            // bucket = row >> 10
#define BRWS  1024          // rows per bucket
#define NBK   147           // ceil(150000/1024)
#define BCAP  24576         // records per bucket region (mean item bucket ~20.5K)
#define CHUNK 16384         // edges per pass1 block

typedef __hip_bfloat16 bf16;
typedef unsigned short ushort;
typedef unsigned long long u64;
typedef float f4 __attribute__((ext_vector_type(4)));
typedef ushort us4 __attribute__((ext_vector_type(4)));

__device__ __forceinline__ float loadF(const void* p, long i, int isbf16) {
    return isbf16 ? __bfloat162float(((const bf16*)p)[i]) : ((const float*)p)[i];
}

__device__ __forceinline__ bool keepE(const void* mask, int e, int isbyte) {
    return isbyte ? (((const unsigned char*)mask)[e] != 0)
                  : (((const int*)mask)[e] != 0);
}

__device__ __forceinline__ ushort f2bf(float x) {   // round-to-nearest-even
    unsigned u = __float_as_uint(x);
    return (ushort)((u + 0x7FFFu + ((u >> 16) & 1u)) >> 16);
}
__device__ __forceinline__ float bf2f(ushort u) {
    return __uint_as_float((unsigned)u << 16);
}

// val = 2*adj_val in (0,2]; exactly bf16 (inputs bf16-rounded, x2 = exp bump).
// 13-bit code: (e8-95)<<7 | m7.
__device__ __forceinline__ unsigned encodeV(float v) {
    unsigned fb = __float_as_uint(v);
    unsigned e8 = (fb >> 23) & 0xFFu;
    unsigned m7 = (fb >> 16) & 0x7Fu;
    return ((e8 - 95u) << 7) | m7;
}
__device__ __forceinline__ float decodeV(unsigned code) {
    unsigned vb = code >> 18;                      // 13 bits at [18,31)
    return __uint_as_float((((vb >> 7) + 95u) << 23) | ((vb & 0x7Fu) << 16));
}

// ---------------------------------------------------------------------------
// flags[0]: drop_mask is 1-byte. flags[1]: users/items are int64.
// flags[2]: float arrays are bf16 (insurance; expected 0 = f32).
__global__ __launch_bounds__(256) void detect_fmt(const unsigned int* __restrict__ mask,
                                                  const unsigned int* __restrict__ users,
                                                  const unsigned int* __restrict__ adjv,
                                                  int* __restrict__ flags) {
    __shared__ int s[3];
    if (threadIdx.x < 3) s[threadIdx.x] = 0;
    __syncthreads();
    int c0 = 0, c1 = 0, c2 = 0;
    for (int i = threadIdx.x; i < 4096; i += 256) {
        c0 += (mask[i] > 1u) ? 1 : 0;
        if (i & 1) c1 += (users[i] == 0u) ? 1 : 0;
        unsigned lo = adjv[i] & 0xFFFFu;
        unsigned ex = (lo >> 7) & 0xFFu;
        c2 += ((lo >> 15) == 0u && ex >= 0x60u && ex <= 0x7Fu) ? 1 : 0;
    }
    atomicAdd(&s[0], c0); atomicAdd(&s[1], c1); atomicAdd(&s[2], c2);
    __syncthreads();
    if (threadIdx.x == 0) {
        flags[0] = (s[0] > 16) ? 1 : 0;
        flags[1] = (s[1] > 1024) ? 1 : 0;
        flags[2] = (s[2] > 3000) ? 1 : 0;
    }
}

__global__ __launch_bounds__(256) void init_bcur(int* __restrict__ bcur) {
    for (int b = threadIdx.x; b < NBK; b += 256) bcur[b] = b * BCAP;
}

// pass1: partition kept edges into 147 bucket regions with run reservation.
// record u64 = r10(10b) | col(18b)<<10 | valcode(13b)<<28
__global__ __launch_bounds__(256) void pass1_partition(const void* __restrict__ mask,
                                                       const int* __restrict__ rows,
                                                       const int* __restrict__ cols,
                                                       const void* __restrict__ adjv,
                                                       const int* __restrict__ flags,
                                                       int* __restrict__ bcur,
                                                       u64* __restrict__ part) {
    __shared__ int cnt[NBK];
    __shared__ int cur[NBK];
    const int isbyte = flags[0];
    const int isbf = flags[2];
    const int base_e = blockIdx.x * CHUNK;

    for (int b = threadIdx.x; b < NBK; b += 256) cnt[b] = 0;
    __syncthreads();

    // phase A: count kept per bucket
    for (int i = threadIdx.x; i < CHUNK; i += 256) {
        int e = base_e + i;
        if (e >= NNZ) break;
        if (keepE(mask, e, isbyte)) atomicAdd(&cnt[rows[e] >> BSH2], 1);
    }
    __syncthreads();

    // phase B: reserve contiguous runs (one global atomic per nonzero bucket)
    for (int b = threadIdx.x; b < NBK; b += 256)
        cur[b] = cnt[b] ? atomicAdd(&bcur[b], cnt[b]) : 0;
    __syncthreads();

    // phase C: stream records into runs (chunk data is L2-hot from phase A)
    for (int i = threadIdx.x; i < CHUNK; i += 256) {
        int e = base_e + i;
        if (e >= NNZ) break;
        if (!keepE(mask, e, isbyte)) continue;
        int r = rows[e];
        int b = r >> BSH2;
        int pos = atomicAdd(&cur[b], 1);       // LDS atomic
        if (pos < (b + 1) * BCAP) {
            float v = 2.0f * loadF(adjv, e, isbf);
            u64 rec = (u64)(unsigned)(r & (BRWS - 1))
                    | ((u64)(unsigned)cols[e] << 10)
                    | ((u64)encodeV(v) << 28);
            part[pos] = rec;
        }
    }
}

// exclusive scan of bucket totals -> gbase; rowptr[0] = 0
__global__ __launch_bounds__(256) void bucket_scan(const int* __restrict__ bcur,
                                                   int* __restrict__ gbase,
                                                   int* __restrict__ rowptr) {
    __shared__ int s[256];
    int tid = threadIdx.x;
    int v = 0;
    if (tid < NBK) {
        v = bcur[tid] - tid * BCAP;
        if (v > BCAP) v = BCAP;
    }
    s[tid] = v;
    __syncthreads();
    for (int off = 1; off < 256; off <<= 1) {
        int t = (tid >= off) ? s[tid - off] : 0;
        __syncthreads();
        s[tid] += t;
        __syncthreads();
    }
    if (tid < NBK) gbase[tid] = s[tid] - v;
    if (tid == 0) rowptr[0] = 0;
}

// pass2: one WG per bucket -> bucket-local CSR (hist + scan + scatter in LDS).
// final edge u32 = col(18b) | valcode(13b)<<18  (round-7 spmm format)
__global__ __launch_bounds__(256) void pass2_csr(const u64* __restrict__ part,
                                                 const int* __restrict__ bcur,
                                                 const int* __restrict__ gbase,
                                                 unsigned* __restrict__ edges,
                                                 int* __restrict__ rowptr) {
    __shared__ int cnt[BRWS];
    __shared__ int ex[BRWS];
    __shared__ int wsum[256];
    int b = blockIdx.x;
    int tid = threadIdx.x;
    int n = bcur[b] - b * BCAP;
    if (n > BCAP) n = BCAP;
    const u64* rp = part + (size_t)b * BCAP;
    int gb = gbase[b];

    for (int i = tid; i < BRWS; i += 256) cnt[i] = 0;
    __syncthreads();
    for (int j = tid; j < n; j += 256)
        atomicAdd(&cnt[(int)(rp[j] & (BRWS - 1))], 1);
    __syncthreads();

    // scan: thread t owns rows [4t, 4t+4)
    int idx = tid * 4;
    int c0 = cnt[idx], c1 = cnt[idx + 1], c2 = cnt[idx + 2], c3 = cnt[idx + 3];
    int tsum = c0 + c1 + c2 + c3;
    wsum[tid] = tsum;
    __syncthreads();
    for (int off = 1; off < 256; off <<= 1) {
        int t = (tid >= off) ? wsum[tid - off] : 0;
        __syncthreads();
        wsum[tid] += t;
        __syncthreads();
    }
    int tbase = wsum[tid] - tsum;               // exclusive over threads
    ex[idx]     = tbase;
    ex[idx + 1] = tbase + c0;
    ex[idx + 2] = tbase + c0 + c1;
    ex[idx + 3] = tbase + c0 + c1 + c2;
    // global rowptr for the 4 owned rows
    int rbase = b << BSH2;
    int inc = tbase;
    if (rbase + idx < NNODE)     { inc += c0; rowptr[rbase + idx + 1] = gb + inc; }
    if (rbase + idx + 1 < NNODE) { inc += c1; rowptr[rbase + idx + 2] = gb + inc; }
    if (rbase + idx + 2 < NNODE) { inc += c2; rowptr[rbase + idx + 3] = gb + inc; }
    if (rbase + idx + 3 < NNODE) { inc += c3; rowptr[rbase + idx + 4] = gb + inc; }
    __syncthreads();

    // scatter into final CSR (ex doubles as per-row cursor)
    for (int j = tid; j < n; j += 256) {
        u64 rec = rp[j];
        int r = (int)(rec & (BRWS - 1));
        int pos = atomicAdd(&ex[r], 1);
        unsigned col = (unsigned)((rec >> 10) & 0x3FFFFu);
        unsigned code = (unsigned)((rec >> 28) & 0x1FFFu);
        edges[gb + pos] = col | (code << 18);
    }
}

// A(bf16) = concat(user_emb, item_emb); thread = one us4 (4 dims)
__global__ __launch_bounds__(256) void concat_cast(const void* __restrict__ ue,
                                                   const void* __restrict__ ie,
                                                   const int* __restrict__ flags,
                                                   ushort* __restrict__ A) {
    long q = (long)blockIdx.x * 256 + threadIdx.x;   // us4 index
    const long NU4 = (long)NUSER * DIM / 4;
    const long NT4 = (long)NNODE * DIM / 4;
    if (q >= NT4) return;
    us4 o;
    if (!flags[2]) {
        const f4* s = (q < NU4) ? (const f4*)ue : (const f4*)ie;
        f4 v = s[(q < NU4) ? q : q - NU4];
        o[0] = f2bf(v.x); o[1] = f2bf(v.y); o[2] = f2bf(v.z); o[3] = f2bf(v.w);
    } else {
        const us4* s = (q < NU4) ? (const us4*)ue : (const us4*)ie;
        o = s[(q < NU4) ? q : q - NU4];
    }
    ((us4*)A)[q] = o;
}

// dst[r,:] = sum_j val[j] * src[col[j],:]   (src/dst bf16, acc f32)
// One 64-lane wave per row; quarter q handles edges j0+q, j0+q+4, ...;
// lane t covers dims [4t,4t+4). Unroll-2 => 8 gathers in flight per wave.
__global__ __launch_bounds__(256) void spmm_csr(const ushort* __restrict__ src,
                                                const int* __restrict__ rowptr,
                                                const unsigned* __restrict__ edges,
                                                ushort* __restrict__ dst) {
    int r = blockIdx.x * 4 + (threadIdx.x >> 6);
    if (r >= NNODE) return;
    int lane = threadIdx.x & 63;
    int q = lane >> 4;
    int t = lane & 15;
    int j0 = rowptr[r], j1 = rowptr[r + 1];
    f4 acc = {0.0f, 0.0f, 0.0f, 0.0f};
    int j = j0 + q;
    for (; j + 4 < j1; j += 8) {
        unsigned e0 = edges[j];
        unsigned e1 = edges[j + 4];
        int c0 = (int)(e0 & 0x3FFFFu);
        int c1 = (int)(e1 & 0x3FFFFu);
        float v0 = decodeV(e0);
        float v1 = decodeV(e1);
        us4 s0 = ((const us4*)(src + (size_t)c0 * DIM))[t];
        us4 s1 = ((const us4*)(src + (size_t)c1 * DIM))[t];
        acc.x += v0 * bf2f(s0[0]); acc.y += v0 * bf2f(s0[1]);
        acc.z += v0 * bf2f(s0[2]); acc.w += v0 * bf2f(s0[3]);
        acc.x += v1 * bf2f(s1[0]); acc.y += v1 * bf2f(s1[1]);
        acc.z += v1 * bf2f(s1[2]); acc.w += v1 * bf2f(s1[3]);
    }
    if (j < j1) {
        unsigned e0 = edges[j];
        int c0 = (int)(e0 & 0x3FFFFu);
        float v0 = decodeV(e0);
        us4 s0 = ((const us4*)(src + (size_t)c0 * DIM))[t];
        acc.x += v0 * bf2f(s0[0]); acc.y += v0 * bf2f(s0[1]);
        acc.z += v0 * bf2f(s0[2]); acc.w += v0 * bf2f(s0[3]);
    }
    acc.x += __shfl_xor(acc.x, 16); acc.y += __shfl_xor(acc.y, 16);
    acc.z += __shfl_xor(acc.z, 16); acc.w += __shfl_xor(acc.w, 16);
    acc.x += __shfl_xor(acc.x, 32); acc.y += __shfl_xor(acc.y, 32);
    acc.z += __shfl_xor(acc.z, 32); acc.w += __shfl_xor(acc.w, 32);
    if (q == 0) {
        us4 o;
        o[0] = f2bf(acc.x); o[1] = f2bf(acc.y); o[2] = f2bf(acc.z); o[3] = f2bf(acc.w);
        __builtin_nontemporal_store(o, (us4*)(dst + (size_t)r * DIM) + t);
    }
}

__device__ __forceinline__ long nodeOf(int b, const int* users, const int* items, int sh) {
    if (b < BATCH) return (long)users[(size_t)b << sh];
    return (long)NUSER + (long)items[(size_t)(b - BATCH) << sh];
}

// acc[b,:] = table[node(b),:]
__global__ __launch_bounds__(256) void gather_first(const ushort* __restrict__ table,
                                                    const int* __restrict__ users,
                                                    const int* __restrict__ items,
                                                    const int* __restrict__ flags,
                                                    float* __restrict__ acc) {
    int t = blockIdx.x * 256 + threadIdx.x;          // f4/us4 index
    if (t >= 2 * BATCH * DIM / 4) return;
    long node = nodeOf(t >> 4, users, items, flags[1]);
    us4 u = ((const us4*)(table + node * DIM))[t & 15];
    f4 a = {bf2f(u[0]), bf2f(u[1]), bf2f(u[2]), bf2f(u[3])};
    ((f4*)acc)[t] = a;
}

// acc[b,:] += table[node(b),:]
__global__ __launch_bounds__(256) void gather_add(const ushort* __restrict__ table,
                                                  const int* __restrict__ users,
                                                  const int* __restrict__ items,
                                                  const int* __restrict__ flags,
                                                  float* __restrict__ acc) {
    int t = blockIdx.x * 256 + threadIdx.x;
    if (t >= 2 * BATCH * DIM / 4) return;
    long node = nodeOf(t >> 4, users, items, flags[1]);
    us4 u = ((const us4*)(table + node * DIM))[t & 15];
    f4 a = ((f4*)acc)[t];
    a.x += bf2f(u[0]); a.y += bf2f(u[1]); a.z += bf2f(u[2]); a.w += bf2f(u[3]);
    ((f4*)acc)[t] = a;
}

// out = 0.25 * (acc + table[node])
__global__ __launch_bounds__(256) void gather_final(const ushort* __restrict__ table,
                                                    const int* __restrict__ users,
                                                    const int* __restrict__ items,
                                                    const int* __restrict__ flags,
                                                    const float* __restrict__ acc,
                                                    float* __restrict__ out) {
    int t = blockIdx.x * 256 + threadIdx.x;
    if (t >= 2 * BATCH * DIM / 4) return;
    long node = nodeOf(t >> 4, users, items, flags[1]);
    us4 u = ((const us4*)(table + node * DIM))[t & 15];
    f4 a = ((const f4*)acc)[t];
    a.x = 0.25f * (a.x + bf2f(u[0]));
    a.y = 0.25f * (a.y + bf2f(u[1]));
    a.z = 0.25f * (a.z + bf2f(u[2]));
    a.w = 0.25f * (a.w + bf2f(u[3]));
    __builtin_nontemporal_store(a, (f4*)out + t);
}

extern "C" void kernel_launch(void* const* d_in, const int* in_sizes, int n_in,
                              void* d_out, int out_size, void* d_ws, size_t ws_size,
                              hipStream_t stream) {
    const void* user_emb = d_in[0];
    const void* item_emb = d_in[1];
    const void* adj_val  = d_in[2];
    const int*  adj_row  = (const int*)d_in[3];
    const int*  adj_col  = (const int*)d_in[4];
    const void* drop_msk = d_in[5];
    const int*  users    = (const int*)d_in[6];
    const int*  items    = (const int*)d_in[7];
    float* out = (float*)d_out;

    char* ws = (char*)d_ws;
    size_t off = 0;
    int* flags = (int*)(ws + off);            off += 256;
    float* out_acc = (float*)(ws + off);      off += (size_t)2 * BATCH * DIM * 4;   // 8 MB
    ushort* A = (ushort*)(ws + off);          off += (size_t)NNODE * DIM * 2;       // 19.2 MB
    ushort* B = (ushort*)(ws + off);          off += (size_t)NNODE * DIM * 2;       // 19.2 MB
    int* rowptr = (int*)(ws + off);           off += 600064;                        // NNODE+1
    int* bcur = (int*)(ws + off);             off += 1024;
    int* gbase = (int*)(ws + off);            off += 1024;
    u64* part = (u64*)(ws + off);             off += (size_t)NBK * BCAP * 8;        // 28.9 MB
    unsigned* edges = (unsigned*)(ws + off);  off += (size_t)NNZ * 4;               // 16 MB

    const int OUTN4 = 2 * BATCH * DIM / 4;            // 524288
    const int GOUT = (OUTN4 + 255) / 256;             // 2048
    const int GP1 = (NNZ + CHUNK - 1) / CHUNK;        // 245

    detect_fmt<<<1, 256, 0, stream>>>((const unsigned int*)drop_msk,
                                      (const unsigned int*)users,
                                      (const unsigned int*)adj_val, flags);
    init_bcur<<<1, 256, 0, stream>>>(bcur);
    pass1_partition<<<GP1, 256, 0, stream>>>(drop_msk, adj_row, adj_col, adj_val,
                                             flags, bcur, part);
    bucket_scan<<<1, 256, 0, stream>>>(bcur, gbase, rowptr);
    pass2_csr<<<NBK, 256, 0, stream>>>(part, bcur, gbase, edges, rowptr);
    concat_cast<<<((NNODE * DIM / 4) + 255) / 256, 256, 0, stream>>>(user_emb, item_emb,
                                                                     flags, A);
    gather_first<<<GOUT, 256, 0, stream>>>(A, users, items, flags, out_acc);

    ushort* src = A;
    ushort* dst = B;
    for (int l = 0; l < 3; ++l) {
        spmm_csr<<<(NNODE + 3) / 4, 256, 0, stream>>>(src, rowptr, edges, dst);
        if (l < 2) {
            gather_add<<<GOUT, 256, 0, stream>>>(dst, users, items, flags, out_acc);
        } else {
            gather_final<<<GOUT, 256, 0, stream>>>(dst, users, items, flags, out_acc, out);
        }
        ushort* t = src; src = dst; dst = t;
    }
}

// Round 9
// 342.577 us; speedup vs baseline: 7.7818x; 1.1096x over previous
//
#include <hip/hip_runtime.h>
#include <hip/hip_bf16.h>

// LightGCN encoder on MI355X.
// Device dtypes: user_emb/item_emb/adj_val = float32 (bf16-rounded values),
// adj_row/adj_col = int32, drop_mask = bool/int32 (runtime-detected),
// users/items = int64/int32 (runtime-detected), output = float32.
//
// Round-8 post-mortem: two-pass partition fixed write amplification
// (WRITE 134->16 MB) but pass1 ran at 10.5% occupancy (245 blocks on 256
// CUs) -> 140 us of pure latency. Round 9: CHUNK 16384->2048 (1954 blocks,
// ~8 blocks/CU); run-reservation atomics grow to ~287K over 147 independent
// addresses (pipelined fetch-add, negligible). SpMM inner loop unroll 2->4
// (16 independent ushort4 gathers in flight per wave).

#define NUSER 100000
#define NITEM 50000
#define NNODE 150000
#define DIM   64
#define NNZ   4000000
#define BATCH 16384

#define BSH2  10            // bucket = row >> 10
#define BRWS  1024          // rows per bucket
#define NBK   147           // ceil(150000/1024)
#define BCAP  24576         // records per bucket region (mean item bucket ~20.5K)
#define CHUNK 2048          // edges per pass1 block

typedef __hip_bfloat16 bf16;
typedef unsigned short ushort;
typedef unsigned long long u64;
typedef float f4 __attribute__((ext_vector_type(4)));
typedef ushort us4 __attribute__((ext_vector_type(4)));

__device__ __forceinline__ float loadF(const void* p, long i, int isbf16) {
    return isbf16 ? __bfloat162float(((const bf16*)p)[i]) : ((const float*)p)[i];
}

__device__ __forceinline__ bool keepE(const void* mask, int e, int isbyte) {
    return isbyte ? (((const unsigned char*)mask)[e] != 0)
                  : (((const int*)mask)[e] != 0);
}

__device__ __forceinline__ ushort f2bf(float x) {   // round-to-nearest-even
    unsigned u = __float_as_uint(x);
    return (ushort)((u + 0x7FFFu + ((u >> 16) & 1u)) >> 16);
}
__device__ __forceinline__ float bf2f(ushort u) {
    return __uint_as_float((unsigned)u << 16);
}

// val = 2*adj_val in (0,2]; exactly bf16 (inputs bf16-rounded, x2 = exp bump).
// 13-bit code: (e8-95)<<7 | m7.
__device__ __forceinline__ unsigned encodeV(float v) {
    unsigned fb = __float_as_uint(v);
    unsigned e8 = (fb >> 23) & 0xFFu;
    unsigned m7 = (fb >> 16) & 0x7Fu;
    return ((e8 - 95u) << 7) | m7;
}
__device__ __forceinline__ float decodeV(unsigned code) {
    unsigned vb = code >> 18;                      // 13 bits at [18,31)
    return __uint_as_float((((vb >> 7) + 95u) << 23) | ((vb & 0x7Fu) << 16));
}

// ---------------------------------------------------------------------------
// flags[0]: drop_mask is 1-byte. flags[1]: users/items are int64.
// flags[2]: float arrays are bf16 (insurance; expected 0 = f32).
__global__ __launch_bounds__(256) void detect_fmt(const unsigned int* __restrict__ mask,
                                                  const unsigned int* __restrict__ users,
                                                  const unsigned int* __restrict__ adjv,
                                                  int* __restrict__ flags) {
    __shared__ int s[3];
    if (threadIdx.x < 3) s[threadIdx.x] = 0;
    __syncthreads();
    int c0 = 0, c1 = 0, c2 = 0;
    for (int i = threadIdx.x; i < 4096; i += 256) {
        c0 += (mask[i] > 1u) ? 1 : 0;
        if (i & 1) c1 += (users[i] == 0u) ? 1 : 0;
        unsigned lo = adjv[i] & 0xFFFFu;
        unsigned ex = (lo >> 7) & 0xFFu;
        c2 += ((lo >> 15) == 0u && ex >= 0x60u && ex <= 0x7Fu) ? 1 : 0;
    }
    atomicAdd(&s[0], c0); atomicAdd(&s[1], c1); atomicAdd(&s[2], c2);
    __syncthreads();
    if (threadIdx.x == 0) {
        flags[0] = (s[0] > 16) ? 1 : 0;
        flags[1] = (s[1] > 1024) ? 1 : 0;
        flags[2] = (s[2] > 3000) ? 1 : 0;
    }
}

__global__ __launch_bounds__(256) void init_bcur(int* __restrict__ bcur) {
    for (int b = threadIdx.x; b < NBK; b += 256) bcur[b] = b * BCAP;
}

// pass1: partition kept edges into 147 bucket regions with run reservation.
// record u64 = r10(10b) | col(18b)<<10 | valcode(13b)<<28
__global__ __launch_bounds__(256) void pass1_partition(const void* __restrict__ mask,
                                                       const int* __restrict__ rows,
                                                       const int* __restrict__ cols,
                                                       const void* __restrict__ adjv,
                                                       const int* __restrict__ flags,
                                                       int* __restrict__ bcur,
                                                       u64* __restrict__ part) {
    __shared__ int cnt[NBK];
    __shared__ int cur[NBK];
    const int isbyte = flags[0];
    const int isbf = flags[2];
    const int base_e = blockIdx.x * CHUNK;

    for (int b = threadIdx.x; b < NBK; b += 256) cnt[b] = 0;
    __syncthreads();

    // phase A: count kept per bucket
    for (int i = threadIdx.x; i < CHUNK; i += 256) {
        int e = base_e + i;
        if (e >= NNZ) break;
        if (keepE(mask, e, isbyte)) atomicAdd(&cnt[rows[e] >> BSH2], 1);
    }
    __syncthreads();

    // phase B: reserve contiguous runs (one global atomic per nonzero bucket)
    for (int b = threadIdx.x; b < NBK; b += 256)
        cur[b] = cnt[b] ? atomicAdd(&bcur[b], cnt[b]) : 0;
    __syncthreads();

    // phase C: stream records into runs (chunk data is L2-hot from phase A)
    for (int i = threadIdx.x; i < CHUNK; i += 256) {
        int e = base_e + i;
        if (e >= NNZ) break;
        if (!keepE(mask, e, isbyte)) continue;
        int r = rows[e];
        int b = r >> BSH2;
        int pos = atomicAdd(&cur[b], 1);       // LDS atomic
        if (pos < (b + 1) * BCAP) {
            float v = 2.0f * loadF(adjv, e, isbf);
            u64 rec = (u64)(unsigned)(r & (BRWS - 1))
                    | ((u64)(unsigned)cols[e] << 10)
                    | ((u64)encodeV(v) << 28);
            part[pos] = rec;
        }
    }
}

// exclusive scan of bucket totals -> gbase; rowptr[0] = 0
__global__ __launch_bounds__(256) void bucket_scan(const int* __restrict__ bcur,
                                                   int* __restrict__ gbase,
                                                   int* __restrict__ rowptr) {
    __shared__ int s[256];
    int tid = threadIdx.x;
    int v = 0;
    if (tid < NBK) {
        v = bcur[tid] - tid * BCAP;
        if (v > BCAP) v = BCAP;
    }
    s[tid] = v;
    __syncthreads();
    for (int off = 1; off < 256; off <<= 1) {
        int t = (tid >= off) ? s[tid - off] : 0;
        __syncthreads();
        s[tid] += t;
        __syncthreads();
    }
    if (tid < NBK) gbase[tid] = s[tid] - v;
    if (tid == 0) rowptr[0] = 0;
}

// pass2: one WG per bucket -> bucket-local CSR (hist + scan + scatter in LDS).
// final edge u32 = col(18b) | valcode(13b)<<18
__global__ __launch_bounds__(256) void pass2_csr(const u64* __restrict__ part,
                                                 const int* __restrict__ bcur,
                                                 const int* __restrict__ gbase,
                                                 unsigned* __restrict__ edges,
                                                 int* __restrict__ rowptr) {
    __shared__ int cnt[BRWS];
    __shared__ int ex[BRWS];
    __shared__ int wsum[256];
    int b = blockIdx.x;
    int tid = threadIdx.x;
    int n = bcur[b] - b * BCAP;
    if (n > BCAP) n = BCAP;
    const u64* rp = part + (size_t)b * BCAP;
    int gb = gbase[b];

    for (int i = tid; i < BRWS; i += 256) cnt[i] = 0;
    __syncthreads();
    for (int j = tid; j < n; j += 256)
        atomicAdd(&cnt[(int)(rp[j] & (BRWS - 1))], 1);
    __syncthreads();

    // scan: thread t owns rows [4t, 4t+4)
    int idx = tid * 4;
    int c0 = cnt[idx], c1 = cnt[idx + 1], c2 = cnt[idx + 2], c3 = cnt[idx + 3];
    int tsum = c0 + c1 + c2 + c3;
    wsum[tid] = tsum;
    __syncthreads();
    for (int off = 1; off < 256; off <<= 1) {
        int t = (tid >= off) ? wsum[tid - off] : 0;
        __syncthreads();
        wsum[tid] += t;
        __syncthreads();
    }
    int tbase = wsum[tid] - tsum;               // exclusive over threads
    ex[idx]     = tbase;
    ex[idx + 1] = tbase + c0;
    ex[idx + 2] = tbase + c0 + c1;
    ex[idx + 3] = tbase + c0 + c1 + c2;
    // global rowptr for the 4 owned rows
    int rbase = b << BSH2;
    int inc = tbase;
    if (rbase + idx < NNODE)     { inc += c0; rowptr[rbase + idx + 1] = gb + inc; }
    if (rbase + idx + 1 < NNODE) { inc += c1; rowptr[rbase + idx + 2] = gb + inc; }
    if (rbase + idx + 2 < NNODE) { inc += c2; rowptr[rbase + idx + 3] = gb + inc; }
    if (rbase + idx + 3 < NNODE) { inc += c3; rowptr[rbase + idx + 4] = gb + inc; }
    __syncthreads();

    // scatter into final CSR (ex doubles as per-row cursor)
    for (int j = tid; j < n; j += 256) {
        u64 rec = rp[j];
        int r = (int)(rec & (BRWS - 1));
        int pos = atomicAdd(&ex[r], 1);
        unsigned col = (unsigned)((rec >> 10) & 0x3FFFFu);
        unsigned code = (unsigned)((rec >> 28) & 0x1FFFu);
        edges[gb + pos] = col | (code << 18);
    }
}

// A(bf16) = concat(user_emb, item_emb); thread = one us4 (4 dims)
__global__ __launch_bounds__(256) void concat_cast(const void* __restrict__ ue,
                                                   const void* __restrict__ ie,
                                                   const int* __restrict__ flags,
                                                   ushort* __restrict__ A) {
    long q = (long)blockIdx.x * 256 + threadIdx.x;   // us4 index
    const long NU4 = (long)NUSER * DIM / 4;
    const long NT4 = (long)NNODE * DIM / 4;
    if (q >= NT4) return;
    us4 o;
    if (!flags[2]) {
        const f4* s = (q < NU4) ? (const f4*)ue : (const f4*)ie;
        f4 v = s[(q < NU4) ? q : q - NU4];
        o[0] = f2bf(v.x); o[1] = f2bf(v.y); o[2] = f2bf(v.z); o[3] = f2bf(v.w);
    } else {
        const us4* s = (q < NU4) ? (const us4*)ue : (const us4*)ie;
        o = s[(q < NU4) ? q : q - NU4];
    }
    ((us4*)A)[q] = o;
}

// dst[r,:] = sum_j val[j] * src[col[j],:]   (src/dst bf16, acc f32)
// One 64-lane wave per row; quarter q handles edges j0+q, j0+q+4, ...;
// lane t covers dims [4t,4t+4). Unroll-4 => 16 gathers in flight per wave.
__global__ __launch_bounds__(256) void spmm_csr(const ushort* __restrict__ src,
                                                const int* __restrict__ rowptr,
                                                const unsigned* __restrict__ edges,
                                                ushort* __restrict__ dst) {
    int r = blockIdx.x * 4 + (threadIdx.x >> 6);
    if (r >= NNODE) return;
    int lane = threadIdx.x & 63;
    int q = lane >> 4;
    int t = lane & 15;
    int j0 = rowptr[r], j1 = rowptr[r + 1];
    f4 acc = {0.0f, 0.0f, 0.0f, 0.0f};
    int j = j0 + q;
    for (; j + 12 < j1; j += 16) {
        unsigned e0 = edges[j];
        unsigned e1 = edges[j + 4];
        unsigned e2 = edges[j + 8];
        unsigned e3 = edges[j + 12];
        int c0 = (int)(e0 & 0x3FFFFu);
        int c1 = (int)(e1 & 0x3FFFFu);
        int c2 = (int)(e2 & 0x3FFFFu);
        int c3 = (int)(e3 & 0x3FFFFu);
        float v0 = decodeV(e0);
        float v1 = decodeV(e1);
        float v2 = decodeV(e2);
        float v3 = decodeV(e3);
        us4 s0 = ((const us4*)(src + (size_t)c0 * DIM))[t];
        us4 s1 = ((const us4*)(src + (size_t)c1 * DIM))[t];
        us4 s2 = ((const us4*)(src + (size_t)c2 * DIM))[t];
        us4 s3 = ((const us4*)(src + (size_t)c3 * DIM))[t];
        acc.x += v0 * bf2f(s0[0]); acc.y += v0 * bf2f(s0[1]);
        acc.z += v0 * bf2f(s0[2]); acc.w += v0 * bf2f(s0[3]);
        acc.x += v1 * bf2f(s1[0]); acc.y += v1 * bf2f(s1[1]);
        acc.z += v1 * bf2f(s1[2]); acc.w += v1 * bf2f(s1[3]);
        acc.x += v2 * bf2f(s2[0]); acc.y += v2 * bf2f(s2[1]);
        acc.z += v2 * bf2f(s2[2]); acc.w += v2 * bf2f(s2[3]);
        acc.x += v3 * bf2f(s3[0]); acc.y += v3 * bf2f(s3[1]);
        acc.z += v3 * bf2f(s3[2]); acc.w += v3 * bf2f(s3[3]);
    }
    for (; j < j1; j += 4) {
        unsigned e0 = edges[j];
        int c0 = (int)(e0 & 0x3FFFFu);
        float v0 = decodeV(e0);
        us4 s0 = ((const us4*)(src + (size_t)c0 * DIM))[t];
        acc.x += v0 * bf2f(s0[0]); acc.y += v0 * bf2f(s0[1]);
        acc.z += v0 * bf2f(s0[2]); acc.w += v0 * bf2f(s0[3]);
    }
    acc.x += __shfl_xor(acc.x, 16); acc.y += __shfl_xor(acc.y, 16);
    acc.z += __shfl_xor(acc.z, 16); acc.w += __shfl_xor(acc.w, 16);
    acc.x += __shfl_xor(acc.x, 32); acc.y += __shfl_xor(acc.y, 32);
    acc.z += __shfl_xor(acc.z, 32); acc.w += __shfl_xor(acc.w, 32);
    if (q == 0) {
        us4 o;
        o[0] = f2bf(acc.x); o[1] = f2bf(acc.y); o[2] = f2bf(acc.z); o[3] = f2bf(acc.w);
        __builtin_nontemporal_store(o, (us4*)(dst + (size_t)r * DIM) + t);
    }
}

__device__ __forceinline__ long nodeOf(int b, const int* users, const int* items, int sh) {
    if (b < BATCH) return (long)users[(size_t)b << sh];
    return (long)NUSER + (long)items[(size_t)(b - BATCH) << sh];
}

// acc[b,:] = table[node(b),:]
__global__ __launch_bounds__(256) void gather_first(const ushort* __restrict__ table,
                                                    const int* __restrict__ users,
                                                    const int* __restrict__ items,
                                                    const int* __restrict__ flags,
                                                    float* __restrict__ acc) {
    int t = blockIdx.x * 256 + threadIdx.x;          // f4/us4 index
    if (t >= 2 * BATCH * DIM / 4) return;
    long node = nodeOf(t >> 4, users, items, flags[1]);
    us4 u = ((const us4*)(table + node * DIM))[t & 15];
    f4 a = {bf2f(u[0]), bf2f(u[1]), bf2f(u[2]), bf2f(u[3])};
    ((f4*)acc)[t] = a;
}

// acc[b,:] += table[node(b),:]
__global__ __launch_bounds__(256) void gather_add(const ushort* __restrict__ table,
                                                  const int* __restrict__ users,
                                                  const int* __restrict__ items,
                                                  const int* __restrict__ flags,
                                                  float* __restrict__ acc) {
    int t = blockIdx.x * 256 + threadIdx.x;
    if (t >= 2 * BATCH * DIM / 4) return;
    long node = nodeOf(t >> 4, users, items, flags[1]);
    us4 u = ((const us4*)(table + node * DIM))[t & 15];
    f4 a = ((f4*)acc)[t];
    a.x += bf2f(u[0]); a.y += bf2f(u[1]); a.z += bf2f(u[2]); a.w += bf2f(u[3]);
    ((f4*)acc)[t] = a;
}

// out = 0.25 * (acc + table[node])
__global__ __launch_bounds__(256) void gather_final(const ushort* __restrict__ table,
                                                    const int* __restrict__ users,
                                                    const int* __restrict__ items,
                                                    const int* __restrict__ flags,
                                                    const float* __restrict__ acc,
                                                    float* __restrict__ out) {
    int t = blockIdx.x * 256 + threadIdx.x;
    if (t >= 2 * BATCH * DIM / 4) return;
    long node = nodeOf(t >> 4, users, items, flags[1]);
    us4 u = ((const us4*)(table + node * DIM))[t & 15];
    f4 a = ((const f4*)acc)[t];
    a.x = 0.25f * (a.x + bf2f(u[0]));
    a.y = 0.25f * (a.y + bf2f(u[1]));
    a.z = 0.25f * (a.z + bf2f(u[2]));
    a.w = 0.25f * (a.w + bf2f(u[3]));
    __builtin_nontemporal_store(a, (f4*)out + t);
}

extern "C" void kernel_launch(void* const* d_in, const int* in_sizes, int n_in,
                              void* d_out, int out_size, void* d_ws, size_t ws_size,
                              hipStream_t stream) {
    const void* user_emb = d_in[0];
    const void* item_emb = d_in[1];
    const void* adj_val  = d_in[2];
    const int*  adj_row  = (const int*)d_in[3];
    const int*  adj_col  = (const int*)d_in[4];
    const void* drop_msk = d_in[5];
    const int*  users    = (const int*)d_in[6];
    const int*  items    = (const int*)d_in[7];
    float* out = (float*)d_out;

    char* ws = (char*)d_ws;
    size_t off = 0;
    int* flags = (int*)(ws + off);            off += 256;
    float* out_acc = (float*)(ws + off);      off += (size_t)2 * BATCH * DIM * 4;   // 8 MB
    ushort* A = (ushort*)(ws + off);          off += (size_t)NNODE * DIM * 2;       // 19.2 MB
    ushort* B = (ushort*)(ws + off);          off += (size_t)NNODE * DIM * 2;       // 19.2 MB
    int* rowptr = (int*)(ws + off);           off += 600064;                        // NNODE+1
    int* bcur = (int*)(ws + off);             off += 1024;
    int* gbase = (int*)(ws + off);            off += 1024;
    u64* part = (u64*)(ws + off);             off += (size_t)NBK * BCAP * 8;        // 28.9 MB
    unsigned* edges = (unsigned*)(ws + off);  off += (size_t)NNZ * 4;               // 16 MB

    const int OUTN4 = 2 * BATCH * DIM / 4;            // 524288
    const int GOUT = (OUTN4 + 255) / 256;             // 2048
    const int GP1 = (NNZ + CHUNK - 1) / CHUNK;        // 1954

    detect_fmt<<<1, 256, 0, stream>>>((const unsigned int*)drop_msk,
                                      (const unsigned int*)users,
                                      (const unsigned int*)adj_val, flags);
    init_bcur<<<1, 256, 0, stream>>>(bcur);
    pass1_partition<<<GP1, 256, 0, stream>>>(drop_msk, adj_row, adj_col, adj_val,
                                             flags, bcur, part);
    bucket_scan<<<1, 256, 0, stream>>>(bcur, gbase, rowptr);
    pass2_csr<<<NBK, 256, 0, stream>>>(part, bcur, gbase, edges, rowptr);
    concat_cast<<<((NNODE * DIM / 4) + 255) / 256, 256, 0, stream>>>(user_emb, item_emb,
                                                                     flags, A);
    gather_first<<<GOUT, 256, 0, stream>>>(A, users, items, flags, out_acc);

    ushort* src = A;
    ushort* dst = B;
    for (int l = 0; l < 3; ++l) {
        spmm_csr<<<(NNODE + 3) / 4, 256, 0, stream>>>(src, rowptr, edges, dst);
        if (l < 2) {
            gather_add<<<GOUT, 256, 0, stream>>>(dst, users, items, flags, out_acc);
        } else {
            gather_final<<<GOUT, 256, 0, stream>>>(dst, users, items, flags, out_acc, out);
        }
        ushort* t = src; src = dst; dst = t;
    }
}

// Round 10
// 329.820 us; speedup vs baseline: 8.0828x; 1.0387x over previous
//
#include <hip/hip_runtime.h>
#include <hip/hip_bf16.h>

// LightGCN encoder on MI355X.
// Device dtypes: user_emb/item_emb/adj_val = float32 (bf16-rounded values),
// adj_row/adj_col = int32, drop_mask = bool/int32 (runtime-detected),
// users/items = int64/int32 (runtime-detected), output = float32.
//
// Round-9 post-mortem: pass1 re-read all edge arrays in phase C (96 MB issued
// for a 64 MB problem) and pass2 ran 147 blocks (0.57/CU, half machine idle).
// Round 10: pass1 builds records in registers during ONE read pass (phase C =
// LDS fetch-add + store only); buckets shrink to 512 rows (293 blocks x 512
// threads in pass2, thread = row); spmm unroll 4->8.

#define NUSER 100000
#define NITEM 50000
#define NNODE 150000
#define DIM   64
#define NNZ   4000000
#define BATCH 16384

#define BSH2  9             // bucket = row >> 9
#define BRWS  512           // rows per bucket
#define NBK   293           // ceil(150000/512)
#define BCAP  12288         // records per bucket region (mean item bucket ~10.2K)
#define CHUNK 2048          // edges per pass1 block (8 per thread)

typedef __hip_bfloat16 bf16;
typedef unsigned short ushort;
typedef unsigned long long u64;
typedef float f4 __attribute__((ext_vector_type(4)));
typedef ushort us4 __attribute__((ext_vector_type(4)));

__device__ __forceinline__ float loadF(const void* p, long i, int isbf16) {
    return isbf16 ? __bfloat162float(((const bf16*)p)[i]) : ((const float*)p)[i];
}

__device__ __forceinline__ bool keepE(const void* mask, int e, int isbyte) {
    return isbyte ? (((const unsigned char*)mask)[e] != 0)
                  : (((const int*)mask)[e] != 0);
}

__device__ __forceinline__ ushort f2bf(float x) {   // round-to-nearest-even
    unsigned u = __float_as_uint(x);
    return (ushort)((u + 0x7FFFu + ((u >> 16) & 1u)) >> 16);
}
__device__ __forceinline__ float bf2f(ushort u) {
    return __uint_as_float((unsigned)u << 16);
}

// val = 2*adj_val in (0,2]; exactly bf16 (inputs bf16-rounded, x2 = exp bump).
// 13-bit code: (e8-95)<<7 | m7.
__device__ __forceinline__ unsigned encodeV(float v) {
    unsigned fb = __float_as_uint(v);
    unsigned e8 = (fb >> 23) & 0xFFu;
    unsigned m7 = (fb >> 16) & 0x7Fu;
    return ((e8 - 95u) << 7) | m7;
}
__device__ __forceinline__ float decodeV(unsigned code) {
    unsigned vb = code >> 18;                      // 13 bits at [18,31)
    return __uint_as_float((((vb >> 7) + 95u) << 23) | ((vb & 0x7Fu) << 16));
}

// ---------------------------------------------------------------------------
// flags[0]: drop_mask is 1-byte. flags[1]: users/items are int64.
// flags[2]: float arrays are bf16 (insurance; expected 0 = f32).
__global__ __launch_bounds__(256) void detect_fmt(const unsigned int* __restrict__ mask,
                                                  const unsigned int* __restrict__ users,
                                                  const unsigned int* __restrict__ adjv,
                                                  int* __restrict__ flags) {
    __shared__ int s[3];
    if (threadIdx.x < 3) s[threadIdx.x] = 0;
    __syncthreads();
    int c0 = 0, c1 = 0, c2 = 0;
    for (int i = threadIdx.x; i < 4096; i += 256) {
        c0 += (mask[i] > 1u) ? 1 : 0;
        if (i & 1) c1 += (users[i] == 0u) ? 1 : 0;
        unsigned lo = adjv[i] & 0xFFFFu;
        unsigned ex = (lo >> 7) & 0xFFu;
        c2 += ((lo >> 15) == 0u && ex >= 0x60u && ex <= 0x7Fu) ? 1 : 0;
    }
    atomicAdd(&s[0], c0); atomicAdd(&s[1], c1); atomicAdd(&s[2], c2);
    __syncthreads();
    if (threadIdx.x == 0) {
        flags[0] = (s[0] > 16) ? 1 : 0;
        flags[1] = (s[1] > 1024) ? 1 : 0;
        flags[2] = (s[2] > 3000) ? 1 : 0;
    }
}

__global__ __launch_bounds__(256) void init_bcur(int* __restrict__ bcur) {
    for (int b = threadIdx.x; b < NBK; b += 256) bcur[b] = b * BCAP;
}

// pass1: one read pass; records built in registers (8 edges/thread, full
// unroll -> register-resident), then LDS fetch-add + store per kept edge.
// record u64 = r9(9b) | col(18b)<<9 | valcode(13b)<<27
__global__ __launch_bounds__(256) void pass1_partition(const void* __restrict__ mask,
                                                       const int* __restrict__ rows,
                                                       const int* __restrict__ cols,
                                                       const void* __restrict__ adjv,
                                                       const int* __restrict__ flags,
                                                       int* __restrict__ bcur,
                                                       u64* __restrict__ part) {
    __shared__ int cnt[NBK];
    __shared__ int cur[NBK];
    const int isbyte = flags[0];
    const int isbf = flags[2];
    const int base_e = blockIdx.x * CHUNK;
    u64 rec[8];
    int bkt[8];
    unsigned kept = 0;

    for (int b = threadIdx.x; b < NBK; b += 256) cnt[b] = 0;
    __syncthreads();

    #pragma unroll
    for (int k = 0; k < 8; ++k) {
        int e = base_e + k * 256 + threadIdx.x;
        if (e < NNZ && keepE(mask, e, isbyte)) {
            int r = rows[e];
            float v = 2.0f * loadF(adjv, e, isbf);
            rec[k] = (u64)(unsigned)(r & (BRWS - 1))
                   | ((u64)(unsigned)cols[e] << 9)
                   | ((u64)encodeV(v) << 27);
            bkt[k] = r >> BSH2;
            kept |= 1u << k;
            atomicAdd(&cnt[bkt[k]], 1);
        }
    }
    __syncthreads();

    // reserve contiguous runs (one global atomic per nonzero bucket)
    for (int b = threadIdx.x; b < NBK; b += 256)
        cur[b] = cnt[b] ? atomicAdd(&bcur[b], cnt[b]) : 0;
    __syncthreads();

    #pragma unroll
    for (int k = 0; k < 8; ++k) {
        if (kept & (1u << k)) {
            int pos = atomicAdd(&cur[bkt[k]], 1);   // LDS fetch-add
            if (pos < (bkt[k] + 1) * BCAP) part[pos] = rec[k];
        }
    }
}

// exclusive scan of bucket totals -> gbase; rowptr[0] = 0
__global__ __launch_bounds__(512) void bucket_scan(const int* __restrict__ bcur,
                                                   int* __restrict__ gbase,
                                                   int* __restrict__ rowptr) {
    __shared__ int s[512];
    int tid = threadIdx.x;
    int v = 0;
    if (tid < NBK) {
        v = bcur[tid] - tid * BCAP;
        if (v > BCAP) v = BCAP;
    }
    s[tid] = v;
    __syncthreads();
    for (int off = 1; off < 512; off <<= 1) {
        int t = (tid >= off) ? s[tid - off] : 0;
        __syncthreads();
        s[tid] += t;
        __syncthreads();
    }
    if (tid < NBK) gbase[tid] = s[tid] - v;
    if (tid == 0) rowptr[0] = 0;
}

// pass2: one 512-thread WG per bucket; thread = row. hist + scan + scatter.
// final edge u32 = col(18b) | valcode(13b)<<18
__global__ __launch_bounds__(512) void pass2_csr(const u64* __restrict__ part,
                                                 const int* __restrict__ bcur,
                                                 const int* __restrict__ gbase,
                                                 unsigned* __restrict__ edges,
                                                 int* __restrict__ rowptr) {
    __shared__ int cnt[BRWS];
    __shared__ int ex[BRWS];    // doubles as per-row cursor
    __shared__ int wsum[512];
    int b = blockIdx.x;
    int tid = threadIdx.x;
    int n = bcur[b] - b * BCAP;
    if (n > BCAP) n = BCAP;
    const u64* rp = part + (size_t)b * BCAP;
    int gb = gbase[b];

    cnt[tid] = 0;
    __syncthreads();
    for (int j = tid; j < n; j += 512)
        atomicAdd(&cnt[(int)(rp[j] & (BRWS - 1))], 1);
    __syncthreads();

    int c = cnt[tid];
    wsum[tid] = c;
    __syncthreads();
    for (int off = 1; off < 512; off <<= 1) {
        int t = (tid >= off) ? wsum[tid - off] : 0;
        __syncthreads();
        wsum[tid] += t;
        __syncthreads();
    }
    int incl = wsum[tid];
    ex[tid] = incl - c;
    int gr = (b << BSH2) + tid;
    if (gr < NNODE) rowptr[gr + 1] = gb + incl;
    __syncthreads();

    for (int j = tid; j < n; j += 512) {
        u64 rec = rp[j];
        int r = (int)(rec & (BRWS - 1));
        int pos = atomicAdd(&ex[r], 1);
        unsigned col = (unsigned)((rec >> 9) & 0x3FFFFu);
        unsigned code = (unsigned)((rec >> 27) & 0x1FFFu);
        edges[gb + pos] = col | (code << 18);
    }
}

// A(bf16) = concat(user_emb, item_emb); thread = one us4 (4 dims)
__global__ __launch_bounds__(256) void concat_cast(const void* __restrict__ ue,
                                                   const void* __restrict__ ie,
                                                   const int* __restrict__ flags,
                                                   ushort* __restrict__ A) {
    long q = (long)blockIdx.x * 256 + threadIdx.x;   // us4 index
    const long NU4 = (long)NUSER * DIM / 4;
    const long NT4 = (long)NNODE * DIM / 4;
    if (q >= NT4) return;
    us4 o;
    if (!flags[2]) {
        const f4* s = (q < NU4) ? (const f4*)ue : (const f4*)ie;
        f4 v = s[(q < NU4) ? q : q - NU4];
        o[0] = f2bf(v.x); o[1] = f2bf(v.y); o[2] = f2bf(v.z); o[3] = f2bf(v.w);
    } else {
        const us4* s = (q < NU4) ? (const us4*)ue : (const us4*)ie;
        o = s[(q < NU4) ? q : q - NU4];
    }
    ((us4*)A)[q] = o;
}

// dst[r,:] = sum_j val[j] * src[col[j],:]   (src/dst bf16, acc f32)
// One 64-lane wave per row; quarter q handles edges j0+q, j0+q+4, ...;
// lane t covers dims [4t,4t+4). Unroll-8 => 32 gathers in flight per wave.
__global__ __launch_bounds__(256) void spmm_csr(const ushort* __restrict__ src,
                                                const int* __restrict__ rowptr,
                                                const unsigned* __restrict__ edges,
                                                ushort* __restrict__ dst) {
    int r = blockIdx.x * 4 + (threadIdx.x >> 6);
    if (r >= NNODE) return;
    int lane = threadIdx.x & 63;
    int q = lane >> 4;
    int t = lane & 15;
    int j0 = rowptr[r], j1 = rowptr[r + 1];
    f4 acc = {0.0f, 0.0f, 0.0f, 0.0f};
    int j = j0 + q;
    for (; j + 28 < j1; j += 32) {
        unsigned e[8];
        #pragma unroll
        for (int k = 0; k < 8; ++k) e[k] = edges[j + 4 * k];
        us4 s[8];
        #pragma unroll
        for (int k = 0; k < 8; ++k)
            s[k] = ((const us4*)(src + (size_t)(e[k] & 0x3FFFFu) * DIM))[t];
        #pragma unroll
        for (int k = 0; k < 8; ++k) {
            float v = decodeV(e[k]);
            acc.x += v * bf2f(s[k][0]); acc.y += v * bf2f(s[k][1]);
            acc.z += v * bf2f(s[k][2]); acc.w += v * bf2f(s[k][3]);
        }
    }
    for (; j < j1; j += 4) {
        unsigned e0 = edges[j];
        float v0 = decodeV(e0);
        us4 s0 = ((const us4*)(src + (size_t)(e0 & 0x3FFFFu) * DIM))[t];
        acc.x += v0 * bf2f(s0[0]); acc.y += v0 * bf2f(s0[1]);
        acc.z += v0 * bf2f(s0[2]); acc.w += v0 * bf2f(s0[3]);
    }
    acc.x += __shfl_xor(acc.x, 16); acc.y += __shfl_xor(acc.y, 16);
    acc.z += __shfl_xor(acc.z, 16); acc.w += __shfl_xor(acc.w, 16);
    acc.x += __shfl_xor(acc.x, 32); acc.y += __shfl_xor(acc.y, 32);
    acc.z += __shfl_xor(acc.z, 32); acc.w += __shfl_xor(acc.w, 32);
    if (q == 0) {
        us4 o;
        o[0] = f2bf(acc.x); o[1] = f2bf(acc.y); o[2] = f2bf(acc.z); o[3] = f2bf(acc.w);
        __builtin_nontemporal_store(o, (us4*)(dst + (size_t)r * DIM) + t);
    }
}

__device__ __forceinline__ long nodeOf(int b, const int* users, const int* items, int sh) {
    if (b < BATCH) return (long)users[(size_t)b << sh];
    return (long)NUSER + (long)items[(size_t)(b - BATCH) << sh];
}

// acc[b,:] = table[node(b),:]
__global__ __launch_bounds__(256) void gather_first(const ushort* __restrict__ table,
                                                    const int* __restrict__ users,
                                                    const int* __restrict__ items,
                                                    const int* __restrict__ flags,
                                                    float* __restrict__ acc) {
    int t = blockIdx.x * 256 + threadIdx.x;          // f4/us4 index
    if (t >= 2 * BATCH * DIM / 4) return;
    long node = nodeOf(t >> 4, users, items, flags[1]);
    us4 u = ((const us4*)(table + node * DIM))[t & 15];
    f4 a = {bf2f(u[0]), bf2f(u[1]), bf2f(u[2]), bf2f(u[3])};
    ((f4*)acc)[t] = a;
}

// acc[b,:] += table[node(b),:]
__global__ __launch_bounds__(256) void gather_add(const ushort* __restrict__ table,
                                                  const int* __restrict__ users,
                                                  const int* __restrict__ items,
                                                  const int* __restrict__ flags,
                                                  float* __restrict__ acc) {
    int t = blockIdx.x * 256 + threadIdx.x;
    if (t >= 2 * BATCH * DIM / 4) return;
    long node = nodeOf(t >> 4, users, items, flags[1]);
    us4 u = ((const us4*)(table + node * DIM))[t & 15];
    f4 a = ((f4*)acc)[t];
    a.x += bf2f(u[0]); a.y += bf2f(u[1]); a.z += bf2f(u[2]); a.w += bf2f(u[3]);
    ((f4*)acc)[t] = a;
}

// out = 0.25 * (acc + table[node])
__global__ __launch_bounds__(256) void gather_final(const ushort* __restrict__ table,
                                                    const int* __restrict__ users,
                                                    const int* __restrict__ items,
                                                    const int* __restrict__ flags,
                                                    const float* __restrict__ acc,
                                                    float* __restrict__ out) {
    int t = blockIdx.x * 256 + threadIdx.x;
    if (t >= 2 * BATCH * DIM / 4) return;
    long node = nodeOf(t >> 4, users, items, flags[1]);
    us4 u = ((const us4*)(table + node * DIM))[t & 15];
    f4 a = ((const f4*)acc)[t];
    a.x = 0.25f * (a.x + bf2f(u[0]));
    a.y = 0.25f * (a.y + bf2f(u[1]));
    a.z = 0.25f * (a.z + bf2f(u[2]));
    a.w = 0.25f * (a.w + bf2f(u[3]));
    __builtin_nontemporal_store(a, (f4*)out + t);
}

extern "C" void kernel_launch(void* const* d_in, const int* in_sizes, int n_in,
                              void* d_out, int out_size, void* d_ws, size_t ws_size,
                              hipStream_t stream) {
    const void* user_emb = d_in[0];
    const void* item_emb = d_in[1];
    const void* adj_val  = d_in[2];
    const int*  adj_row  = (const int*)d_in[3];
    const int*  adj_col  = (const int*)d_in[4];
    const void* drop_msk = d_in[5];
    const int*  users    = (const int*)d_in[6];
    const int*  items    = (const int*)d_in[7];
    float* out = (float*)d_out;

    char* ws = (char*)d_ws;
    size_t off = 0;
    int* flags = (int*)(ws + off);            off += 256;
    float* out_acc = (float*)(ws + off);      off += (size_t)2 * BATCH * DIM * 4;   // 8 MB
    ushort* A = (ushort*)(ws + off);          off += (size_t)NNODE * DIM * 2;       // 19.2 MB
    ushort* B = (ushort*)(ws + off);          off += (size_t)NNODE * DIM * 2;       // 19.2 MB
    int* rowptr = (int*)(ws + off);           off += 600064;                        // NNODE+1
    int* bcur = (int*)(ws + off);             off += 2048;
    int* gbase = (int*)(ws + off);            off += 2048;
    u64* part = (u64*)(ws + off);             off += (size_t)NBK * BCAP * 8;        // 28.8 MB
    unsigned* edges = (unsigned*)(ws + off);  off += (size_t)NNZ * 4;               // 16 MB

    const int OUTN4 = 2 * BATCH * DIM / 4;            // 524288
    const int GOUT = (OUTN4 + 255) / 256;             // 2048
    const int GP1 = (NNZ + CHUNK - 1) / CHUNK;        // 1954

    detect_fmt<<<1, 256, 0, stream>>>((const unsigned int*)drop_msk,
                                      (const unsigned int*)users,
                                      (const unsigned int*)adj_val, flags);
    init_bcur<<<1, 256, 0, stream>>>(bcur);
    pass1_partition<<<GP1, 256, 0, stream>>>(drop_msk, adj_row, adj_col, adj_val,
                                             flags, bcur, part);
    bucket_scan<<<1, 512, 0, stream>>>(bcur, gbase, rowptr);
    pass2_csr<<<NBK, 512, 0, stream>>>(part, bcur, gbase, edges, rowptr);
    concat_cast<<<((NNODE * DIM / 4) + 255) / 256, 256, 0, stream>>>(user_emb, item_emb,
                                                                     flags, A);
    gather_first<<<GOUT, 256, 0, stream>>>(A, users, items, flags, out_acc);

    ushort* src = A;
    ushort* dst = B;
    for (int l = 0; l < 3; ++l) {
        spmm_csr<<<(NNODE + 3) / 4, 256, 0, stream>>>(src, rowptr, edges, dst);
        if (l < 2) {
            gather_add<<<GOUT, 256, 0, stream>>>(dst, users, items, flags, out_acc);
        } else {
            gather_final<<<GOUT, 256, 0, stream>>>(dst, users, items, flags, out_acc, out);
        }
        ushort* t = src; src = dst; dst = t;
    }
}

// Round 11
// 234.703 us; speedup vs baseline: 11.3584x; 1.4053x over previous
//
#include <hip/hip_runtime.h>
#include <hip/hip_bf16.h>

// LightGCN encoder on MI355X.
// Device dtypes: user_emb/item_emb/adj_val = float32 (bf16-rounded values),
// adj_row/adj_col = int32, drop_mask = bool/int32 (runtime-detected),
// users/items = int64/int32 (runtime-detected), output = float32.
//
// Round-10 post-mortem: wave-per-row spmm with unroll-8 needed >=32 edges to
// enter the MLP loop, but kept degrees are ~Poisson(10/20) -> user rows ran
// the serial remainder (1 gather in flight). Round 11: QUARTER-wave per row
// (16 lanes = 64 dims via ushort4; no cross-lane reduce), unroll-4 over the
// row's edges -> 4 gathers in flight per quarter even for 10-edge rows,
// 16 per wave, 4 rows per wave concurrently.

#define NUSER 100000
#define NITEM 50000
#define NNODE 150000
#define DIM   64
#define NNZ   4000000
#define BATCH 16384

#define BSH2  9             // bucket = row >> 9
#define BRWS  512           // rows per bucket
#define NBK   293           // ceil(150000/512)
#define BCAP  12288         // records per bucket region (mean item bucket ~10.2K)
#define CHUNK 2048          // edges per pass1 block (8 per thread)

typedef __hip_bfloat16 bf16;
typedef unsigned short ushort;
typedef unsigned long long u64;
typedef float f4 __attribute__((ext_vector_type(4)));
typedef ushort us4 __attribute__((ext_vector_type(4)));

__device__ __forceinline__ float loadF(const void* p, long i, int isbf16) {
    return isbf16 ? __bfloat162float(((const bf16*)p)[i]) : ((const float*)p)[i];
}

__device__ __forceinline__ bool keepE(const void* mask, int e, int isbyte) {
    return isbyte ? (((const unsigned char*)mask)[e] != 0)
                  : (((const int*)mask)[e] != 0);
}

__device__ __forceinline__ ushort f2bf(float x) {   // round-to-nearest-even
    unsigned u = __float_as_uint(x);
    return (ushort)((u + 0x7FFFu + ((u >> 16) & 1u)) >> 16);
}
__device__ __forceinline__ float bf2f(ushort u) {
    return __uint_as_float((unsigned)u << 16);
}

// val = 2*adj_val in (0,2]; exactly bf16 (inputs bf16-rounded, x2 = exp bump).
// 13-bit code: (e8-95)<<7 | m7.
__device__ __forceinline__ unsigned encodeV(float v) {
    unsigned fb = __float_as_uint(v);
    unsigned e8 = (fb >> 23) & 0xFFu;
    unsigned m7 = (fb >> 16) & 0x7Fu;
    return ((e8 - 95u) << 7) | m7;
}
__device__ __forceinline__ float decodeV(unsigned code) {
    unsigned vb = code >> 18;                      // 13 bits at [18,31)
    return __uint_as_float((((vb >> 7) + 95u) << 23) | ((vb & 0x7Fu) << 16));
}

// ---------------------------------------------------------------------------
// flags[0]: drop_mask is 1-byte. flags[1]: users/items are int64.
// flags[2]: float arrays are bf16 (insurance; expected 0 = f32).
__global__ __launch_bounds__(256) void detect_fmt(const unsigned int* __restrict__ mask,
                                                  const unsigned int* __restrict__ users,
                                                  const unsigned int* __restrict__ adjv,
                                                  int* __restrict__ flags) {
    __shared__ int s[3];
    if (threadIdx.x < 3) s[threadIdx.x] = 0;
    __syncthreads();
    int c0 = 0, c1 = 0, c2 = 0;
    for (int i = threadIdx.x; i < 4096; i += 256) {
        c0 += (mask[i] > 1u) ? 1 : 0;
        if (i & 1) c1 += (users[i] == 0u) ? 1 : 0;
        unsigned lo = adjv[i] & 0xFFFFu;
        unsigned ex = (lo >> 7) & 0xFFu;
        c2 += ((lo >> 15) == 0u && ex >= 0x60u && ex <= 0x7Fu) ? 1 : 0;
    }
    atomicAdd(&s[0], c0); atomicAdd(&s[1], c1); atomicAdd(&s[2], c2);
    __syncthreads();
    if (threadIdx.x == 0) {
        flags[0] = (s[0] > 16) ? 1 : 0;
        flags[1] = (s[1] > 1024) ? 1 : 0;
        flags[2] = (s[2] > 3000) ? 1 : 0;
    }
}

__global__ __launch_bounds__(256) void init_bcur(int* __restrict__ bcur) {
    for (int b = threadIdx.x; b < NBK; b += 256) bcur[b] = b * BCAP;
}

// pass1: one read pass; records built in registers (8 edges/thread, full
// unroll -> register-resident), then LDS fetch-add + store per kept edge.
// record u64 = r9(9b) | col(18b)<<9 | valcode(13b)<<27
__global__ __launch_bounds__(256) void pass1_partition(const void* __restrict__ mask,
                                                       const int* __restrict__ rows,
                                                       const int* __restrict__ cols,
                                                       const void* __restrict__ adjv,
                                                       const int* __restrict__ flags,
                                                       int* __restrict__ bcur,
                                                       u64* __restrict__ part) {
    __shared__ int cnt[NBK];
    __shared__ int cur[NBK];
    const int isbyte = flags[0];
    const int isbf = flags[2];
    const int base_e = blockIdx.x * CHUNK;
    u64 rec[8];
    int bkt[8];
    unsigned kept = 0;

    for (int b = threadIdx.x; b < NBK; b += 256) cnt[b] = 0;
    __syncthreads();

    #pragma unroll
    for (int k = 0; k < 8; ++k) {
        int e = base_e + k * 256 + threadIdx.x;
        if (e < NNZ && keepE(mask, e, isbyte)) {
            int r = rows[e];
            float v = 2.0f * loadF(adjv, e, isbf);
            rec[k] = (u64)(unsigned)(r & (BRWS - 1))
                   | ((u64)(unsigned)cols[e] << 9)
                   | ((u64)encodeV(v) << 27);
            bkt[k] = r >> BSH2;
            kept |= 1u << k;
            atomicAdd(&cnt[bkt[k]], 1);
        }
    }
    __syncthreads();

    // reserve contiguous runs (one global atomic per nonzero bucket)
    for (int b = threadIdx.x; b < NBK; b += 256)
        cur[b] = cnt[b] ? atomicAdd(&bcur[b], cnt[b]) : 0;
    __syncthreads();

    #pragma unroll
    for (int k = 0; k < 8; ++k) {
        if (kept & (1u << k)) {
            int pos = atomicAdd(&cur[bkt[k]], 1);   // LDS fetch-add
            if (pos < (bkt[k] + 1) * BCAP) part[pos] = rec[k];
        }
    }
}

// exclusive scan of bucket totals -> gbase; rowptr[0] = 0
__global__ __launch_bounds__(512) void bucket_scan(const int* __restrict__ bcur,
                                                   int* __restrict__ gbase,
                                                   int* __restrict__ rowptr) {
    __shared__ int s[512];
    int tid = threadIdx.x;
    int v = 0;
    if (tid < NBK) {
        v = bcur[tid] - tid * BCAP;
        if (v > BCAP) v = BCAP;
    }
    s[tid] = v;
    __syncthreads();
    for (int off = 1; off < 512; off <<= 1) {
        int t = (tid >= off) ? s[tid - off] : 0;
        __syncthreads();
        s[tid] += t;
        __syncthreads();
    }
    if (tid < NBK) gbase[tid] = s[tid] - v;
    if (tid == 0) rowptr[0] = 0;
}

// pass2: one 512-thread WG per bucket; thread = row. hist + scan + scatter.
// final edge u32 = col(18b) | valcode(13b)<<18
__global__ __launch_bounds__(512) void pass2_csr(const u64* __restrict__ part,
                                                 const int* __restrict__ bcur,
                                                 const int* __restrict__ gbase,
                                                 unsigned* __restrict__ edges,
                                                 int* __restrict__ rowptr) {
    __shared__ int cnt[BRWS];
    __shared__ int ex[BRWS];    // doubles as per-row cursor
    __shared__ int wsum[512];
    int b = blockIdx.x;
    int tid = threadIdx.x;
    int n = bcur[b] - b * BCAP;
    if (n > BCAP) n = BCAP;
    const u64* rp = part + (size_t)b * BCAP;
    int gb = gbase[b];

    cnt[tid] = 0;
    __syncthreads();
    for (int j = tid; j < n; j += 512)
        atomicAdd(&cnt[(int)(rp[j] & (BRWS - 1))], 1);
    __syncthreads();

    int c = cnt[tid];
    wsum[tid] = c;
    __syncthreads();
    for (int off = 1; off < 512; off <<= 1) {
        int t = (tid >= off) ? wsum[tid - off] : 0;
        __syncthreads();
        wsum[tid] += t;
        __syncthreads();
    }
    int incl = wsum[tid];
    ex[tid] = incl - c;
    int gr = (b << BSH2) + tid;
    if (gr < NNODE) rowptr[gr + 1] = gb + incl;
    __syncthreads();

    for (int j = tid; j < n; j += 512) {
        u64 rec = rp[j];
        int r = (int)(rec & (BRWS - 1));
        int pos = atomicAdd(&ex[r], 1);
        unsigned col = (unsigned)((rec >> 9) & 0x3FFFFu);
        unsigned code = (unsigned)((rec >> 27) & 0x1FFFu);
        edges[gb + pos] = col | (code << 18);
    }
}

// A(bf16) = concat(user_emb, item_emb); thread = one us4 (4 dims)
__global__ __launch_bounds__(256) void concat_cast(const void* __restrict__ ue,
                                                   const void* __restrict__ ie,
                                                   const int* __restrict__ flags,
                                                   ushort* __restrict__ A) {
    long q = (long)blockIdx.x * 256 + threadIdx.x;   // us4 index
    const long NU4 = (long)NUSER * DIM / 4;
    const long NT4 = (long)NNODE * DIM / 4;
    if (q >= NT4) return;
    us4 o;
    if (!flags[2]) {
        const f4* s = (q < NU4) ? (const f4*)ue : (const f4*)ie;
        f4 v = s[(q < NU4) ? q : q - NU4];
        o[0] = f2bf(v.x); o[1] = f2bf(v.y); o[2] = f2bf(v.z); o[3] = f2bf(v.w);
    } else {
        const us4* s = (q < NU4) ? (const us4*)ue : (const us4*)ie;
        o = s[(q < NU4) ? q : q - NU4];
    }
    ((us4*)A)[q] = o;
}

// dst[r,:] = sum_j val[j] * src[col[j],:]   (src/dst bf16, acc f32)
// QUARTER-wave per row: 16 lanes own the row (lane t = dims [4t,4t+4) via
// one us4); unroll-4 over the row's edges -> 4 gathers in flight per quarter
// regardless of row length. No cross-lane reduce. 16 rows per 256-block.
__global__ __launch_bounds__(256) void spmm_csr(const ushort* __restrict__ src,
                                                const int* __restrict__ rowptr,
                                                const unsigned* __restrict__ edges,
                                                ushort* __restrict__ dst) {
    int r = blockIdx.x * 16 + (threadIdx.x >> 4);
    if (r >= NNODE) return;
    int t = threadIdx.x & 15;
    int j0 = rowptr[r], j1 = rowptr[r + 1];
    f4 acc = {0.0f, 0.0f, 0.0f, 0.0f};
    int j = j0;
    for (; j + 4 <= j1; j += 4) {
        unsigned e0 = edges[j];
        unsigned e1 = edges[j + 1];
        unsigned e2 = edges[j + 2];
        unsigned e3 = edges[j + 3];
        us4 s0 = ((const us4*)(src + (size_t)(e0 & 0x3FFFFu) * DIM))[t];
        us4 s1 = ((const us4*)(src + (size_t)(e1 & 0x3FFFFu) * DIM))[t];
        us4 s2 = ((const us4*)(src + (size_t)(e2 & 0x3FFFFu) * DIM))[t];
        us4 s3 = ((const us4*)(src + (size_t)(e3 & 0x3FFFFu) * DIM))[t];
        float v0 = decodeV(e0), v1 = decodeV(e1);
        float v2 = decodeV(e2), v3 = decodeV(e3);
        acc.x += v0 * bf2f(s0[0]); acc.y += v0 * bf2f(s0[1]);
        acc.z += v0 * bf2f(s0[2]); acc.w += v0 * bf2f(s0[3]);
        acc.x += v1 * bf2f(s1[0]); acc.y += v1 * bf2f(s1[1]);
        acc.z += v1 * bf2f(s1[2]); acc.w += v1 * bf2f(s1[3]);
        acc.x += v2 * bf2f(s2[0]); acc.y += v2 * bf2f(s2[1]);
        acc.z += v2 * bf2f(s2[2]); acc.w += v2 * bf2f(s2[3]);
        acc.x += v3 * bf2f(s3[0]); acc.y += v3 * bf2f(s3[1]);
        acc.z += v3 * bf2f(s3[2]); acc.w += v3 * bf2f(s3[3]);
    }
    for (; j < j1; ++j) {
        unsigned e0 = edges[j];
        float v0 = decodeV(e0);
        us4 s0 = ((const us4*)(src + (size_t)(e0 & 0x3FFFFu) * DIM))[t];
        acc.x += v0 * bf2f(s0[0]); acc.y += v0 * bf2f(s0[1]);
        acc.z += v0 * bf2f(s0[2]); acc.w += v0 * bf2f(s0[3]);
    }
    us4 o;
    o[0] = f2bf(acc.x); o[1] = f2bf(acc.y); o[2] = f2bf(acc.z); o[3] = f2bf(acc.w);
    __builtin_nontemporal_store(o, (us4*)(dst + (size_t)r * DIM) + t);
}

__device__ __forceinline__ long nodeOf(int b, const int* users, const int* items, int sh) {
    if (b < BATCH) return (long)users[(size_t)b << sh];
    return (long)NUSER + (long)items[(size_t)(b - BATCH) << sh];
}

// acc[b,:] = table[node(b),:]
__global__ __launch_bounds__(256) void gather_first(const ushort* __restrict__ table,
                                                    const int* __restrict__ users,
                                                    const int* __restrict__ items,
                                                    const int* __restrict__ flags,
                                                    float* __restrict__ acc) {
    int t = blockIdx.x * 256 + threadIdx.x;          // f4/us4 index
    if (t >= 2 * BATCH * DIM / 4) return;
    long node = nodeOf(t >> 4, users, items, flags[1]);
    us4 u = ((const us4*)(table + node * DIM))[t & 15];
    f4 a = {bf2f(u[0]), bf2f(u[1]), bf2f(u[2]), bf2f(u[3])};
    ((f4*)acc)[t] = a;
}

// acc[b,:] += table[node(b),:]
__global__ __launch_bounds__(256) void gather_add(const ushort* __restrict__ table,
                                                  const int* __restrict__ users,
                                                  const int* __restrict__ items,
                                                  const int* __restrict__ flags,
                                                  float* __restrict__ acc) {
    int t = blockIdx.x * 256 + threadIdx.x;
    if (t >= 2 * BATCH * DIM / 4) return;
    long node = nodeOf(t >> 4, users, items, flags[1]);
    us4 u = ((const us4*)(table + node * DIM))[t & 15];
    f4 a = ((f4*)acc)[t];
    a.x += bf2f(u[0]); a.y += bf2f(u[1]); a.z += bf2f(u[2]); a.w += bf2f(u[3]);
    ((f4*)acc)[t] = a;
}

// out = 0.25 * (acc + table[node])
__global__ __launch_bounds__(256) void gather_final(const ushort* __restrict__ table,
                                                    const int* __restrict__ users,
                                                    const int* __restrict__ items,
                                                    const int* __restrict__ flags,
                                                    const float* __restrict__ acc,
                                                    float* __restrict__ out) {
    int t = blockIdx.x * 256 + threadIdx.x;
    if (t >= 2 * BATCH * DIM / 4) return;
    long node = nodeOf(t >> 4, users, items, flags[1]);
    us4 u = ((const us4*)(table + node * DIM))[t & 15];
    f4 a = ((const f4*)acc)[t];
    a.x = 0.25f * (a.x + bf2f(u[0]));
    a.y = 0.25f * (a.y + bf2f(u[1]));
    a.z = 0.25f * (a.z + bf2f(u[2]));
    a.w = 0.25f * (a.w + bf2f(u[3]));
    __builtin_nontemporal_store(a, (f4*)out + t);
}

extern "C" void kernel_launch(void* const* d_in, const int* in_sizes, int n_in,
                              void* d_out, int out_size, void* d_ws, size_t ws_size,
                              hipStream_t stream) {
    const void* user_emb = d_in[0];
    const void* item_emb = d_in[1];
    const void* adj_val  = d_in[2];
    const int*  adj_row  = (const int*)d_in[3];
    const int*  adj_col  = (const int*)d_in[4];
    const void* drop_msk = d_in[5];
    const int*  users    = (const int*)d_in[6];
    const int*  items    = (const int*)d_in[7];
    float* out = (float*)d_out;

    char* ws = (char*)d_ws;
    size_t off = 0;
    int* flags = (int*)(ws + off);            off += 256;
    float* out_acc = (float*)(ws + off);      off += (size_t)2 * BATCH * DIM * 4;   // 8 MB
    ushort* A = (ushort*)(ws + off);          off += (size_t)NNODE * DIM * 2;       // 19.2 MB
    ushort* B = (ushort*)(ws + off);          off += (size_t)NNODE * DIM * 2;       // 19.2 MB
    int* rowptr = (int*)(ws + off);           off += 600064;                        // NNODE+1
    int* bcur = (int*)(ws + off);             off += 2048;
    int* gbase = (int*)(ws + off);            off += 2048;
    u64* part = (u64*)(ws + off);             off += (size_t)NBK * BCAP * 8;        // 28.8 MB
    unsigned* edges = (unsigned*)(ws + off);  off += (size_t)NNZ * 4;               // 16 MB

    const int OUTN4 = 2 * BATCH * DIM / 4;            // 524288
    const int GOUT = (OUTN4 + 255) / 256;             // 2048
    const int GP1 = (NNZ + CHUNK - 1) / CHUNK;        // 1954
    const int GSP = (NNODE + 15) / 16;                // 9375

    detect_fmt<<<1, 256, 0, stream>>>((const unsigned int*)drop_msk,
                                      (const unsigned int*)users,
                                      (const unsigned int*)adj_val, flags);
    init_bcur<<<1, 256, 0, stream>>>(bcur);
    pass1_partition<<<GP1, 256, 0, stream>>>(drop_msk, adj_row, adj_col, adj_val,
                                             flags, bcur, part);
    bucket_scan<<<1, 512, 0, stream>>>(bcur, gbase, rowptr);
    pass2_csr<<<NBK, 512, 0, stream>>>(part, bcur, gbase, edges, rowptr);
    concat_cast<<<((NNODE * DIM / 4) + 255) / 256, 256, 0, stream>>>(user_emb, item_emb,
                                                                     flags, A);
    gather_first<<<GOUT, 256, 0, stream>>>(A, users, items, flags, out_acc);

    ushort* src = A;
    ushort* dst = B;
    for (int l = 0; l < 3; ++l) {
        spmm_csr<<<GSP, 256, 0, stream>>>(src, rowptr, edges, dst);
        if (l < 2) {
            gather_add<<<GOUT, 256, 0, stream>>>(dst, users, items, flags, out_acc);
        } else {
            gather_final<<<GOUT, 256, 0, stream>>>(dst, users, items, flags, out_acc, out);
        }
        ushort* t = src; src = dst; dst = t;
    }
}

// Round 12
// 214.618 us; speedup vs baseline: 12.4214x; 1.0936x over previous
//
#include <hip/hip_runtime.h>
#include <hip/hip_bf16.h>

// LightGCN encoder on MI355X.
// Device dtypes: user_emb/item_emb/adj_val = float32 (bf16-rounded values),
// adj_row/adj_col = int32, drop_mask = bool/int32 (runtime-detected),
// users/items = int64/int32 (runtime-detected), output = float32.
//
// Round-11 post-mortem: pass1 latency-bound on its dependent chain
// (mask->test->loads->encode->LDS atomic->store). Round 12:
//  * pass1 loads all 4 streams unconditionally for full chunks (32
//    independent loads in flight), records built before any branching.
//  * spmm: eighth-wave per row (8 lanes x ushort8 = 16B/lane, 128B/edge
//    coalesced, no reduce, unroll-4) -> half the load instructions, 2x rows
//    per wave. If this is neutral, spmm is at the LLC-BW roofline.
//  * init_bcur folded into detect_fmt.

#define NUSER 100000
#define NITEM 50000
#define NNODE 150000
#define DIM   64
#define NNZ   4000000
#define BATCH 16384

#define BSH2  9             // bucket = row >> 9
#define BRWS  512           // rows per bucket
#define NBK   293           // ceil(150000/512)
#define BCAP  12288         // records per bucket region (mean item bucket ~10.2K)
#define CHUNK 2048          // edges per pass1 block (8 per thread)

typedef __hip_bfloat16 bf16;
typedef unsigned short ushort;
typedef unsigned long long u64;
typedef float f4 __attribute__((ext_vector_type(4)));
typedef ushort us4 __attribute__((ext_vector_type(4)));
typedef ushort us8 __attribute__((ext_vector_type(8)));

__device__ __forceinline__ float loadF(const void* p, long i, int isbf16) {
    return isbf16 ? __bfloat162float(((const bf16*)p)[i]) : ((const float*)p)[i];
}

__device__ __forceinline__ bool keepE(const void* mask, int e, int isbyte) {
    return isbyte ? (((const unsigned char*)mask)[e] != 0)
                  : (((const int*)mask)[e] != 0);
}

__device__ __forceinline__ ushort f2bf(float x) {   // round-to-nearest-even
    unsigned u = __float_as_uint(x);
    return (ushort)((u + 0x7FFFu + ((u >> 16) & 1u)) >> 16);
}
__device__ __forceinline__ float bf2f(ushort u) {
    return __uint_as_float((unsigned)u << 16);
}

// val = 2*adj_val in (0,2]; exactly bf16 (inputs bf16-rounded, x2 = exp bump).
// 13-bit code: (e8-95)<<7 | m7.
__device__ __forceinline__ unsigned encodeV(float v) {
    unsigned fb = __float_as_uint(v);
    unsigned e8 = (fb >> 23) & 0xFFu;
    unsigned m7 = (fb >> 16) & 0x7Fu;
    return ((e8 - 95u) << 7) | m7;
}
__device__ __forceinline__ float decodeV(unsigned code) {
    unsigned vb = code >> 18;                      // 13 bits at [18,31)
    return __uint_as_float((((vb >> 7) + 95u) << 23) | ((vb & 0x7Fu) << 16));
}

// ---------------------------------------------------------------------------
// flags[0]: drop_mask is 1-byte. flags[1]: users/items are int64.
// flags[2]: float arrays are bf16 (insurance; expected 0 = f32).
// Also initializes bcur (folded former init_bcur kernel).
__global__ __launch_bounds__(256) void detect_fmt(const unsigned int* __restrict__ mask,
                                                  const unsigned int* __restrict__ users,
                                                  const unsigned int* __restrict__ adjv,
                                                  int* __restrict__ flags,
                                                  int* __restrict__ bcur) {
    __shared__ int s[3];
    if (threadIdx.x < 3) s[threadIdx.x] = 0;
    for (int b = threadIdx.x; b < NBK; b += 256) bcur[b] = b * BCAP;
    __syncthreads();
    int c0 = 0, c1 = 0, c2 = 0;
    for (int i = threadIdx.x; i < 4096; i += 256) {
        c0 += (mask[i] > 1u) ? 1 : 0;
        if (i & 1) c1 += (users[i] == 0u) ? 1 : 0;
        unsigned lo = adjv[i] & 0xFFFFu;
        unsigned ex = (lo >> 7) & 0xFFu;
        c2 += ((lo >> 15) == 0u && ex >= 0x60u && ex <= 0x7Fu) ? 1 : 0;
    }
    atomicAdd(&s[0], c0); atomicAdd(&s[1], c1); atomicAdd(&s[2], c2);
    __syncthreads();
    if (threadIdx.x == 0) {
        flags[0] = (s[0] > 16) ? 1 : 0;
        flags[1] = (s[1] > 1024) ? 1 : 0;
        flags[2] = (s[2] > 3000) ? 1 : 0;
    }
}

// pass1: unconditional batched loads (full chunks) -> records in registers ->
// LDS count -> run reservation -> LDS fetch-add + store per kept edge.
// record u64 = r9(9b) | col(18b)<<9 | valcode(13b)<<27
__global__ __launch_bounds__(256) void pass1_partition(const void* __restrict__ mask,
                                                       const int* __restrict__ rows,
                                                       const int* __restrict__ cols,
                                                       const void* __restrict__ adjv,
                                                       const int* __restrict__ flags,
                                                       int* __restrict__ bcur,
                                                       u64* __restrict__ part) {
    __shared__ int cnt[NBK];
    __shared__ int cur[NBK];
    const int isbyte = flags[0];
    const int isbf = flags[2];
    const int base_e = blockIdx.x * CHUNK;
    u64 rec[8];
    int bkt[8];
    unsigned kept = 0;

    for (int b = threadIdx.x; b < NBK; b += 256) cnt[b] = 0;
    __syncthreads();

    if (base_e + CHUNK <= NNZ) {
        // fast path: all loads issued up-front, independent
        int mk[8], rr[8]; unsigned cc[8]; float vv[8];
        #pragma unroll
        for (int k = 0; k < 8; ++k) {
            int e = base_e + k * 256 + threadIdx.x;
            mk[k] = isbyte ? (int)((const unsigned char*)mask)[e]
                           : ((const int*)mask)[e];
            rr[k] = rows[e];
            cc[k] = (unsigned)cols[e];
            vv[k] = 2.0f * loadF(adjv, e, isbf);
        }
        #pragma unroll
        for (int k = 0; k < 8; ++k) {
            if (mk[k]) {
                rec[k] = (u64)(unsigned)(rr[k] & (BRWS - 1))
                       | ((u64)cc[k] << 9)
                       | ((u64)encodeV(vv[k]) << 27);
                bkt[k] = rr[k] >> BSH2;
                kept |= 1u << k;
                atomicAdd(&cnt[bkt[k]], 1);
            }
        }
    } else {
        #pragma unroll
        for (int k = 0; k < 8; ++k) {
            int e = base_e + k * 256 + threadIdx.x;
            if (e < NNZ && keepE(mask, e, isbyte)) {
                int r = rows[e];
                float v = 2.0f * loadF(adjv, e, isbf);
                rec[k] = (u64)(unsigned)(r & (BRWS - 1))
                       | ((u64)(unsigned)cols[e] << 9)
                       | ((u64)encodeV(v) << 27);
                bkt[k] = r >> BSH2;
                kept |= 1u << k;
                atomicAdd(&cnt[bkt[k]], 1);
            }
        }
    }
    __syncthreads();

    // reserve contiguous runs (one global atomic per nonzero bucket)
    for (int b = threadIdx.x; b < NBK; b += 256)
        cur[b] = cnt[b] ? atomicAdd(&bcur[b], cnt[b]) : 0;
    __syncthreads();

    #pragma unroll
    for (int k = 0; k < 8; ++k) {
        if (kept & (1u << k)) {
            int pos = atomicAdd(&cur[bkt[k]], 1);   // LDS fetch-add
            if (pos < (bkt[k] + 1) * BCAP) part[pos] = rec[k];
        }
    }
}

// exclusive scan of bucket totals -> gbase; rowptr[0] = 0
__global__ __launch_bounds__(512) void bucket_scan(const int* __restrict__ bcur,
                                                   int* __restrict__ gbase,
                                                   int* __restrict__ rowptr) {
    __shared__ int s[512];
    int tid = threadIdx.x;
    int v = 0;
    if (tid < NBK) {
        v = bcur[tid] - tid * BCAP;
        if (v > BCAP) v = BCAP;
    }
    s[tid] = v;
    __syncthreads();
    for (int off = 1; off < 512; off <<= 1) {
        int t = (tid >= off) ? s[tid - off] : 0;
        __syncthreads();
        s[tid] += t;
        __syncthreads();
    }
    if (tid < NBK) gbase[tid] = s[tid] - v;
    if (tid == 0) rowptr[0] = 0;
}

// pass2: one 512-thread WG per bucket; thread = row. hist + scan + scatter.
// final edge u32 = col(18b) | valcode(13b)<<18
__global__ __launch_bounds__(512) void pass2_csr(const u64* __restrict__ part,
                                                 const int* __restrict__ bcur,
                                                 const int* __restrict__ gbase,
                                                 unsigned* __restrict__ edges,
                                                 int* __restrict__ rowptr) {
    __shared__ int cnt[BRWS];
    __shared__ int ex[BRWS];    // doubles as per-row cursor
    __shared__ int wsum[512];
    int b = blockIdx.x;
    int tid = threadIdx.x;
    int n = bcur[b] - b * BCAP;
    if (n > BCAP) n = BCAP;
    const u64* rp = part + (size_t)b * BCAP;
    int gb = gbase[b];

    cnt[tid] = 0;
    __syncthreads();
    for (int j = tid; j < n; j += 512)
        atomicAdd(&cnt[(int)(rp[j] & (BRWS - 1))], 1);
    __syncthreads();

    int c = cnt[tid];
    wsum[tid] = c;
    __syncthreads();
    for (int off = 1; off < 512; off <<= 1) {
        int t = (tid >= off) ? wsum[tid - off] : 0;
        __syncthreads();
        wsum[tid] += t;
        __syncthreads();
    }
    int incl = wsum[tid];
    ex[tid] = incl - c;
    int gr = (b << BSH2) + tid;
    if (gr < NNODE) rowptr[gr + 1] = gb + incl;
    __syncthreads();

    for (int j = tid; j < n; j += 512) {
        u64 rec = rp[j];
        int r = (int)(rec & (BRWS - 1));
        int pos = atomicAdd(&ex[r], 1);
        unsigned col = (unsigned)((rec >> 9) & 0x3FFFFu);
        unsigned code = (unsigned)((rec >> 27) & 0x1FFFu);
        edges[gb + pos] = col | (code << 18);
    }
}

// A(bf16) = concat(user_emb, item_emb); thread = one us4 (4 dims)
__global__ __launch_bounds__(256) void concat_cast(const void* __restrict__ ue,
                                                   const void* __restrict__ ie,
                                                   const int* __restrict__ flags,
                                                   ushort* __restrict__ A) {
    long q = (long)blockIdx.x * 256 + threadIdx.x;   // us4 index
    const long NU4 = (long)NUSER * DIM / 4;
    const long NT4 = (long)NNODE * DIM / 4;
    if (q >= NT4) return;
    us4 o;
    if (!flags[2]) {
        const f4* s = (q < NU4) ? (const f4*)ue : (const f4*)ie;
        f4 v = s[(q < NU4) ? q : q - NU4];
        o[0] = f2bf(v.x); o[1] = f2bf(v.y); o[2] = f2bf(v.z); o[3] = f2bf(v.w);
    } else {
        const us4* s = (q < NU4) ? (const us4*)ue : (const us4*)ie;
        o = s[(q < NU4) ? q : q - NU4];
    }
    ((us4*)A)[q] = o;
}

// dst[r,:] = sum_j val[j] * src[col[j],:]   (src/dst bf16, acc f32)
// EIGHTH-wave per row: 8 lanes own the row (lane t = dims [8t,8t+8) via one
// us8 = 16B load); unroll-4 over the row's edges -> 4 gathers in flight per
// group, half the load instructions of the quarter-wave version, 8 rows/wave.
__global__ __launch_bounds__(256) void spmm_csr(const ushort* __restrict__ src,
                                                const int* __restrict__ rowptr,
                                                const unsigned* __restrict__ edges,
                                                ushort* __restrict__ dst) {
    int r = blockIdx.x * 32 + (threadIdx.x >> 3);
    if (r >= NNODE) return;
    int t = threadIdx.x & 7;
    int j0 = rowptr[r], j1 = rowptr[r + 1];
    float acc[8] = {0, 0, 0, 0, 0, 0, 0, 0};
    int j = j0;
    for (; j + 4 <= j1; j += 4) {
        unsigned e0 = edges[j];
        unsigned e1 = edges[j + 1];
        unsigned e2 = edges[j + 2];
        unsigned e3 = edges[j + 3];
        us8 s0 = ((const us8*)(src + (size_t)(e0 & 0x3FFFFu) * DIM))[t];
        us8 s1 = ((const us8*)(src + (size_t)(e1 & 0x3FFFFu) * DIM))[t];
        us8 s2 = ((const us8*)(src + (size_t)(e2 & 0x3FFFFu) * DIM))[t];
        us8 s3 = ((const us8*)(src + (size_t)(e3 & 0x3FFFFu) * DIM))[t];
        float v0 = decodeV(e0), v1 = decodeV(e1);
        float v2 = decodeV(e2), v3 = decodeV(e3);
        #pragma unroll
        for (int d = 0; d < 8; ++d) {
            acc[d] += v0 * bf2f(s0[d]);
            acc[d] += v1 * bf2f(s1[d]);
            acc[d] += v2 * bf2f(s2[d]);
            acc[d] += v3 * bf2f(s3[d]);
        }
    }
    for (; j < j1; ++j) {
        unsigned e0 = edges[j];
        float v0 = decodeV(e0);
        us8 s0 = ((const us8*)(src + (size_t)(e0 & 0x3FFFFu) * DIM))[t];
        #pragma unroll
        for (int d = 0; d < 8; ++d) acc[d] += v0 * bf2f(s0[d]);
    }
    us8 o;
    #pragma unroll
    for (int d = 0; d < 8; ++d) o[d] = f2bf(acc[d]);
    __builtin_nontemporal_store(o, (us8*)(dst + (size_t)r * DIM) + t);
}

__device__ __forceinline__ long nodeOf(int b, const int* users, const int* items, int sh) {
    if (b < BATCH) return (long)users[(size_t)b << sh];
    return (long)NUSER + (long)items[(size_t)(b - BATCH) << sh];
}

// acc[b,:] = table[node(b),:]
__global__ __launch_bounds__(256) void gather_first(const ushort* __restrict__ table,
                                                    const int* __restrict__ users,
                                                    const int* __restrict__ items,
                                                    const int* __restrict__ flags,
                                                    float* __restrict__ acc) {
    int t = blockIdx.x * 256 + threadIdx.x;          // f4/us4 index
    if (t >= 2 * BATCH * DIM / 4) return;
    long node = nodeOf(t >> 4, users, items, flags[1]);
    us4 u = ((const us4*)(table + node * DIM))[t & 15];
    f4 a = {bf2f(u[0]), bf2f(u[1]), bf2f(u[2]), bf2f(u[3])};
    ((f4*)acc)[t] = a;
}

// acc[b,:] += table[node(b),:]
__global__ __launch_bounds__(256) void gather_add(const ushort* __restrict__ table,
                                                  const int* __restrict__ users,
                                                  const int* __restrict__ items,
                                                  const int* __restrict__ flags,
                                                  float* __restrict__ acc) {
    int t = blockIdx.x * 256 + threadIdx.x;
    if (t >= 2 * BATCH * DIM / 4) return;
    long node = nodeOf(t >> 4, users, items, flags[1]);
    us4 u = ((const us4*)(table + node * DIM))[t & 15];
    f4 a = ((f4*)acc)[t];
    a.x += bf2f(u[0]); a.y += bf2f(u[1]); a.z += bf2f(u[2]); a.w += bf2f(u[3]);
    ((f4*)acc)[t] = a;
}

// out = 0.25 * (acc + table[node])
__global__ __launch_bounds__(256) void gather_final(const ushort* __restrict__ table,
                                                    const int* __restrict__ users,
                                                    const int* __restrict__ items,
                                                    const int* __restrict__ flags,
                                                    const float* __restrict__ acc,
                                                    float* __restrict__ out) {
    int t = blockIdx.x * 256 + threadIdx.x;
    if (t >= 2 * BATCH * DIM / 4) return;
    long node = nodeOf(t >> 4, users, items, flags[1]);
    us4 u = ((const us4*)(table + node * DIM))[t & 15];
    f4 a = ((const f4*)acc)[t];
    a.x = 0.25f * (a.x + bf2f(u[0]));
    a.y = 0.25f * (a.y + bf2f(u[1]));
    a.z = 0.25f * (a.z + bf2f(u[2]));
    a.w = 0.25f * (a.w + bf2f(u[3]));
    __builtin_nontemporal_store(a, (f4*)out + t);
}

extern "C" void kernel_launch(void* const* d_in, const int* in_sizes, int n_in,
                              void* d_out, int out_size, void* d_ws, size_t ws_size,
                              hipStream_t stream) {
    const void* user_emb = d_in[0];
    const void* item_emb = d_in[1];
    const void* adj_val  = d_in[2];
    const int*  adj_row  = (const int*)d_in[3];
    const int*  adj_col  = (const int*)d_in[4];
    const void* drop_msk = d_in[5];
    const int*  users    = (const int*)d_in[6];
    const int*  items    = (const int*)d_in[7];
    float* out = (float*)d_out;

    char* ws = (char*)d_ws;
    size_t off = 0;
    int* flags = (int*)(ws + off);            off += 256;
    float* out_acc = (float*)(ws + off);      off += (size_t)2 * BATCH * DIM * 4;   // 8 MB
    ushort* A = (ushort*)(ws + off);          off += (size_t)NNODE * DIM * 2;       // 19.2 MB
    ushort* B = (ushort*)(ws + off);          off += (size_t)NNODE * DIM * 2;       // 19.2 MB
    int* rowptr = (int*)(ws + off);           off += 600064;                        // NNODE+1
    int* bcur = (int*)(ws + off);             off += 2048;
    int* gbase = (int*)(ws + off);            off += 2048;
    u64* part = (u64*)(ws + off);             off += (size_t)NBK * BCAP * 8;        // 28.8 MB
    unsigned* edges = (unsigned*)(ws + off);  off += (size_t)NNZ * 4;               // 16 MB

    const int OUTN4 = 2 * BATCH * DIM / 4;            // 524288
    const int GOUT = (OUTN4 + 255) / 256;             // 2048
    const int GP1 = (NNZ + CHUNK - 1) / CHUNK;        // 1954
    const int GSP = (NNODE + 31) / 32;                // 4688

    detect_fmt<<<1, 256, 0, stream>>>((const unsigned int*)drop_msk,
                                      (const unsigned int*)users,
                                      (const unsigned int*)adj_val, flags, bcur);
    pass1_partition<<<GP1, 256, 0, stream>>>(drop_msk, adj_row, adj_col, adj_val,
                                             flags, bcur, part);
    bucket_scan<<<1, 512, 0, stream>>>(bcur, gbase, rowptr);
    pass2_csr<<<NBK, 512, 0, stream>>>(part, bcur, gbase, edges, rowptr);
    concat_cast<<<((NNODE * DIM / 4) + 255) / 256, 256, 0, stream>>>(user_emb, item_emb,
                                                                     flags, A);
    gather_first<<<GOUT, 256, 0, stream>>>(A, users, items, flags, out_acc);

    ushort* src = A;
    ushort* dst = B;
    for (int l = 0; l < 3; ++l) {
        spmm_csr<<<GSP, 256, 0, stream>>>(src, rowptr, edges, dst);
        if (l < 2) {
            gather_add<<<GOUT, 256, 0, stream>>>(dst, users, items, flags, out_acc);
        } else {
            gather_final<<<GOUT, 256, 0, stream>>>(dst, users, items, flags, out_acc, out);
        }
        ushort* t = src; src = dst; dst = t;
    }
}

// Round 13
// 202.595 us; speedup vs baseline: 13.1586x; 1.0593x over previous
//
#include <hip/hip_runtime.h>
#include <hip/hip_bf16.h>

// LightGCN encoder on MI355X.
// Device dtypes: user_emb/item_emb/adj_val = float32 (bf16-rounded values),
// adj_row/adj_col = int32, drop_mask = bool/int32 (runtime-detected),
// users/items = int64/int32 (runtime-detected), output = float32.
//
// Round-12 post-mortem: pass1's batched loads were neutral (loads never the
// bottleneck). Remaining cost: phase-B run reservation = 1954 blocks x 293
// SAME-ADDRESS global fetch-adds (~2000-deep per address) serialized at L2,
// with each block barrier-waiting on the slowest return. Round 13: shard the
// reservation counters 8x by blockIdx&7 (bcur[shard][bucket], separate lines;
// bucket region = 8 shard sub-runs of SCAP) -> contention/address drops 8x.
// pass2 iterates 8 sub-runs per bucket. pass1 back to conditional loads.

#define NUSER 100000
#define NITEM 50000
#define NNODE 150000
#define DIM   64
#define NNZ   4000000
#define BATCH 16384

#define BSH2  9             // bucket = row >> 9
#define BRWS  512           // rows per bucket
#define NBK   293           // ceil(150000/512)
#define SCAP  2048          // per-shard sub-run capacity
#define BCAP  16384         // 8 * SCAP records per bucket region
#define CHUNK 2048          // edges per pass1 block (8 per thread)

typedef __hip_bfloat16 bf16;
typedef unsigned short ushort;
typedef unsigned long long u64;
typedef float f4 __attribute__((ext_vector_type(4)));
typedef ushort us4 __attribute__((ext_vector_type(4)));
typedef ushort us8 __attribute__((ext_vector_type(8)));

__device__ __forceinline__ float loadF(const void* p, long i, int isbf16) {
    return isbf16 ? __bfloat162float(((const bf16*)p)[i]) : ((const float*)p)[i];
}

__device__ __forceinline__ bool keepE(const void* mask, int e, int isbyte) {
    return isbyte ? (((const unsigned char*)mask)[e] != 0)
                  : (((const int*)mask)[e] != 0);
}

__device__ __forceinline__ ushort f2bf(float x) {   // round-to-nearest-even
    unsigned u = __float_as_uint(x);
    return (ushort)((u + 0x7FFFu + ((u >> 16) & 1u)) >> 16);
}
__device__ __forceinline__ float bf2f(ushort u) {
    return __uint_as_float((unsigned)u << 16);
}

// val = 2*adj_val in (0,2]; exactly bf16 (inputs bf16-rounded, x2 = exp bump).
// 13-bit code: (e8-95)<<7 | m7.
__device__ __forceinline__ unsigned encodeV(float v) {
    unsigned fb = __float_as_uint(v);
    unsigned e8 = (fb >> 23) & 0xFFu;
    unsigned m7 = (fb >> 16) & 0x7Fu;
    return ((e8 - 95u) << 7) | m7;
}
__device__ __forceinline__ float decodeV(unsigned code) {
    unsigned vb = code >> 18;                      // 13 bits at [18,31)
    return __uint_as_float((((vb >> 7) + 95u) << 23) | ((vb & 0x7Fu) << 16));
}

// ---------------------------------------------------------------------------
// flags[0]: drop_mask is 1-byte. flags[1]: users/items are int64.
// flags[2]: float arrays are bf16 (insurance; expected 0 = f32).
// Also zero-inits the 8*NBK sharded reservation counters.
__global__ __launch_bounds__(256) void detect_fmt(const unsigned int* __restrict__ mask,
                                                  const unsigned int* __restrict__ users,
                                                  const unsigned int* __restrict__ adjv,
                                                  int* __restrict__ flags,
                                                  int* __restrict__ bcur) {
    __shared__ int s[3];
    if (threadIdx.x < 3) s[threadIdx.x] = 0;
    for (int b = threadIdx.x; b < 8 * NBK; b += 256) bcur[b] = 0;
    __syncthreads();
    int c0 = 0, c1 = 0, c2 = 0;
    for (int i = threadIdx.x; i < 4096; i += 256) {
        c0 += (mask[i] > 1u) ? 1 : 0;
        if (i & 1) c1 += (users[i] == 0u) ? 1 : 0;
        unsigned lo = adjv[i] & 0xFFFFu;
        unsigned ex = (lo >> 7) & 0xFFu;
        c2 += ((lo >> 15) == 0u && ex >= 0x60u && ex <= 0x7Fu) ? 1 : 0;
    }
    atomicAdd(&s[0], c0); atomicAdd(&s[1], c1); atomicAdd(&s[2], c2);
    __syncthreads();
    if (threadIdx.x == 0) {
        flags[0] = (s[0] > 16) ? 1 : 0;
        flags[1] = (s[1] > 1024) ? 1 : 0;
        flags[2] = (s[2] > 3000) ? 1 : 0;
    }
}

// pass1: records in registers -> LDS count -> SHARDED run reservation
// (shard = blockIdx&7; bcur[shard*NBK+b]) -> LDS fetch-add + store.
// record u64 = r9(9b) | col(18b)<<9 | valcode(13b)<<27
__global__ __launch_bounds__(256) void pass1_partition(const void* __restrict__ mask,
                                                       const int* __restrict__ rows,
                                                       const int* __restrict__ cols,
                                                       const void* __restrict__ adjv,
                                                       const int* __restrict__ flags,
                                                       int* __restrict__ bcur,
                                                       u64* __restrict__ part) {
    __shared__ int cnt[NBK];
    __shared__ int cur[NBK];
    const int isbyte = flags[0];
    const int isbf = flags[2];
    const int base_e = blockIdx.x * CHUNK;
    const int sh = blockIdx.x & 7;
    u64 rec[8];
    int bkt[8];
    unsigned kept = 0;

    for (int b = threadIdx.x; b < NBK; b += 256) cnt[b] = 0;
    __syncthreads();

    #pragma unroll
    for (int k = 0; k < 8; ++k) {
        int e = base_e + k * 256 + threadIdx.x;
        if (e < NNZ && keepE(mask, e, isbyte)) {
            int r = rows[e];
            float v = 2.0f * loadF(adjv, e, isbf);
            rec[k] = (u64)(unsigned)(r & (BRWS - 1))
                   | ((u64)(unsigned)cols[e] << 9)
                   | ((u64)encodeV(v) << 27);
            bkt[k] = r >> BSH2;
            kept |= 1u << k;
            atomicAdd(&cnt[bkt[k]], 1);
        }
    }
    __syncthreads();

    // reserve shard-local runs (contention/address ~244 instead of ~1954)
    for (int b = threadIdx.x; b < NBK; b += 256)
        cur[b] = cnt[b] ? atomicAdd(&bcur[sh * NBK + b], cnt[b]) : 0;
    __syncthreads();

    #pragma unroll
    for (int k = 0; k < 8; ++k) {
        if (kept & (1u << k)) {
            int pos = atomicAdd(&cur[bkt[k]], 1);   // LDS fetch-add
            if (pos < SCAP)
                part[(size_t)bkt[k] * BCAP + sh * SCAP + pos] = rec[k];
        }
    }
}

// exclusive scan of bucket totals (sum of 8 shard counts) -> gbase
__global__ __launch_bounds__(512) void bucket_scan(const int* __restrict__ bcur,
                                                   int* __restrict__ gbase,
                                                   int* __restrict__ rowptr) {
    __shared__ int s[512];
    int tid = threadIdx.x;
    int v = 0;
    if (tid < NBK) {
        #pragma unroll
        for (int sh = 0; sh < 8; ++sh) {
            int c = bcur[sh * NBK + tid];
            v += (c > SCAP) ? SCAP : c;
        }
    }
    s[tid] = v;
    __syncthreads();
    for (int off = 1; off < 512; off <<= 1) {
        int t = (tid >= off) ? s[tid - off] : 0;
        __syncthreads();
        s[tid] += t;
        __syncthreads();
    }
    if (tid < NBK) gbase[tid] = s[tid] - v;
    if (tid == 0) rowptr[0] = 0;
}

// pass2: one 512-thread WG per bucket; thread = row; iterates 8 shard
// sub-runs. hist + scan + scatter. edge u32 = col(18b) | valcode(13b)<<18
__global__ __launch_bounds__(512) void pass2_csr(const u64* __restrict__ part,
                                                 const int* __restrict__ bcur,
                                                 const int* __restrict__ gbase,
                                                 unsigned* __restrict__ edges,
                                                 int* __restrict__ rowptr) {
    __shared__ int cnt[BRWS];
    __shared__ int ex[BRWS];    // doubles as per-row cursor
    __shared__ int wsum[512];
    __shared__ int ns[8];
    int b = blockIdx.x;
    int tid = threadIdx.x;
    if (tid < 8) {
        int c = bcur[tid * NBK + b];
        ns[tid] = (c > SCAP) ? SCAP : c;
    }
    const u64* bp = part + (size_t)b * BCAP;
    int gb = gbase[b];

    cnt[tid] = 0;
    __syncthreads();
    #pragma unroll
    for (int sh = 0; sh < 8; ++sh) {
        int n = ns[sh];
        const u64* rp = bp + sh * SCAP;
        for (int j = tid; j < n; j += 512)
            atomicAdd(&cnt[(int)(rp[j] & (BRWS - 1))], 1);
    }
    __syncthreads();

    int c = cnt[tid];
    wsum[tid] = c;
    __syncthreads();
    for (int off = 1; off < 512; off <<= 1) {
        int t = (tid >= off) ? wsum[tid - off] : 0;
        __syncthreads();
        wsum[tid] += t;
        __syncthreads();
    }
    int incl = wsum[tid];
    ex[tid] = incl - c;
    int gr = (b << BSH2) + tid;
    if (gr < NNODE) rowptr[gr + 1] = gb + incl;
    __syncthreads();

    #pragma unroll
    for (int sh = 0; sh < 8; ++sh) {
        int n = ns[sh];
        const u64* rp = bp + sh * SCAP;
        for (int j = tid; j < n; j += 512) {
            u64 rec = rp[j];
            int r = (int)(rec & (BRWS - 1));
            int pos = atomicAdd(&ex[r], 1);
            unsigned col = (unsigned)((rec >> 9) & 0x3FFFFu);
            unsigned code = (unsigned)((rec >> 27) & 0x1FFFu);
            edges[gb + pos] = col | (code << 18);
        }
    }
}

// A(bf16) = concat(user_emb, item_emb); thread = one us4 (4 dims)
__global__ __launch_bounds__(256) void concat_cast(const void* __restrict__ ue,
                                                   const void* __restrict__ ie,
                                                   const int* __restrict__ flags,
                                                   ushort* __restrict__ A) {
    long q = (long)blockIdx.x * 256 + threadIdx.x;   // us4 index
    const long NU4 = (long)NUSER * DIM / 4;
    const long NT4 = (long)NNODE * DIM / 4;
    if (q >= NT4) return;
    us4 o;
    if (!flags[2]) {
        const f4* s = (q < NU4) ? (const f4*)ue : (const f4*)ie;
        f4 v = s[(q < NU4) ? q : q - NU4];
        o[0] = f2bf(v.x); o[1] = f2bf(v.y); o[2] = f2bf(v.z); o[3] = f2bf(v.w);
    } else {
        const us4* s = (q < NU4) ? (const us4*)ue : (const us4*)ie;
        o = s[(q < NU4) ? q : q - NU4];
    }
    ((us4*)A)[q] = o;
}

// dst[r,:] = sum_j val[j] * src[col[j],:]   (src/dst bf16, acc f32)
// EIGHTH-wave per row: 8 lanes own the row (lane t = dims [8t,8t+8) via one
// us8 = 16B load); unroll-4 -> 4 gathers in flight per group, 8 rows/wave.
__global__ __launch_bounds__(256) void spmm_csr(const ushort* __restrict__ src,
                                                const int* __restrict__ rowptr,
                                                const unsigned* __restrict__ edges,
                                                ushort* __restrict__ dst) {
    int r = blockIdx.x * 32 + (threadIdx.x >> 3);
    if (r >= NNODE) return;
    int t = threadIdx.x & 7;
    int j0 = rowptr[r], j1 = rowptr[r + 1];
    float acc[8] = {0, 0, 0, 0, 0, 0, 0, 0};
    int j = j0;
    for (; j + 4 <= j1; j += 4) {
        unsigned e0 = edges[j];
        unsigned e1 = edges[j + 1];
        unsigned e2 = edges[j + 2];
        unsigned e3 = edges[j + 3];
        us8 s0 = ((const us8*)(src + (size_t)(e0 & 0x3FFFFu) * DIM))[t];
        us8 s1 = ((const us8*)(src + (size_t)(e1 & 0x3FFFFu) * DIM))[t];
        us8 s2 = ((const us8*)(src + (size_t)(e2 & 0x3FFFFu) * DIM))[t];
        us8 s3 = ((const us8*)(src + (size_t)(e3 & 0x3FFFFu) * DIM))[t];
        float v0 = decodeV(e0), v1 = decodeV(e1);
        float v2 = decodeV(e2), v3 = decodeV(e3);
        #pragma unroll
        for (int d = 0; d < 8; ++d) {
            acc[d] += v0 * bf2f(s0[d]);
            acc[d] += v1 * bf2f(s1[d]);
            acc[d] += v2 * bf2f(s2[d]);
            acc[d] += v3 * bf2f(s3[d]);
        }
    }
    for (; j < j1; ++j) {
        unsigned e0 = edges[j];
        float v0 = decodeV(e0);
        us8 s0 = ((const us8*)(src + (size_t)(e0 & 0x3FFFFu) * DIM))[t];
        #pragma unroll
        for (int d = 0; d < 8; ++d) acc[d] += v0 * bf2f(s0[d]);
    }
    us8 o;
    #pragma unroll
    for (int d = 0; d < 8; ++d) o[d] = f2bf(acc[d]);
    __builtin_nontemporal_store(o, (us8*)(dst + (size_t)r * DIM) + t);
}

__device__ __forceinline__ long nodeOf(int b, const int* users, const int* items, int sh) {
    if (b < BATCH) return (long)users[(size_t)b << sh];
    return (long)NUSER + (long)items[(size_t)(b - BATCH) << sh];
}

// acc[b,:] = table[node(b),:]
__global__ __launch_bounds__(256) void gather_first(const ushort* __restrict__ table,
                                                    const int* __restrict__ users,
                                                    const int* __restrict__ items,
                                                    const int* __restrict__ flags,
                                                    float* __restrict__ acc) {
    int t = blockIdx.x * 256 + threadIdx.x;          // f4/us4 index
    if (t >= 2 * BATCH * DIM / 4) return;
    long node = nodeOf(t >> 4, users, items, flags[1]);
    us4 u = ((const us4*)(table + node * DIM))[t & 15];
    f4 a = {bf2f(u[0]), bf2f(u[1]), bf2f(u[2]), bf2f(u[3])};
    ((f4*)acc)[t] = a;
}

// acc[b,:] += table[node(b),:]
__global__ __launch_bounds__(256) void gather_add(const ushort* __restrict__ table,
                                                  const int* __restrict__ users,
                                                  const int* __restrict__ items,
                                                  const int* __restrict__ flags,
                                                  float* __restrict__ acc) {
    int t = blockIdx.x * 256 + threadIdx.x;
    if (t >= 2 * BATCH * DIM / 4) return;
    long node = nodeOf(t >> 4, users, items, flags[1]);
    us4 u = ((const us4*)(table + node * DIM))[t & 15];
    f4 a = ((f4*)acc)[t];
    a.x += bf2f(u[0]); a.y += bf2f(u[1]); a.z += bf2f(u[2]); a.w += bf2f(u[3]);
    ((f4*)acc)[t] = a;
}

// out = 0.25 * (acc + table[node])
__global__ __launch_bounds__(256) void gather_final(const ushort* __restrict__ table,
                                                    const int* __restrict__ users,
                                                    const int* __restrict__ items,
                                                    const int* __restrict__ flags,
                                                    const float* __restrict__ acc,
                                                    float* __restrict__ out) {
    int t = blockIdx.x * 256 + threadIdx.x;
    if (t >= 2 * BATCH * DIM / 4) return;
    long node = nodeOf(t >> 4, users, items, flags[1]);
    us4 u = ((const us4*)(table + node * DIM))[t & 15];
    f4 a = ((const f4*)acc)[t];
    a.x = 0.25f * (a.x + bf2f(u[0]));
    a.y = 0.25f * (a.y + bf2f(u[1]));
    a.z = 0.25f * (a.z + bf2f(u[2]));
    a.w = 0.25f * (a.w + bf2f(u[3]));
    __builtin_nontemporal_store(a, (f4*)out + t);
}

extern "C" void kernel_launch(void* const* d_in, const int* in_sizes, int n_in,
                              void* d_out, int out_size, void* d_ws, size_t ws_size,
                              hipStream_t stream) {
    const void* user_emb = d_in[0];
    const void* item_emb = d_in[1];
    const void* adj_val  = d_in[2];
    const int*  adj_row  = (const int*)d_in[3];
    const int*  adj_col  = (const int*)d_in[4];
    const void* drop_msk = d_in[5];
    const int*  users    = (const int*)d_in[6];
    const int*  items    = (const int*)d_in[7];
    float* out = (float*)d_out;

    char* ws = (char*)d_ws;
    size_t off = 0;
    int* flags = (int*)(ws + off);            off += 256;
    float* out_acc = (float*)(ws + off);      off += (size_t)2 * BATCH * DIM * 4;   // 8 MB
    ushort* A = (ushort*)(ws + off);          off += (size_t)NNODE * DIM * 2;       // 19.2 MB
    ushort* B = (ushort*)(ws + off);          off += (size_t)NNODE * DIM * 2;       // 19.2 MB
    int* rowptr = (int*)(ws + off);           off += 600064;                        // NNODE+1
    int* bcur = (int*)(ws + off);             off += 16384;                         // 8*NBK ints
    int* gbase = (int*)(ws + off);            off += 2048;
    u64* part = (u64*)(ws + off);             off += (size_t)NBK * BCAP * 8;        // 38.4 MB
    unsigned* edges = (unsigned*)(ws + off);  off += (size_t)NNZ * 4;               // 16 MB

    const int OUTN4 = 2 * BATCH * DIM / 4;            // 524288
    const int GOUT = (OUTN4 + 255) / 256;             // 2048
    const int GP1 = (NNZ + CHUNK - 1) / CHUNK;        // 1954
    const int GSP = (NNODE + 31) / 32;                // 4688

    detect_fmt<<<1, 256, 0, stream>>>((const unsigned int*)drop_msk,
                                      (const unsigned int*)users,
                                      (const unsigned int*)adj_val, flags, bcur);
    pass1_partition<<<GP1, 256, 0, stream>>>(drop_msk, adj_row, adj_col, adj_val,
                                             flags, bcur, part);
    bucket_scan<<<1, 512, 0, stream>>>(bcur, gbase, rowptr);
    pass2_csr<<<NBK, 512, 0, stream>>>(part, bcur, gbase, edges, rowptr);
    concat_cast<<<((NNODE * DIM / 4) + 255) / 256, 256, 0, stream>>>(user_emb, item_emb,
                                                                     flags, A);
    gather_first<<<GOUT, 256, 0, stream>>>(A, users, items, flags, out_acc);

    ushort* src = A;
    ushort* dst = B;
    for (int l = 0; l < 3; ++l) {
        spmm_csr<<<GSP, 256, 0, stream>>>(src, rowptr, edges, dst);
        if (l < 2) {
            gather_add<<<GOUT, 256, 0, stream>>>(dst, users, items, flags, out_acc);
        } else {
            gather_final<<<GOUT, 256, 0, stream>>>(dst, users, items, flags, out_acc, out);
        }
        ushort* t = src; src = dst; dst = t;
    }
}

// Round 14
// 196.389 us; speedup vs baseline: 13.5744x; 1.0316x over previous
//
#include <hip/hip_runtime.h>
#include <hip/hip_bf16.h>

// LightGCN encoder on MI355X.
// Device dtypes: user_emb/item_emb/adj_val = float32 (bf16-rounded values),
// adj_row/adj_col = int32, drop_mask = bool/int32 (runtime-detected),
// users/items = int64/int32 (runtime-detected), output = float32.
//
// Round-14: (a) pass1 uses the phase-A count atomic's RETURN VALUE as the
// within-block offset -> phase C has no LDS atomics at all; (b) pass1 +
// concat_cast + gather_first fused into one launch (independent work;
// concat's streaming fills CUs while pass1 blocks wait on atomics);
// (c) bucket_scan folded into pass2 (each block recomputes the 293-bucket
// prefix in LDS). 9 launches total.

#define NUSER 100000
#define NITEM 50000
#define NNODE 150000
#define DIM   64
#define NNZ   4000000
#define BATCH 16384

#define BSH2  9             // bucket = row >> 9
#define BRWS  512           // rows per bucket
#define NBK   293           // ceil(150000/512)
#define SCAP  2048          // per-shard sub-run capacity
#define BCAP  16384         // 8 * SCAP records per bucket region
#define CHUNK 2048          // edges per pass1 block (8 per thread)
#define GP1   1954          // ceil(NNZ/CHUNK)
#define GCC   9375          // ceil(NNODE*DIM/4/256)  concat blocks
#define GGF   2048          // gather_first blocks

typedef __hip_bfloat16 bf16;
typedef unsigned short ushort;
typedef unsigned long long u64;
typedef float f4 __attribute__((ext_vector_type(4)));
typedef ushort us4 __attribute__((ext_vector_type(4)));
typedef ushort us8 __attribute__((ext_vector_type(8)));

__device__ __forceinline__ float loadF(const void* p, long i, int isbf16) {
    return isbf16 ? __bfloat162float(((const bf16*)p)[i]) : ((const float*)p)[i];
}

__device__ __forceinline__ bool keepE(const void* mask, int e, int isbyte) {
    return isbyte ? (((const unsigned char*)mask)[e] != 0)
                  : (((const int*)mask)[e] != 0);
}

__device__ __forceinline__ ushort f2bf(float x) {   // round-to-nearest-even
    unsigned u = __float_as_uint(x);
    return (ushort)((u + 0x7FFFu + ((u >> 16) & 1u)) >> 16);
}
__device__ __forceinline__ float bf2f(ushort u) {
    return __uint_as_float((unsigned)u << 16);
}

// val = 2*adj_val in (0,2]; exactly bf16. 13-bit code: (e8-95)<<7 | m7.
__device__ __forceinline__ unsigned encodeV(float v) {
    unsigned fb = __float_as_uint(v);
    unsigned e8 = (fb >> 23) & 0xFFu;
    unsigned m7 = (fb >> 16) & 0x7Fu;
    return ((e8 - 95u) << 7) | m7;
}
__device__ __forceinline__ float decodeV(unsigned code) {
    unsigned vb = code >> 18;                      // 13 bits at [18,31)
    return __uint_as_float((((vb >> 7) + 95u) << 23) | ((vb & 0x7Fu) << 16));
}

__device__ __forceinline__ long nodeOf(int b, const int* users, const int* items, int sh) {
    if (b < BATCH) return (long)users[(size_t)b << sh];
    return (long)NUSER + (long)items[(size_t)(b - BATCH) << sh];
}

// ---------------------------------------------------------------------------
// flags[0]: drop_mask is 1-byte. flags[1]: users/items are int64.
// flags[2]: float arrays are bf16. Also zero-inits sharded counters.
__global__ __launch_bounds__(256) void detect_fmt(const unsigned int* __restrict__ mask,
                                                  const unsigned int* __restrict__ users,
                                                  const unsigned int* __restrict__ adjv,
                                                  int* __restrict__ flags,
                                                  int* __restrict__ bcur) {
    __shared__ int s[3];
    if (threadIdx.x < 3) s[threadIdx.x] = 0;
    for (int b = threadIdx.x; b < 8 * NBK; b += 256) bcur[b] = 0;
    __syncthreads();
    int c0 = 0, c1 = 0, c2 = 0;
    for (int i = threadIdx.x; i < 4096; i += 256) {
        c0 += (mask[i] > 1u) ? 1 : 0;
        if (i & 1) c1 += (users[i] == 0u) ? 1 : 0;
        unsigned lo = adjv[i] & 0xFFFFu;
        unsigned ex = (lo >> 7) & 0xFFu;
        c2 += ((lo >> 15) == 0u && ex >= 0x60u && ex <= 0x7Fu) ? 1 : 0;
    }
    atomicAdd(&s[0], c0); atomicAdd(&s[1], c1); atomicAdd(&s[2], c2);
    __syncthreads();
    if (threadIdx.x == 0) {
        flags[0] = (s[0] > 16) ? 1 : 0;
        flags[1] = (s[1] > 1024) ? 1 : 0;
        flags[2] = (s[2] > 3000) ? 1 : 0;
    }
}

// ---------------------------------------------------------------------------
// Fused prep: blocks [0,GP1) = pass1 partition; [GP1,GP1+GCC) = concat_cast;
// [GP1+GCC, +GGF) = gather_first (reads raw inputs; same values as A).
__global__ __launch_bounds__(256) void prep_fused(const void* __restrict__ mask,
                                                  const int* __restrict__ rows,
                                                  const int* __restrict__ cols,
                                                  const void* __restrict__ adjv,
                                                  const void* __restrict__ ue,
                                                  const void* __restrict__ ie,
                                                  const int* __restrict__ users,
                                                  const int* __restrict__ items,
                                                  const int* __restrict__ flags,
                                                  int* __restrict__ bcur,
                                                  u64* __restrict__ part,
                                                  ushort* __restrict__ A,
                                                  float* __restrict__ out_acc) {
    __shared__ int cnt[NBK];
    __shared__ int cur[NBK];
    const int blk = blockIdx.x;

    if (blk < GP1) {
        // ---- pass1: partition kept edges; single LDS atomic per edge ----
        const int isbyte = flags[0];
        const int isbf = flags[2];
        const int base_e = blk * CHUNK;
        const int sh = blk & 7;
        u64 rec[8];
        int bkt[8], off[8];
        unsigned kept = 0;

        for (int b = threadIdx.x; b < NBK; b += 256) cnt[b] = 0;
        __syncthreads();

        #pragma unroll
        for (int k = 0; k < 8; ++k) {
            int e = base_e + k * 256 + threadIdx.x;
            if (e < NNZ && keepE(mask, e, isbyte)) {
                int r = rows[e];
                float v = 2.0f * loadF(adjv, e, isbf);
                rec[k] = (u64)(unsigned)(r & (BRWS - 1))
                       | ((u64)(unsigned)cols[e] << 9)
                       | ((u64)encodeV(v) << 27);
                bkt[k] = r >> BSH2;
                off[k] = atomicAdd(&cnt[bkt[k]], 1);   // offset = count return
                kept |= 1u << k;
            }
        }
        __syncthreads();

        for (int b = threadIdx.x; b < NBK; b += 256)
            cur[b] = cnt[b] ? atomicAdd(&bcur[sh * NBK + b], cnt[b]) : 0;
        __syncthreads();

        #pragma unroll
        for (int k = 0; k < 8; ++k) {
            if (kept & (1u << k)) {
                int pos = cur[bkt[k]] + off[k];        // no atomic
                if (pos < SCAP)
                    part[(size_t)bkt[k] * BCAP + sh * SCAP + pos] = rec[k];
            }
        }
    } else if (blk < GP1 + GCC) {
        // ---- concat_cast: A(bf16) = concat(ue, ie) ----
        long q = (long)(blk - GP1) * 256 + threadIdx.x;   // us4 index
        const long NU4 = (long)NUSER * DIM / 4;
        const long NT4 = (long)NNODE * DIM / 4;
        if (q >= NT4) return;
        us4 o;
        if (!flags[2]) {
            const f4* s = (q < NU4) ? (const f4*)ue : (const f4*)ie;
            f4 v = s[(q < NU4) ? q : q - NU4];
            o[0] = f2bf(v.x); o[1] = f2bf(v.y); o[2] = f2bf(v.z); o[3] = f2bf(v.w);
        } else {
            const us4* s = (q < NU4) ? (const us4*)ue : (const us4*)ie;
            o = s[(q < NU4) ? q : q - NU4];
        }
        ((us4*)A)[q] = o;
    } else {
        // ---- gather_first: out_acc[b,:] = input[node(b),:] (raw inputs) ----
        int t = (blk - GP1 - GCC) * 256 + threadIdx.x;    // f4 index
        if (t >= 2 * BATCH * DIM / 4) return;
        long node = nodeOf(t >> 4, users, items, flags[1]);
        int d4 = t & 15;
        const void* src = (node < NUSER) ? ue : ie;
        long q = (node < NUSER ? node : node - NUSER) * 16 + d4;  // us4/f4 idx
        f4 a;
        if (!flags[2]) {
            a = ((const f4*)src)[q];
        } else {
            us4 u = ((const us4*)src)[q];
            a.x = bf2f(u[0]); a.y = bf2f(u[1]); a.z = bf2f(u[2]); a.w = bf2f(u[3]);
        }
        ((f4*)out_acc)[t] = a;
    }
}

// ---------------------------------------------------------------------------
// pass2 (+ folded bucket scan): one 512-thread WG per bucket; thread = row.
// Computes gbase via in-block prefix over bucket totals, then hist + scan +
// scatter of the 8 shard sub-runs. edge u32 = col(18b) | valcode(13b)<<18
__global__ __launch_bounds__(512) void pass2_csr(const u64* __restrict__ part,
                                                 const int* __restrict__ bcur,
                                                 unsigned* __restrict__ edges,
                                                 int* __restrict__ rowptr) {
    __shared__ int tot[512];
    __shared__ int cnt[BRWS];
    __shared__ int ex[BRWS];    // doubles as per-row cursor
    __shared__ int wsum[512];
    __shared__ int ns[8];
    __shared__ int gb_s, n_s;
    int b = blockIdx.x;
    int tid = threadIdx.x;

    // bucket totals (all buckets) -> prefix at b
    int v = 0;
    if (tid < NBK) {
        #pragma unroll
        for (int sh = 0; sh < 8; ++sh) {
            int c = bcur[sh * NBK + tid];
            v += (c > SCAP) ? SCAP : c;
        }
    }
    tot[tid] = v;
    if (tid < 8) {
        int c = bcur[tid * NBK + b];
        ns[tid] = (c > SCAP) ? SCAP : c;
    }
    cnt[tid] = 0;
    __syncthreads();
    for (int off = 1; off < 512; off <<= 1) {
        int t = (tid >= off) ? tot[tid - off] : 0;
        __syncthreads();
        tot[tid] += t;
        __syncthreads();
    }
    if (tid == 0) {
        gb_s = (b > 0) ? tot[b - 1] : 0;
        n_s = tot[b] - ((b > 0) ? tot[b - 1] : 0);
        if (b == 0) rowptr[0] = 0;
    }
    __syncthreads();
    const int gb = gb_s;
    const u64* bp = part + (size_t)b * BCAP;

    #pragma unroll
    for (int sh = 0; sh < 8; ++sh) {
        int n = ns[sh];
        const u64* rp = bp + sh * SCAP;
        for (int j = tid; j < n; j += 512)
            atomicAdd(&cnt[(int)(rp[j] & (BRWS - 1))], 1);
    }
    __syncthreads();

    int c = cnt[tid];
    wsum[tid] = c;
    __syncthreads();
    for (int off = 1; off < 512; off <<= 1) {
        int t = (tid >= off) ? wsum[tid - off] : 0;
        __syncthreads();
        wsum[tid] += t;
        __syncthreads();
    }
    int incl = wsum[tid];
    ex[tid] = incl - c;
    int gr = (b << BSH2) + tid;
    if (gr < NNODE) rowptr[gr + 1] = gb + incl;
    __syncthreads();

    #pragma unroll
    for (int sh = 0; sh < 8; ++sh) {
        int n = ns[sh];
        const u64* rp = bp + sh * SCAP;
        for (int j = tid; j < n; j += 512) {
            u64 rec = rp[j];
            int r = (int)(rec & (BRWS - 1));
            int pos = atomicAdd(&ex[r], 1);
            unsigned col = (unsigned)((rec >> 9) & 0x3FFFFu);
            unsigned code = (unsigned)((rec >> 27) & 0x1FFFu);
            edges[gb + pos] = col | (code << 18);
        }
    }
}

// dst[r,:] = sum_j val[j] * src[col[j],:]   (src/dst bf16, acc f32)
// EIGHTH-wave per row: 8 lanes own the row (lane t = dims [8t,8t+8) via one
// us8 = 16B load); unroll-4 -> 4 gathers in flight per group, 8 rows/wave.
__global__ __launch_bounds__(256) void spmm_csr(const ushort* __restrict__ src,
                                                const int* __restrict__ rowptr,
                                                const unsigned* __restrict__ edges,
                                                ushort* __restrict__ dst) {
    int r = blockIdx.x * 32 + (threadIdx.x >> 3);
    if (r >= NNODE) return;
    int t = threadIdx.x & 7;
    int j0 = rowptr[r], j1 = rowptr[r + 1];
    float acc[8] = {0, 0, 0, 0, 0, 0, 0, 0};
    int j = j0;
    for (; j + 4 <= j1; j += 4) {
        unsigned e0 = edges[j];
        unsigned e1 = edges[j + 1];
        unsigned e2 = edges[j + 2];
        unsigned e3 = edges[j + 3];
        us8 s0 = ((const us8*)(src + (size_t)(e0 & 0x3FFFFu) * DIM))[t];
        us8 s1 = ((const us8*)(src + (size_t)(e1 & 0x3FFFFu) * DIM))[t];
        us8 s2 = ((const us8*)(src + (size_t)(e2 & 0x3FFFFu) * DIM))[t];
        us8 s3 = ((const us8*)(src + (size_t)(e3 & 0x3FFFFu) * DIM))[t];
        float v0 = decodeV(e0), v1 = decodeV(e1);
        float v2 = decodeV(e2), v3 = decodeV(e3);
        #pragma unroll
        for (int d = 0; d < 8; ++d) {
            acc[d] += v0 * bf2f(s0[d]);
            acc[d] += v1 * bf2f(s1[d]);
            acc[d] += v2 * bf2f(s2[d]);
            acc[d] += v3 * bf2f(s3[d]);
        }
    }
    for (; j < j1; ++j) {
        unsigned e0 = edges[j];
        float v0 = decodeV(e0);
        us8 s0 = ((const us8*)(src + (size_t)(e0 & 0x3FFFFu) * DIM))[t];
        #pragma unroll
        for (int d = 0; d < 8; ++d) acc[d] += v0 * bf2f(s0[d]);
    }
    us8 o;
    #pragma unroll
    for (int d = 0; d < 8; ++d) o[d] = f2bf(acc[d]);
    __builtin_nontemporal_store(o, (us8*)(dst + (size_t)r * DIM) + t);
}

// acc[b,:] += table[node(b),:]
__global__ __launch_bounds__(256) void gather_add(const ushort* __restrict__ table,
                                                  const int* __restrict__ users,
                                                  const int* __restrict__ items,
                                                  const int* __restrict__ flags,
                                                  float* __restrict__ acc) {
    int t = blockIdx.x * 256 + threadIdx.x;
    if (t >= 2 * BATCH * DIM / 4) return;
    long node = nodeOf(t >> 4, users, items, flags[1]);
    us4 u = ((const us4*)(table + node * DIM))[t & 15];
    f4 a = ((f4*)acc)[t];
    a.x += bf2f(u[0]); a.y += bf2f(u[1]); a.z += bf2f(u[2]); a.w += bf2f(u[3]);
    ((f4*)acc)[t] = a;
}

// out = 0.25 * (acc + table[node])
__global__ __launch_bounds__(256) void gather_final(const ushort* __restrict__ table,
                                                    const int* __restrict__ users,
                                                    const int* __restrict__ items,
                                                    const int* __restrict__ flags,
                                                    const float* __restrict__ acc,
                                                    float* __restrict__ out) {
    int t = blockIdx.x * 256 + threadIdx.x;
    if (t >= 2 * BATCH * DIM / 4) return;
    long node = nodeOf(t >> 4, users, items, flags[1]);
    us4 u = ((const us4*)(table + node * DIM))[t & 15];
    f4 a = ((const f4*)acc)[t];
    a.x = 0.25f * (a.x + bf2f(u[0]));
    a.y = 0.25f * (a.y + bf2f(u[1]));
    a.z = 0.25f * (a.z + bf2f(u[2]));
    a.w = 0.25f * (a.w + bf2f(u[3]));
    __builtin_nontemporal_store(a, (f4*)out + t);
}

extern "C" void kernel_launch(void* const* d_in, const int* in_sizes, int n_in,
                              void* d_out, int out_size, void* d_ws, size_t ws_size,
                              hipStream_t stream) {
    const void* user_emb = d_in[0];
    const void* item_emb = d_in[1];
    const void* adj_val  = d_in[2];
    const int*  adj_row  = (const int*)d_in[3];
    const int*  adj_col  = (const int*)d_in[4];
    const void* drop_msk = d_in[5];
    const int*  users    = (const int*)d_in[6];
    const int*  items    = (const int*)d_in[7];
    float* out = (float*)d_out;

    char* ws = (char*)d_ws;
    size_t off = 0;
    int* flags = (int*)(ws + off);            off += 256;
    float* out_acc = (float*)(ws + off);      off += (size_t)2 * BATCH * DIM * 4;   // 8 MB
    ushort* A = (ushort*)(ws + off);          off += (size_t)NNODE * DIM * 2;       // 19.2 MB
    ushort* B = (ushort*)(ws + off);          off += (size_t)NNODE * DIM * 2;       // 19.2 MB
    int* rowptr = (int*)(ws + off);           off += 600064;                        // NNODE+1
    int* bcur = (int*)(ws + off);             off += 16384;                         // 8*NBK ints
    u64* part = (u64*)(ws + off);             off += (size_t)NBK * BCAP * 8;        // 38.4 MB
    unsigned* edges = (unsigned*)(ws + off);  off += (size_t)NNZ * 4;               // 16 MB

    const int OUTN4 = 2 * BATCH * DIM / 4;            // 524288
    const int GOUT = (OUTN4 + 255) / 256;             // 2048
    const int GSP = (NNODE + 31) / 32;                // 4688

    detect_fmt<<<1, 256, 0, stream>>>((const unsigned int*)drop_msk,
                                      (const unsigned int*)users,
                                      (const unsigned int*)adj_val, flags, bcur);
    prep_fused<<<GP1 + GCC + GGF, 256, 0, stream>>>(drop_msk, adj_row, adj_col,
                                                    adj_val, user_emb, item_emb,
                                                    users, items, flags, bcur,
                                                    part, A, out_acc);
    pass2_csr<<<NBK, 512, 0, stream>>>(part, bcur, edges, rowptr);

    ushort* src = A;
    ushort* dst = B;
    for (int l = 0; l < 3; ++l) {
        spmm_csr<<<GSP, 256, 0, stream>>>(src, rowptr, edges, dst);
        if (l < 2) {
            gather_add<<<GOUT, 256, 0, stream>>>(dst, users, items, flags, out_acc);
        } else {
            gather_final<<<GOUT, 256, 0, stream>>>(dst, users, items, flags, out_acc, out);
        }
        ushort* t = src; src = dst; dst = t;
    }
}

// Round 15
// 188.734 us; speedup vs baseline: 14.1250x; 1.0406x over previous
//
#include <hip/hip_runtime.h>
#include <hip/hip_bf16.h>

// LightGCN encoder on MI355X.
// Device dtypes: user_emb/item_emb/adj_val = float32 (bf16-rounded values),
// adj_row/adj_col = int32, drop_mask = bool/int32 (runtime-detected),
// users/items = int64/int32 (runtime-detected), output = float32.
//
// Round-15: (a) pass1 blocks 512-thread / CHUNK 4096 -> 977 blocks: halves
// the sharded reservation atomics (573K -> 287K) and per-block fixed phases;
// (b) gather_add fused into the FOLLOWING spmm launch (gather reads that
// spmm's src == previous layer's output; spmm writes the other buffer, no
// hazard) -> 2 launches removed. 7 launches total.

#define NUSER 100000
#define NITEM 50000
#define NNODE 150000
#define DIM   64
#define NNZ   4000000
#define BATCH 16384

#define BSH2  9             // bucket = row >> 9
#define BRWS  512           // rows per bucket
#define NBK   293           // ceil(150000/512)
#define SCAP  2048          // per-shard sub-run capacity
#define BCAP  16384         // 8 * SCAP records per bucket region
#define CHUNK 4096          // edges per pass1 block (8 per 512 threads)
#define GP1   977           // ceil(NNZ/CHUNK)
#define GCC   4688          // ceil(NNODE*DIM/4/512)  concat blocks (512t)
#define GGF   1024          // gather_first blocks (512t)
#define GSP   4688          // ceil(NNODE/32) spmm blocks (256t)
#define GOUT  2048          // gather blocks (256t)

typedef __hip_bfloat16 bf16;
typedef unsigned short ushort;
typedef unsigned long long u64;
typedef float f4 __attribute__((ext_vector_type(4)));
typedef ushort us4 __attribute__((ext_vector_type(4)));
typedef ushort us8 __attribute__((ext_vector_type(8)));

__device__ __forceinline__ float loadF(const void* p, long i, int isbf16) {
    return isbf16 ? __bfloat162float(((const bf16*)p)[i]) : ((const float*)p)[i];
}

__device__ __forceinline__ bool keepE(const void* mask, int e, int isbyte) {
    return isbyte ? (((const unsigned char*)mask)[e] != 0)
                  : (((const int*)mask)[e] != 0);
}

__device__ __forceinline__ ushort f2bf(float x) {   // round-to-nearest-even
    unsigned u = __float_as_uint(x);
    return (ushort)((u + 0x7FFFu + ((u >> 16) & 1u)) >> 16);
}
__device__ __forceinline__ float bf2f(ushort u) {
    return __uint_as_float((unsigned)u << 16);
}

// val = 2*adj_val in (0,2]; exactly bf16. 13-bit code: (e8-95)<<7 | m7.
__device__ __forceinline__ unsigned encodeV(float v) {
    unsigned fb = __float_as_uint(v);
    unsigned e8 = (fb >> 23) & 0xFFu;
    unsigned m7 = (fb >> 16) & 0x7Fu;
    return ((e8 - 95u) << 7) | m7;
}
__device__ __forceinline__ float decodeV(unsigned code) {
    unsigned vb = code >> 18;                      // 13 bits at [18,31)
    return __uint_as_float((((vb >> 7) + 95u) << 23) | ((vb & 0x7Fu) << 16));
}

__device__ __forceinline__ long nodeOf(int b, const int* users, const int* items, int sh) {
    if (b < BATCH) return (long)users[(size_t)b << sh];
    return (long)NUSER + (long)items[(size_t)(b - BATCH) << sh];
}

// ---------------------------------------------------------------------------
// flags[0]: drop_mask is 1-byte. flags[1]: users/items are int64.
// flags[2]: float arrays are bf16. Also zero-inits sharded counters.
__global__ __launch_bounds__(256) void detect_fmt(const unsigned int* __restrict__ mask,
                                                  const unsigned int* __restrict__ users,
                                                  const unsigned int* __restrict__ adjv,
                                                  int* __restrict__ flags,
                                                  int* __restrict__ bcur) {
    __shared__ int s[3];
    if (threadIdx.x < 3) s[threadIdx.x] = 0;
    for (int b = threadIdx.x; b < 8 * NBK; b += 256) bcur[b] = 0;
    __syncthreads();
    int c0 = 0, c1 = 0, c2 = 0;
    for (int i = threadIdx.x; i < 4096; i += 256) {
        c0 += (mask[i] > 1u) ? 1 : 0;
        if (i & 1) c1 += (users[i] == 0u) ? 1 : 0;
        unsigned lo = adjv[i] & 0xFFFFu;
        unsigned ex = (lo >> 7) & 0xFFu;
        c2 += ((lo >> 15) == 0u && ex >= 0x60u && ex <= 0x7Fu) ? 1 : 0;
    }
    atomicAdd(&s[0], c0); atomicAdd(&s[1], c1); atomicAdd(&s[2], c2);
    __syncthreads();
    if (threadIdx.x == 0) {
        flags[0] = (s[0] > 16) ? 1 : 0;
        flags[1] = (s[1] > 1024) ? 1 : 0;
        flags[2] = (s[2] > 3000) ? 1 : 0;
    }
}

// ---------------------------------------------------------------------------
// Fused prep (512 threads): blocks [0,GP1) = pass1; [GP1,GP1+GCC) = concat;
// [GP1+GCC, +GGF) = gather_first (reads raw inputs).
__global__ __launch_bounds__(512) void prep_fused(const void* __restrict__ mask,
                                                  const int* __restrict__ rows,
                                                  const int* __restrict__ cols,
                                                  const void* __restrict__ adjv,
                                                  const void* __restrict__ ue,
                                                  const void* __restrict__ ie,
                                                  const int* __restrict__ users,
                                                  const int* __restrict__ items,
                                                  const int* __restrict__ flags,
                                                  int* __restrict__ bcur,
                                                  u64* __restrict__ part,
                                                  ushort* __restrict__ A,
                                                  float* __restrict__ out_acc) {
    __shared__ int cnt[NBK];
    __shared__ int cur[NBK];
    const int blk = blockIdx.x;
    const int tid = threadIdx.x;

    if (blk < GP1) {
        // ---- pass1: partition kept edges; single LDS atomic per edge ----
        const int isbyte = flags[0];
        const int isbf = flags[2];
        const int base_e = blk * CHUNK;
        const int sh = blk & 7;
        u64 rec[8];
        int bkt[8], off[8];
        unsigned kept = 0;

        for (int b = tid; b < NBK; b += 512) cnt[b] = 0;
        __syncthreads();

        #pragma unroll
        for (int k = 0; k < 8; ++k) {
            int e = base_e + k * 512 + tid;
            if (e < NNZ && keepE(mask, e, isbyte)) {
                int r = rows[e];
                float v = 2.0f * loadF(adjv, e, isbf);
                rec[k] = (u64)(unsigned)(r & (BRWS - 1))
                       | ((u64)(unsigned)cols[e] << 9)
                       | ((u64)encodeV(v) << 27);
                bkt[k] = r >> BSH2;
                off[k] = atomicAdd(&cnt[bkt[k]], 1);   // offset = count return
                kept |= 1u << k;
            }
        }
        __syncthreads();

        for (int b = tid; b < NBK; b += 512)
            cur[b] = cnt[b] ? atomicAdd(&bcur[sh * NBK + b], cnt[b]) : 0;
        __syncthreads();

        #pragma unroll
        for (int k = 0; k < 8; ++k) {
            if (kept & (1u << k)) {
                int pos = cur[bkt[k]] + off[k];        // no atomic
                if (pos < SCAP)
                    part[(size_t)bkt[k] * BCAP + sh * SCAP + pos] = rec[k];
            }
        }
    } else if (blk < GP1 + GCC) {
        // ---- concat_cast: A(bf16) = concat(ue, ie) ----
        long q = (long)(blk - GP1) * 512 + tid;           // us4 index
        const long NU4 = (long)NUSER * DIM / 4;
        const long NT4 = (long)NNODE * DIM / 4;
        if (q >= NT4) return;
        us4 o;
        if (!flags[2]) {
            const f4* s = (q < NU4) ? (const f4*)ue : (const f4*)ie;
            f4 v = s[(q < NU4) ? q : q - NU4];
            o[0] = f2bf(v.x); o[1] = f2bf(v.y); o[2] = f2bf(v.z); o[3] = f2bf(v.w);
        } else {
            const us4* s = (q < NU4) ? (const us4*)ue : (const us4*)ie;
            o = s[(q < NU4) ? q : q - NU4];
        }
        ((us4*)A)[q] = o;
    } else {
        // ---- gather_first: out_acc[b,:] = input[node(b),:] ----
        int t = (blk - GP1 - GCC) * 512 + tid;            // f4 index
        if (t >= 2 * BATCH * DIM / 4) return;
        long node = nodeOf(t >> 4, users, items, flags[1]);
        int d4 = t & 15;
        const void* src = (node < NUSER) ? ue : ie;
        long q = (node < NUSER ? node : node - NUSER) * 16 + d4;
        f4 a;
        if (!flags[2]) {
            a = ((const f4*)src)[q];
        } else {
            us4 u = ((const us4*)src)[q];
            a.x = bf2f(u[0]); a.y = bf2f(u[1]); a.z = bf2f(u[2]); a.w = bf2f(u[3]);
        }
        ((f4*)out_acc)[t] = a;
    }
}

// ---------------------------------------------------------------------------
// pass2 (+ folded bucket scan): one 512-thread WG per bucket; thread = row.
__global__ __launch_bounds__(512) void pass2_csr(const u64* __restrict__ part,
                                                 const int* __restrict__ bcur,
                                                 unsigned* __restrict__ edges,
                                                 int* __restrict__ rowptr) {
    __shared__ int tot[512];
    __shared__ int cnt[BRWS];
    __shared__ int ex[BRWS];    // doubles as per-row cursor
    __shared__ int wsum[512];
    __shared__ int ns[8];
    __shared__ int gb_s;
    int b = blockIdx.x;
    int tid = threadIdx.x;

    int v = 0;
    if (tid < NBK) {
        #pragma unroll
        for (int sh = 0; sh < 8; ++sh) {
            int c = bcur[sh * NBK + tid];
            v += (c > SCAP) ? SCAP : c;
        }
    }
    tot[tid] = v;
    if (tid < 8) {
        int c = bcur[tid * NBK + b];
        ns[tid] = (c > SCAP) ? SCAP : c;
    }
    cnt[tid] = 0;
    __syncthreads();
    for (int off = 1; off < 512; off <<= 1) {
        int t = (tid >= off) ? tot[tid - off] : 0;
        __syncthreads();
        tot[tid] += t;
        __syncthreads();
    }
    if (tid == 0) {
        gb_s = (b > 0) ? tot[b - 1] : 0;
        if (b == 0) rowptr[0] = 0;
    }
    __syncthreads();
    const int gb = gb_s;
    const u64* bp = part + (size_t)b * BCAP;

    #pragma unroll
    for (int sh = 0; sh < 8; ++sh) {
        int n = ns[sh];
        const u64* rp = bp + sh * SCAP;
        for (int j = tid; j < n; j += 512)
            atomicAdd(&cnt[(int)(rp[j] & (BRWS - 1))], 1);
    }
    __syncthreads();

    int c = cnt[tid];
    wsum[tid] = c;
    __syncthreads();
    for (int off = 1; off < 512; off <<= 1) {
        int t = (tid >= off) ? wsum[tid - off] : 0;
        __syncthreads();
        wsum[tid] += t;
        __syncthreads();
    }
    int incl = wsum[tid];
    ex[tid] = incl - c;
    int gr = (b << BSH2) + tid;
    if (gr < NNODE) rowptr[gr + 1] = gb + incl;
    __syncthreads();

    #pragma unroll
    for (int sh = 0; sh < 8; ++sh) {
        int n = ns[sh];
        const u64* rp = bp + sh * SCAP;
        for (int j = tid; j < n; j += 512) {
            u64 rec = rp[j];
            int r = (int)(rec & (BRWS - 1));
            int pos = atomicAdd(&ex[r], 1);
            unsigned col = (unsigned)((rec >> 9) & 0x3FFFFu);
            unsigned code = (unsigned)((rec >> 27) & 0x1FFFu);
            edges[gb + pos] = col | (code << 18);
        }
    }
}

// ---------------------------------------------------------------------------
// spmm (+ optionally fused gather_add of the PREVIOUS layer, which reads the
// same src table). Blocks [0,GSP) = spmm eighth-wave-per-row; [GSP,+GOUT) =
// acc[b,:] += src[node(b),:]. dst is the other buffer -> no hazard.
__global__ __launch_bounds__(256) void spmm_fused(const ushort* __restrict__ src,
                                                  const int* __restrict__ rowptr,
                                                  const unsigned* __restrict__ edges,
                                                  ushort* __restrict__ dst,
                                                  const int* __restrict__ users,
                                                  const int* __restrict__ items,
                                                  const int* __restrict__ flags,
                                                  float* __restrict__ acc) {
    if (blockIdx.x >= GSP) {
        int t = (blockIdx.x - GSP) * 256 + threadIdx.x;   // f4 index
        if (t >= 2 * BATCH * DIM / 4) return;
        long node = nodeOf(t >> 4, users, items, flags[1]);
        us4 u = ((const us4*)(src + node * DIM))[t & 15];
        f4 a = ((f4*)acc)[t];
        a.x += bf2f(u[0]); a.y += bf2f(u[1]); a.z += bf2f(u[2]); a.w += bf2f(u[3]);
        ((f4*)acc)[t] = a;
        return;
    }
    int r = blockIdx.x * 32 + (threadIdx.x >> 3);
    if (r >= NNODE) return;
    int t = threadIdx.x & 7;
    int j0 = rowptr[r], j1 = rowptr[r + 1];
    float acc8[8] = {0, 0, 0, 0, 0, 0, 0, 0};
    int j = j0;
    for (; j + 4 <= j1; j += 4) {
        unsigned e0 = edges[j];
        unsigned e1 = edges[j + 1];
        unsigned e2 = edges[j + 2];
        unsigned e3 = edges[j + 3];
        us8 s0 = ((const us8*)(src + (size_t)(e0 & 0x3FFFFu) * DIM))[t];
        us8 s1 = ((const us8*)(src + (size_t)(e1 & 0x3FFFFu) * DIM))[t];
        us8 s2 = ((const us8*)(src + (size_t)(e2 & 0x3FFFFu) * DIM))[t];
        us8 s3 = ((const us8*)(src + (size_t)(e3 & 0x3FFFFu) * DIM))[t];
        float v0 = decodeV(e0), v1 = decodeV(e1);
        float v2 = decodeV(e2), v3 = decodeV(e3);
        #pragma unroll
        for (int d = 0; d < 8; ++d) {
            acc8[d] += v0 * bf2f(s0[d]);
            acc8[d] += v1 * bf2f(s1[d]);
            acc8[d] += v2 * bf2f(s2[d]);
            acc8[d] += v3 * bf2f(s3[d]);
        }
    }
    for (; j < j1; ++j) {
        unsigned e0 = edges[j];
        float v0 = decodeV(e0);
        us8 s0 = ((const us8*)(src + (size_t)(e0 & 0x3FFFFu) * DIM))[t];
        #pragma unroll
        for (int d = 0; d < 8; ++d) acc8[d] += v0 * bf2f(s0[d]);
    }
    us8 o;
    #pragma unroll
    for (int d = 0; d < 8; ++d) o[d] = f2bf(acc8[d]);
    __builtin_nontemporal_store(o, (us8*)(dst + (size_t)r * DIM) + t);
}

// out = 0.25 * (acc + table[node])
__global__ __launch_bounds__(256) void gather_final(const ushort* __restrict__ table,
                                                    const int* __restrict__ users,
                                                    const int* __restrict__ items,
                                                    const int* __restrict__ flags,
                                                    const float* __restrict__ acc,
                                                    float* __restrict__ out) {
    int t = blockIdx.x * 256 + threadIdx.x;
    if (t >= 2 * BATCH * DIM / 4) return;
    long node = nodeOf(t >> 4, users, items, flags[1]);
    us4 u = ((const us4*)(table + node * DIM))[t & 15];
    f4 a = ((const f4*)acc)[t];
    a.x = 0.25f * (a.x + bf2f(u[0]));
    a.y = 0.25f * (a.y + bf2f(u[1]));
    a.z = 0.25f * (a.z + bf2f(u[2]));
    a.w = 0.25f * (a.w + bf2f(u[3]));
    __builtin_nontemporal_store(a, (f4*)out + t);
}

extern "C" void kernel_launch(void* const* d_in, const int* in_sizes, int n_in,
                              void* d_out, int out_size, void* d_ws, size_t ws_size,
                              hipStream_t stream) {
    const void* user_emb = d_in[0];
    const void* item_emb = d_in[1];
    const void* adj_val  = d_in[2];
    const int*  adj_row  = (const int*)d_in[3];
    const int*  adj_col  = (const int*)d_in[4];
    const void* drop_msk = d_in[5];
    const int*  users    = (const int*)d_in[6];
    const int*  items    = (const int*)d_in[7];
    float* out = (float*)d_out;

    char* ws = (char*)d_ws;
    size_t off = 0;
    int* flags = (int*)(ws + off);            off += 256;
    float* out_acc = (float*)(ws + off);      off += (size_t)2 * BATCH * DIM * 4;   // 8 MB
    ushort* A = (ushort*)(ws + off);          off += (size_t)NNODE * DIM * 2;       // 19.2 MB
    ushort* B = (ushort*)(ws + off);          off += (size_t)NNODE * DIM * 2;       // 19.2 MB
    int* rowptr = (int*)(ws + off);           off += 600064;                        // NNODE+1
    int* bcur = (int*)(ws + off);             off += 16384;                         // 8*NBK ints
    u64* part = (u64*)(ws + off);             off += (size_t)NBK * BCAP * 8;        // 38.4 MB
    unsigned* edges = (unsigned*)(ws + off);  off += (size_t)NNZ * 4;               // 16 MB

    detect_fmt<<<1, 256, 0, stream>>>((const unsigned int*)drop_msk,
                                      (const unsigned int*)users,
                                      (const unsigned int*)adj_val, flags, bcur);
    prep_fused<<<GP1 + GCC + GGF, 512, 0, stream>>>(drop_msk, adj_row, adj_col,
                                                    adj_val, user_emb, item_emb,
                                                    users, items, flags, bcur,
                                                    part, A, out_acc);
    pass2_csr<<<NBK, 512, 0, stream>>>(part, bcur, edges, rowptr);

    // l=0: A->B (no fused gather; ego0 already accumulated by prep)
    spmm_fused<<<GSP, 256, 0, stream>>>(A, rowptr, edges, B,
                                        users, items, flags, out_acc);
    // l=1: B->A, fused gather of layer-1 output (src=B)
    spmm_fused<<<GSP + GOUT, 256, 0, stream>>>(B, rowptr, edges, A,
                                               users, items, flags, out_acc);
    // l=2: A->B, fused gather of layer-2 output (src=A)
    spmm_fused<<<GSP + GOUT, 256, 0, stream>>>(A, rowptr, edges, B,
                                               users, items, flags, out_acc);
    // final: acc + gather of layer-3 output (B), scaled
    gather_final<<<GOUT, 256, 0, stream>>>(B, users, items, flags, out_acc, out);
}

// Round 16
// 163.768 us; speedup vs baseline: 16.2783x; 1.1524x over previous
//
#include <hip/hip_runtime.h>
#include <hip/hip_bf16.h>

// LightGCN encoder on MI355X.
// Device dtypes: user_emb/item_emb/adj_val = float32 (bf16-rounded values),
// adj_row/adj_col = int32, drop_mask = bool/int32 (runtime-detected),
// users/items = int64/int32 (runtime-detected), output = float32.
//
// Round-16: layer-3's SpMM output is only read at the <=32768 batch nodes,
// so the full 150K-row layer-3 SpMM (256 MB of gathers + 19 MB write) is
// replaced by final_fused: per batch element, compute its layer-3 row
// directly from the CSR over the layer-2 table, add the layer-2 gather and
// the f32 acc (layers 0+1), scale, store. 6 launches total.

#define NUSER 100000
#define NITEM 50000
#define NNODE 150000
#define DIM   64
#define NNZ   4000000
#define BATCH 16384

#define BSH2  9             // bucket = row >> 9
#define BRWS  512           // rows per bucket
#define NBK   293           // ceil(150000/512)
#define SCAP  2048          // per-shard sub-run capacity
#define BCAP  16384         // 8 * SCAP records per bucket region
#define CHUNK 4096          // edges per pass1 block (8 per 512 threads)
#define GP1   977           // ceil(NNZ/CHUNK)
#define GCC   4688          // ceil(NNODE*DIM/4/512)  concat blocks (512t)
#define GGF   1024          // gather_first blocks (512t)
#define GSP   4688          // ceil(NNODE/32) spmm blocks (256t)
#define GOUT  2048          // gather blocks (256t)
#define GFIN  1024          // final_fused blocks (32 batch elems each)

typedef __hip_bfloat16 bf16;
typedef unsigned short ushort;
typedef unsigned long long u64;
typedef float f4 __attribute__((ext_vector_type(4)));
typedef ushort us4 __attribute__((ext_vector_type(4)));
typedef ushort us8 __attribute__((ext_vector_type(8)));

__device__ __forceinline__ float loadF(const void* p, long i, int isbf16) {
    return isbf16 ? __bfloat162float(((const bf16*)p)[i]) : ((const float*)p)[i];
}

__device__ __forceinline__ bool keepE(const void* mask, int e, int isbyte) {
    return isbyte ? (((const unsigned char*)mask)[e] != 0)
                  : (((const int*)mask)[e] != 0);
}

__device__ __forceinline__ ushort f2bf(float x) {   // round-to-nearest-even
    unsigned u = __float_as_uint(x);
    return (ushort)((u + 0x7FFFu + ((u >> 16) & 1u)) >> 16);
}
__device__ __forceinline__ float bf2f(ushort u) {
    return __uint_as_float((unsigned)u << 16);
}

// val = 2*adj_val in (0,2]; exactly bf16. 13-bit code: (e8-95)<<7 | m7.
__device__ __forceinline__ unsigned encodeV(float v) {
    unsigned fb = __float_as_uint(v);
    unsigned e8 = (fb >> 23) & 0xFFu;
    unsigned m7 = (fb >> 16) & 0x7Fu;
    return ((e8 - 95u) << 7) | m7;
}
__device__ __forceinline__ float decodeV(unsigned code) {
    unsigned vb = code >> 18;                      // 13 bits at [18,31)
    return __uint_as_float((((vb >> 7) + 95u) << 23) | ((vb & 0x7Fu) << 16));
}

__device__ __forceinline__ long nodeOf(int b, const int* users, const int* items, int sh) {
    if (b < BATCH) return (long)users[(size_t)b << sh];
    return (long)NUSER + (long)items[(size_t)(b - BATCH) << sh];
}

// ---------------------------------------------------------------------------
// flags[0]: drop_mask is 1-byte. flags[1]: users/items are int64.
// flags[2]: float arrays are bf16. Also zero-inits sharded counters.
__global__ __launch_bounds__(256) void detect_fmt(const unsigned int* __restrict__ mask,
                                                  const unsigned int* __restrict__ users,
                                                  const unsigned int* __restrict__ adjv,
                                                  int* __restrict__ flags,
                                                  int* __restrict__ bcur) {
    __shared__ int s[3];
    if (threadIdx.x < 3) s[threadIdx.x] = 0;
    for (int b = threadIdx.x; b < 8 * NBK; b += 256) bcur[b] = 0;
    __syncthreads();
    int c0 = 0, c1 = 0, c2 = 0;
    for (int i = threadIdx.x; i < 4096; i += 256) {
        c0 += (mask[i] > 1u) ? 1 : 0;
        if (i & 1) c1 += (users[i] == 0u) ? 1 : 0;
        unsigned lo = adjv[i] & 0xFFFFu;
        unsigned ex = (lo >> 7) & 0xFFu;
        c2 += ((lo >> 15) == 0u && ex >= 0x60u && ex <= 0x7Fu) ? 1 : 0;
    }
    atomicAdd(&s[0], c0); atomicAdd(&s[1], c1); atomicAdd(&s[2], c2);
    __syncthreads();
    if (threadIdx.x == 0) {
        flags[0] = (s[0] > 16) ? 1 : 0;
        flags[1] = (s[1] > 1024) ? 1 : 0;
        flags[2] = (s[2] > 3000) ? 1 : 0;
    }
}

// ---------------------------------------------------------------------------
// Fused prep (512 threads): blocks [0,GP1) = pass1; [GP1,GP1+GCC) = concat;
// [GP1+GCC, +GGF) = gather_first (reads raw inputs).
__global__ __launch_bounds__(512) void prep_fused(const void* __restrict__ mask,
                                                  const int* __restrict__ rows,
                                                  const int* __restrict__ cols,
                                                  const void* __restrict__ adjv,
                                                  const void* __restrict__ ue,
                                                  const void* __restrict__ ie,
                                                  const int* __restrict__ users,
                                                  const int* __restrict__ items,
                                                  const int* __restrict__ flags,
                                                  int* __restrict__ bcur,
                                                  u64* __restrict__ part,
                                                  ushort* __restrict__ A,
                                                  float* __restrict__ out_acc) {
    __shared__ int cnt[NBK];
    __shared__ int cur[NBK];
    const int blk = blockIdx.x;
    const int tid = threadIdx.x;

    if (blk < GP1) {
        // ---- pass1: partition kept edges; single LDS atomic per edge ----
        const int isbyte = flags[0];
        const int isbf = flags[2];
        const int base_e = blk * CHUNK;
        const int sh = blk & 7;
        u64 rec[8];
        int bkt[8], off[8];
        unsigned kept = 0;

        for (int b = tid; b < NBK; b += 512) cnt[b] = 0;
        __syncthreads();

        #pragma unroll
        for (int k = 0; k < 8; ++k) {
            int e = base_e + k * 512 + tid;
            if (e < NNZ && keepE(mask, e, isbyte)) {
                int r = rows[e];
                float v = 2.0f * loadF(adjv, e, isbf);
                rec[k] = (u64)(unsigned)(r & (BRWS - 1))
                       | ((u64)(unsigned)cols[e] << 9)
                       | ((u64)encodeV(v) << 27);
                bkt[k] = r >> BSH2;
                off[k] = atomicAdd(&cnt[bkt[k]], 1);   // offset = count return
                kept |= 1u << k;
            }
        }
        __syncthreads();

        for (int b = tid; b < NBK; b += 512)
            cur[b] = cnt[b] ? atomicAdd(&bcur[sh * NBK + b], cnt[b]) : 0;
        __syncthreads();

        #pragma unroll
        for (int k = 0; k < 8; ++k) {
            if (kept & (1u << k)) {
                int pos = cur[bkt[k]] + off[k];        // no atomic
                if (pos < SCAP)
                    part[(size_t)bkt[k] * BCAP + sh * SCAP + pos] = rec[k];
            }
        }
    } else if (blk < GP1 + GCC) {
        // ---- concat_cast: A(bf16) = concat(ue, ie) ----
        long q = (long)(blk - GP1) * 512 + tid;           // us4 index
        const long NU4 = (long)NUSER * DIM / 4;
        const long NT4 = (long)NNODE * DIM / 4;
        if (q >= NT4) return;
        us4 o;
        if (!flags[2]) {
            const f4* s = (q < NU4) ? (const f4*)ue : (const f4*)ie;
            f4 v = s[(q < NU4) ? q : q - NU4];
            o[0] = f2bf(v.x); o[1] = f2bf(v.y); o[2] = f2bf(v.z); o[3] = f2bf(v.w);
        } else {
            const us4* s = (q < NU4) ? (const us4*)ue : (const us4*)ie;
            o = s[(q < NU4) ? q : q - NU4];
        }
        ((us4*)A)[q] = o;
    } else {
        // ---- gather_first: out_acc[b,:] = input[node(b),:] ----
        int t = (blk - GP1 - GCC) * 512 + tid;            // f4 index
        if (t >= 2 * BATCH * DIM / 4) return;
        long node = nodeOf(t >> 4, users, items, flags[1]);
        int d4 = t & 15;
        const void* src = (node < NUSER) ? ue : ie;
        long q = (node < NUSER ? node : node - NUSER) * 16 + d4;
        f4 a;
        if (!flags[2]) {
            a = ((const f4*)src)[q];
        } else {
            us4 u = ((const us4*)src)[q];
            a.x = bf2f(u[0]); a.y = bf2f(u[1]); a.z = bf2f(u[2]); a.w = bf2f(u[3]);
        }
        ((f4*)out_acc)[t] = a;
    }
}

// ---------------------------------------------------------------------------
// pass2 (+ folded bucket scan): one 512-thread WG per bucket; thread = row.
__global__ __launch_bounds__(512) void pass2_csr(const u64* __restrict__ part,
                                                 const int* __restrict__ bcur,
                                                 unsigned* __restrict__ edges,
                                                 int* __restrict__ rowptr) {
    __shared__ int tot[512];
    __shared__ int cnt[BRWS];
    __shared__ int ex[BRWS];    // doubles as per-row cursor
    __shared__ int wsum[512];
    __shared__ int ns[8];
    __shared__ int gb_s;
    int b = blockIdx.x;
    int tid = threadIdx.x;

    int v = 0;
    if (tid < NBK) {
        #pragma unroll
        for (int sh = 0; sh < 8; ++sh) {
            int c = bcur[sh * NBK + tid];
            v += (c > SCAP) ? SCAP : c;
        }
    }
    tot[tid] = v;
    if (tid < 8) {
        int c = bcur[tid * NBK + b];
        ns[tid] = (c > SCAP) ? SCAP : c;
    }
    cnt[tid] = 0;
    __syncthreads();
    for (int off = 1; off < 512; off <<= 1) {
        int t = (tid >= off) ? tot[tid - off] : 0;
        __syncthreads();
        tot[tid] += t;
        __syncthreads();
    }
    if (tid == 0) {
        gb_s = (b > 0) ? tot[b - 1] : 0;
        if (b == 0) rowptr[0] = 0;
    }
    __syncthreads();
    const int gb = gb_s;
    const u64* bp = part + (size_t)b * BCAP;

    #pragma unroll
    for (int sh = 0; sh < 8; ++sh) {
        int n = ns[sh];
        const u64* rp = bp + sh * SCAP;
        for (int j = tid; j < n; j += 512)
            atomicAdd(&cnt[(int)(rp[j] & (BRWS - 1))], 1);
    }
    __syncthreads();

    int c = cnt[tid];
    wsum[tid] = c;
    __syncthreads();
    for (int off = 1; off < 512; off <<= 1) {
        int t = (tid >= off) ? wsum[tid - off] : 0;
        __syncthreads();
        wsum[tid] += t;
        __syncthreads();
    }
    int incl = wsum[tid];
    ex[tid] = incl - c;
    int gr = (b << BSH2) + tid;
    if (gr < NNODE) rowptr[gr + 1] = gb + incl;
    __syncthreads();

    #pragma unroll
    for (int sh = 0; sh < 8; ++sh) {
        int n = ns[sh];
        const u64* rp = bp + sh * SCAP;
        for (int j = tid; j < n; j += 512) {
            u64 rec = rp[j];
            int r = (int)(rec & (BRWS - 1));
            int pos = atomicAdd(&ex[r], 1);
            unsigned col = (unsigned)((rec >> 9) & 0x3FFFFu);
            unsigned code = (unsigned)((rec >> 27) & 0x1FFFu);
            edges[gb + pos] = col | (code << 18);
        }
    }
}

// ---------------------------------------------------------------------------
// spmm (+ optionally fused gather_add of the PREVIOUS layer, which reads the
// same src table). Blocks [0,GSP) = spmm eighth-wave-per-row; [GSP,+GOUT) =
// acc[b,:] += src[node(b),:]. dst is the other buffer -> no hazard.
__global__ __launch_bounds__(256) void spmm_fused(const ushort* __restrict__ src,
                                                  const int* __restrict__ rowptr,
                                                  const unsigned* __restrict__ edges,
                                                  ushort* __restrict__ dst,
                                                  const int* __restrict__ users,
                                                  const int* __restrict__ items,
                                                  const int* __restrict__ flags,
                                                  float* __restrict__ acc) {
    if (blockIdx.x >= GSP) {
        int t = (blockIdx.x - GSP) * 256 + threadIdx.x;   // f4 index
        if (t >= 2 * BATCH * DIM / 4) return;
        long node = nodeOf(t >> 4, users, items, flags[1]);
        us4 u = ((const us4*)(src + node * DIM))[t & 15];
        f4 a = ((f4*)acc)[t];
        a.x += bf2f(u[0]); a.y += bf2f(u[1]); a.z += bf2f(u[2]); a.w += bf2f(u[3]);
        ((f4*)acc)[t] = a;
        return;
    }
    int r = blockIdx.x * 32 + (threadIdx.x >> 3);
    if (r >= NNODE) return;
    int t = threadIdx.x & 7;
    int j0 = rowptr[r], j1 = rowptr[r + 1];
    float acc8[8] = {0, 0, 0, 0, 0, 0, 0, 0};
    int j = j0;
    for (; j + 4 <= j1; j += 4) {
        unsigned e0 = edges[j];
        unsigned e1 = edges[j + 1];
        unsigned e2 = edges[j + 2];
        unsigned e3 = edges[j + 3];
        us8 s0 = ((const us8*)(src + (size_t)(e0 & 0x3FFFFu) * DIM))[t];
        us8 s1 = ((const us8*)(src + (size_t)(e1 & 0x3FFFFu) * DIM))[t];
        us8 s2 = ((const us8*)(src + (size_t)(e2 & 0x3FFFFu) * DIM))[t];
        us8 s3 = ((const us8*)(src + (size_t)(e3 & 0x3FFFFu) * DIM))[t];
        float v0 = decodeV(e0), v1 = decodeV(e1);
        float v2 = decodeV(e2), v3 = decodeV(e3);
        #pragma unroll
        for (int d = 0; d < 8; ++d) {
            acc8[d] += v0 * bf2f(s0[d]);
            acc8[d] += v1 * bf2f(s1[d]);
            acc8[d] += v2 * bf2f(s2[d]);
            acc8[d] += v3 * bf2f(s3[d]);
        }
    }
    for (; j < j1; ++j) {
        unsigned e0 = edges[j];
        float v0 = decodeV(e0);
        us8 s0 = ((const us8*)(src + (size_t)(e0 & 0x3FFFFu) * DIM))[t];
        #pragma unroll
        for (int d = 0; d < 8; ++d) acc8[d] += v0 * bf2f(s0[d]);
    }
    us8 o;
    #pragma unroll
    for (int d = 0; d < 8; ++d) o[d] = f2bf(acc8[d]);
    __builtin_nontemporal_store(o, (us8*)(dst + (size_t)r * DIM) + t);
}

// ---------------------------------------------------------------------------
// final_fused: eighth-wave per batch element. For element b with node n:
// out[b,:] = 0.25 * (acc[b,:] (layers 0+1) + A[n,:] (layer 2)
//                    + sum_j val[j]*A[col[j],:] (layer 3, computed directly)).
// Replaces the full 150K-row layer-3 SpMM (output was only read here).
__global__ __launch_bounds__(256) void final_fused(const ushort* __restrict__ A,
                                                   const int* __restrict__ rowptr,
                                                   const unsigned* __restrict__ edges,
                                                   const int* __restrict__ users,
                                                   const int* __restrict__ items,
                                                   const int* __restrict__ flags,
                                                   const float* __restrict__ acc,
                                                   float* __restrict__ out) {
    int b = blockIdx.x * 32 + (threadIdx.x >> 3);
    if (b >= 2 * BATCH) return;
    int t = threadIdx.x & 7;
    long node = nodeOf(b, users, items, flags[1]);
    int j0 = rowptr[node], j1 = rowptr[node + 1];
    float a8[8] = {0, 0, 0, 0, 0, 0, 0, 0};
    int j = j0;
    for (; j + 4 <= j1; j += 4) {
        unsigned e0 = edges[j];
        unsigned e1 = edges[j + 1];
        unsigned e2 = edges[j + 2];
        unsigned e3 = edges[j + 3];
        us8 s0 = ((const us8*)(A + (size_t)(e0 & 0x3FFFFu) * DIM))[t];
        us8 s1 = ((const us8*)(A + (size_t)(e1 & 0x3FFFFu) * DIM))[t];
        us8 s2 = ((const us8*)(A + (size_t)(e2 & 0x3FFFFu) * DIM))[t];
        us8 s3 = ((const us8*)(A + (size_t)(e3 & 0x3FFFFu) * DIM))[t];
        float v0 = decodeV(e0), v1 = decodeV(e1);
        float v2 = decodeV(e2), v3 = decodeV(e3);
        #pragma unroll
        for (int d = 0; d < 8; ++d) {
            a8[d] += v0 * bf2f(s0[d]);
            a8[d] += v1 * bf2f(s1[d]);
            a8[d] += v2 * bf2f(s2[d]);
            a8[d] += v3 * bf2f(s3[d]);
        }
    }
    for (; j < j1; ++j) {
        unsigned e0 = edges[j];
        float v0 = decodeV(e0);
        us8 s0 = ((const us8*)(A + (size_t)(e0 & 0x3FFFFu) * DIM))[t];
        #pragma unroll
        for (int d = 0; d < 8; ++d) a8[d] += v0 * bf2f(s0[d]);
    }
    // + layer-2 row (A[node]) and + acc (layers 0+1), scale 0.25
    us8 u2 = ((const us8*)(A + node * DIM))[t];
    const f4* ap = (const f4*)acc + (size_t)b * 16 + 2 * t;
    f4 a0 = ap[0], a1 = ap[1];
    f4 o0, o1;
    o0.x = 0.25f * (a0.x + bf2f(u2[0]) + a8[0]);
    o0.y = 0.25f * (a0.y + bf2f(u2[1]) + a8[1]);
    o0.z = 0.25f * (a0.z + bf2f(u2[2]) + a8[2]);
    o0.w = 0.25f * (a0.w + bf2f(u2[3]) + a8[3]);
    o1.x = 0.25f * (a1.x + bf2f(u2[4]) + a8[4]);
    o1.y = 0.25f * (a1.y + bf2f(u2[5]) + a8[5]);
    o1.z = 0.25f * (a1.z + bf2f(u2[6]) + a8[6]);
    o1.w = 0.25f * (a1.w + bf2f(u2[7]) + a8[7]);
    f4* op = (f4*)(out + (size_t)b * DIM) + 2 * t;
    __builtin_nontemporal_store(o0, op);
    __builtin_nontemporal_store(o1, op + 1);
}

extern "C" void kernel_launch(void* const* d_in, const int* in_sizes, int n_in,
                              void* d_out, int out_size, void* d_ws, size_t ws_size,
                              hipStream_t stream) {
    const void* user_emb = d_in[0];
    const void* item_emb = d_in[1];
    const void* adj_val  = d_in[2];
    const int*  adj_row  = (const int*)d_in[3];
    const int*  adj_col  = (const int*)d_in[4];
    const void* drop_msk = d_in[5];
    const int*  users    = (const int*)d_in[6];
    const int*  items    = (const int*)d_in[7];
    float* out = (float*)d_out;

    char* ws = (char*)d_ws;
    size_t off = 0;
    int* flags = (int*)(ws + off);            off += 256;
    float* out_acc = (float*)(ws + off);      off += (size_t)2 * BATCH * DIM * 4;   // 8 MB
    ushort* A = (ushort*)(ws + off);          off += (size_t)NNODE * DIM * 2;       // 19.2 MB
    ushort* B = (ushort*)(ws + off);          off += (size_t)NNODE * DIM * 2;       // 19.2 MB
    int* rowptr = (int*)(ws + off);           off += 600064;                        // NNODE+1
    int* bcur = (int*)(ws + off);             off += 16384;                         // 8*NBK ints
    u64* part = (u64*)(ws + off);             off += (size_t)NBK * BCAP * 8;        // 38.4 MB
    unsigned* edges = (unsigned*)(ws + off);  off += (size_t)NNZ * 4;               // 16 MB

    detect_fmt<<<1, 256, 0, stream>>>((const unsigned int*)drop_msk,
                                      (const unsigned int*)users,
                                      (const unsigned int*)adj_val, flags, bcur);
    prep_fused<<<GP1 + GCC + GGF, 512, 0, stream>>>(drop_msk, adj_row, adj_col,
                                                    adj_val, user_emb, item_emb,
                                                    users, items, flags, bcur,
                                                    part, A, out_acc);
    pass2_csr<<<NBK, 512, 0, stream>>>(part, bcur, edges, rowptr);

    // l=1: A->B (ego0 already accumulated by prep)
    spmm_fused<<<GSP, 256, 0, stream>>>(A, rowptr, edges, B,
                                        users, items, flags, out_acc);
    // l=2: B->A, fused gather of layer-1 output (src=B)
    spmm_fused<<<GSP + GOUT, 256, 0, stream>>>(B, rowptr, edges, A,
                                               users, items, flags, out_acc);
    // final: per batch element, layer-2 gather + layer-3 row compute + scale
    final_fused<<<GFIN, 256, 0, stream>>>(A, rowptr, edges, users, items,
                                          flags, out_acc, out);
}